// Round 2
// baseline (2817.409 us; speedup 1.0000x reference)
//
#include <hip/hip_runtime.h>
#include <math.h>

__device__ __forceinline__ float gelu_f(float x) {
  // exact erf GELU (torch nn.GELU default / jax approximate=False)
  return 0.5f * x * (1.0f + erff(x * 0.70710678118654752f));
}

// ---------------------------------------------------------------------------
// Generic conv-as-implicit-GEMM: C[m,n] = sum_k A[m,k]*W[n,k] + BN (+GELU)
//   m = (b, oh, ow), k = (ic, dy, dx), weights OIHW (row-major contiguous k).
//   TBL: k->(ic,dy,dx) via LDS lookup (non-pow2 kernels, K<=256)
//   else: kernel size is a power of two, use shifts (ls = log2(ks))
//   TOOUT: store to final [B,196,768] layout at channel offset ch0
// BM=BN=64, BK=16, 256 threads, 4x4 micro-tile. M must be divisible by 64.
// ---------------------------------------------------------------------------
template<bool TBL, bool GELU, bool TOOUT>
__global__ __launch_bounds__(256) void convgemm_k(
    const float* __restrict__ in, const float* __restrict__ w,
    const float* __restrict__ bns, const float* __restrict__ bnb,
    float* __restrict__ out,
    int Cin, int H, int W, int ks, int stride, int pad, int ls,
    int OH, int OW, int N, int K, int ch0) {
  __shared__ __align__(16) float sA[16][64];
  __shared__ __align__(16) float sB[16][64];
  __shared__ int sTbl[256];
  const int tid = threadIdx.x;
  if (TBL) {
    int kk2 = ks * ks;
    for (int k = tid; k < K; k += 256) {
      int ic = k / kk2, r = k - ic * kk2;
      sTbl[k] = (ic << 16) | ((r / ks) << 8) | (r % ks);
    }
  }
  const int m0 = blockIdx.x * 64, n0 = blockIdx.y * 64;
  const int mm = tid >> 2, kq = tid & 3;
  const int OHW = OH * OW, HW = H * W;
  int m = m0 + mm;
  int bI = m / OHW; int r = m - bI * OHW;
  int oh = r / OW;  int ow = r - oh * OW;
  const int ihBase = oh * stride - pad, iwBase = ow * stride - pad;
  const int inBase = bI * Cin * HW;
  const int tm = tid & 15, tn = tid >> 4;
  float acc[4][4] = {};
  for (int k0 = 0; k0 < K; k0 += 16) {
    __syncthreads();  // first iter: publishes sTbl; later: protects LDS reuse
    // ---- stage A tile: sA[kk][mm] = A[m0+mm][k0+kk]
#pragma unroll
    for (int i = 0; i < 4; ++i) {
      int kk = kq * 4 + i, k = k0 + kk;
      float v = 0.0f;
      if (k < K) {
        int ic, dy, dx;
        if (TBL) {
          int tv = sTbl[k]; ic = tv >> 16; dy = (tv >> 8) & 255; dx = tv & 255;
        } else {
          ic = k >> (2 * ls);
          int r2 = k & ((1 << (2 * ls)) - 1);
          dy = r2 >> ls; dx = r2 & ((1 << ls) - 1);
        }
        int ih = ihBase + dy, iw = iwBase + dx;
        if (ih >= 0 && ih < H && iw >= 0 && iw < W)
          v = in[inBase + ic * HW + ih * W + iw];
      }
      sA[kk][mm] = v;
    }
    // ---- stage B tile: sB[kk][nn] = W[n0+nn][k0+kk]
#pragma unroll
    for (int i = 0; i < 4; ++i) {
      int kk = kq * 4 + i, k = k0 + kk;
      int n = n0 + mm;
      float v = 0.0f;
      if (n < N && k < K) v = w[n * K + k];
      sB[kk][mm] = v;
    }
    __syncthreads();
    // ---- 4x4 outer product
#pragma unroll
    for (int kk = 0; kk < 16; ++kk) {
      float4 a4 = *(const float4*)&sA[kk][tm * 4];
      float4 b4 = *(const float4*)&sB[kk][tn * 4];
      acc[0][0] += a4.x * b4.x; acc[0][1] += a4.x * b4.y;
      acc[0][2] += a4.x * b4.z; acc[0][3] += a4.x * b4.w;
      acc[1][0] += a4.y * b4.x; acc[1][1] += a4.y * b4.y;
      acc[1][2] += a4.y * b4.z; acc[1][3] += a4.y * b4.w;
      acc[2][0] += a4.z * b4.x; acc[2][1] += a4.z * b4.y;
      acc[2][2] += a4.z * b4.z; acc[2][3] += a4.z * b4.w;
      acc[3][0] += a4.w * b4.x; acc[3][1] += a4.w * b4.y;
      acc[3][2] += a4.w * b4.z; acc[3][3] += a4.w * b4.w;
    }
  }
  // ---- epilogue: BN (+GELU) + store
#pragma unroll
  for (int i = 0; i < 4; ++i) {
    int mI = m0 + tm * 4 + i;
    int bO = mI / OHW; int rr = mI - bO * OHW;
#pragma unroll
    for (int j = 0; j < 4; ++j) {
      int n = n0 + tn * 4 + j;
      if (n < N) {
        float v = acc[i][j] * bns[n] + bnb[n];
        if (GELU) v = gelu_f(v);
        if (TOOUT) {
          out[(bO * OHW + rr) * 768 + ch0 + n] = v;  // OHW==196
        } else {
          int oh2 = rr / OW, ow2 = rr - oh2 * OW;
          out[((bO * N + n) * OH + oh2) * OW + ow2] = v;
        }
      }
    }
  }
}

// ---------------------------------------------------------------------------
// Split-K conv-GEMM for branch3 (k16s16, pow2 kernel, no pad). Each block
// computes a K-slice [kBase, kBase+kLen) and atomically accumulates
// acc*scale[n] into out (bias pre-written by init_b3). M-guarded (M%64 != 0).
// ---------------------------------------------------------------------------
__global__ __launch_bounds__(256) void convgemm_splitk(
    const float* __restrict__ in, const float* __restrict__ w,
    const float* __restrict__ scale, float* __restrict__ out,
    int Cin, int H, int W, int stride, int ls,
    int OH, int OW, int N, int K, int M, int kLen, int ch0) {
  __shared__ __align__(16) float sA[16][64];
  __shared__ __align__(16) float sB[16][64];
  const int tid = threadIdx.x;
  const int m0 = blockIdx.x * 64, n0 = blockIdx.y * 64;
  const int kBase = blockIdx.z * kLen;
  const int mm = tid >> 2, kq = tid & 3;
  const int OHW = OH * OW, HW = H * W;
  int m = m0 + mm;
  int mc = (m < M) ? m : 0;  // clamp for address math only
  int bI = mc / OHW; int r = mc - bI * OHW;
  int oh = r / OW;  int ow = r - oh * OW;
  const int ihBase = oh * stride, iwBase = ow * stride;
  const int inBase = bI * Cin * HW;
  const int tm = tid & 15, tn = tid >> 4;
  float acc[4][4] = {};
  for (int k0 = kBase; k0 < kBase + kLen; k0 += 16) {
    __syncthreads();
#pragma unroll
    for (int i = 0; i < 4; ++i) {
      int kk = kq * 4 + i, k = k0 + kk;
      float v = 0.0f;
      if (m < M) {
        int ic = k >> (2 * ls);
        int r2 = k & ((1 << (2 * ls)) - 1);
        int dy = r2 >> ls, dx = r2 & ((1 << ls) - 1);
        v = in[inBase + ic * HW + (ihBase + dy) * W + (iwBase + dx)];
      }
      sA[kk][mm] = v;
    }
#pragma unroll
    for (int i = 0; i < 4; ++i) {
      int kk = kq * 4 + i, k = k0 + kk;
      int n = n0 + mm;
      sB[kk][mm] = (n < N) ? w[n * K + k] : 0.0f;
    }
    __syncthreads();
#pragma unroll
    for (int kk = 0; kk < 16; ++kk) {
      float4 a4 = *(const float4*)&sA[kk][tm * 4];
      float4 b4 = *(const float4*)&sB[kk][tn * 4];
      acc[0][0] += a4.x * b4.x; acc[0][1] += a4.x * b4.y;
      acc[0][2] += a4.x * b4.z; acc[0][3] += a4.x * b4.w;
      acc[1][0] += a4.y * b4.x; acc[1][1] += a4.y * b4.y;
      acc[1][2] += a4.y * b4.z; acc[1][3] += a4.y * b4.w;
      acc[2][0] += a4.z * b4.x; acc[2][1] += a4.z * b4.y;
      acc[2][2] += a4.z * b4.z; acc[2][3] += a4.z * b4.w;
      acc[3][0] += a4.w * b4.x; acc[3][1] += a4.w * b4.y;
      acc[3][2] += a4.w * b4.z; acc[3][3] += a4.w * b4.w;
    }
  }
#pragma unroll
  for (int i = 0; i < 4; ++i) {
    int mI = m0 + tm * 4 + i;
    if (mI < M) {
      int bO = mI / OHW; int rr = mI - bO * OHW;
#pragma unroll
      for (int j = 0; j < 4; ++j) {
        int n = n0 + tn * 4 + j;
        if (n < N)
          atomicAdd(&out[(bO * OHW + rr) * 768 + ch0 + n], acc[i][j] * scale[n]);
      }
    }
  }
}

// init branch3 output slice with BN bias (atomic partials add onto it)
__global__ void init_b3(float* __restrict__ out, const float* __restrict__ bias) {
  int i = blockIdx.x * 256 + threadIdx.x;
  if (i < 16 * 196 * 256) {
    int n = i & 255, bp = i >> 8;
    out[bp * 768 + 512 + n] = bias[n];
  }
}

// ---------------------------------------------------------------------------
// Fused RegionLayerDW (+ trailing outer GELU):
//   per tile t of a GxG grid: dw3x3 (zero-padded WITHIN tile) -> BN -> GELU
//   -> 1x1 (CxC) -> BN -> +residual -> outer GELU.
// One block = one 8x8 pixel sub-block of one tile for one batch image.
// ---------------------------------------------------------------------------
template<int C, int TH, int TW, int G>
__global__ __launch_bounds__(256) void region_k(
    const float* __restrict__ in, const float* __restrict__ dww,
    const float* __restrict__ s1v, const float* __restrict__ b1v,
    const float* __restrict__ pwv, const float* __restrict__ s2v,
    const float* __restrict__ b2v, float* __restrict__ out) {
  constexpr int BH = 8, BW = 8, PIX = 64;
  constexpr int FULL = G * TH;        // full H (=W)
  constexpr int NBW = TW / BW;
  static_assert(TH % BH == 0 && TW % BW == 0, "tile divisibility");
  __shared__ __align__(16) float sIn[C][BH + 2][BW + 2];
  __shared__ __align__(16) float sH[C][PIX];
  __shared__ __align__(16) float sPWT[C][C];   // transposed: [c][o]
  __shared__ float sDW[C][9];
  __shared__ float sS1[C], sB1[C], sS2[C], sB2[C];
  const int t = blockIdx.x, pb = blockIdx.y, b = blockIdx.z;
  const int gy = t / G, gx = t % G;
  const int py0 = (pb / NBW) * BH, px0 = (pb % NBW) * BW;
  const int Y0 = gy * TH, X0 = gx * TW;
  const int tid = threadIdx.x;
  for (int i = tid; i < C * C; i += 256) {
    int o = i / C, c = i - o * C;
    sPWT[c][o] = pwv[t * C * C + i];
  }
  for (int i = tid; i < C * 9; i += 256) ((float*)sDW)[i] = dww[t * C * 9 + i];
  for (int i = tid; i < C; i += 256) {
    sS1[i] = s1v[t * C + i]; sB1[i] = b1v[t * C + i];
    sS2[i] = s2v[t * C + i]; sB2[i] = b2v[t * C + i];
  }
  // input halo, zeros OUTSIDE THE TILE (dw conv pads per-tile)
  for (int i = tid; i < C * (BH + 2) * (BW + 2); i += 256) {
    int c = i / ((BH + 2) * (BW + 2)); int rr = i - c * (BH + 2) * (BW + 2);
    int iy = rr / (BW + 2), ix = rr - iy * (BW + 2);
    int ly = py0 + iy - 1, lx = px0 + ix - 1;
    float v = 0.0f;
    if (ly >= 0 && ly < TH && lx >= 0 && lx < TW)
      v = in[((b * C + c) * FULL + Y0 + ly) * FULL + X0 + lx];
    sIn[c][iy][ix] = v;
  }
  __syncthreads();
  // depthwise 3x3 + BN + GELU
  for (int i = tid; i < C * PIX; i += 256) {
    int c = i >> 6, p = i & 63;
    int py = p >> 3, px = p & 7;
    float a = 0.0f;
#pragma unroll
    for (int ky = 0; ky < 3; ++ky)
#pragma unroll
      for (int kx = 0; kx < 3; ++kx)
        a += sIn[c][py + ky][px + kx] * sDW[c][ky * 3 + kx];
    sH[c][p] = gelu_f(a * sS1[c] + sB1[c]);
  }
  __syncthreads();
  // pointwise CxC + BN + residual + outer GELU; thread = 4 o x 4 p
  constexpr int TASKS = (C / 4) * (PIX / 4);
  if (tid < TASKS) {
    const int og = tid >> 4, pg = tid & 15;
    const int o0 = og * 4, p0 = pg * 4;
    float acc[4][4] = {};
    for (int c = 0; c < C; ++c) {
      float4 h4 = *(const float4*)&sH[c][p0];
      float4 w4 = *(const float4*)&sPWT[c][o0];
      float hh[4] = {h4.x, h4.y, h4.z, h4.w};
      float ww[4] = {w4.x, w4.y, w4.z, w4.w};
#pragma unroll
      for (int j = 0; j < 4; ++j)
#pragma unroll
        for (int e = 0; e < 4; ++e) acc[j][e] += ww[j] * hh[e];
    }
#pragma unroll
    for (int j = 0; j < 4; ++j) {
      int o = o0 + j;
#pragma unroll
      for (int e = 0; e < 4; ++e) {
        int p = p0 + e, py = p >> 3, px = p & 7;
        float v = acc[j][e] * sS2[o] + sB2[o] + sIn[o][py + 1][px + 1];
        v = gelu_f(v);
        out[((b * C + o) * FULL + Y0 + py0 + py) * FULL + X0 + px0 + px] = v;
      }
    }
  }
}

// ---------------------------------------------------------------------------
extern "C" void kernel_launch(void* const* d_in, const int* in_sizes, int n_in,
                              void* d_out, int out_size, void* d_ws, size_t ws_size,
                              hipStream_t stream) {
  const float* x     = (const float*)d_in[0];
  const float* r1_w  = (const float*)d_in[1];
  const float* r1_s  = (const float*)d_in[2];
  const float* r1_b  = (const float*)d_in[3];
  const float* r1_dw = (const float*)d_in[4];
  const float* r1_s1 = (const float*)d_in[5];
  const float* r1_b1 = (const float*)d_in[6];
  const float* r1_pw = (const float*)d_in[7];
  const float* r1_s2 = (const float*)d_in[8];
  const float* r1_b2 = (const float*)d_in[9];
  const float* r2_w  = (const float*)d_in[10];
  const float* r2_s  = (const float*)d_in[11];
  const float* r2_b  = (const float*)d_in[12];
  const float* r2_dw = (const float*)d_in[13];
  const float* r2_s1 = (const float*)d_in[14];
  const float* r2_b1 = (const float*)d_in[15];
  const float* r2_pw = (const float*)d_in[16];
  const float* r2_s2 = (const float*)d_in[17];
  const float* r2_b2 = (const float*)d_in[18];
  const float* h1_w1 = (const float*)d_in[19];
  const float* h1_s1 = (const float*)d_in[20];
  const float* h1_b1 = (const float*)d_in[21];
  const float* h1_w2 = (const float*)d_in[22];
  const float* h1_s2 = (const float*)d_in[23];
  const float* h1_b2 = (const float*)d_in[24];
  const float* h1_w3 = (const float*)d_in[25];
  const float* h1_s3 = (const float*)d_in[26];
  const float* h1_b3 = (const float*)d_in[27];
  const float* h2_w1 = (const float*)d_in[28];
  const float* h2_s1 = (const float*)d_in[29];
  const float* h2_b1 = (const float*)d_in[30];
  const float* h2_w2 = (const float*)d_in[31];
  const float* h2_s2 = (const float*)d_in[32];
  const float* h2_b2 = (const float*)d_in[33];
  const float* h3_w  = (const float*)d_in[34];
  const float* h3_s  = (const float*)d_in[35];
  const float* h3_b  = (const float*)d_in[36];
  float* out = (float*)d_out;

  // Workspace layout (floats). Peak = 38,535,168 f = 154.2 MB.
  //   R1 : region1 full [16,24,224,224]            @ 0        (19,267,584 f)
  //   T1 : 4-image temp [4,<=48,224,224]           @ 19267584 ( 9,633,792 f)
  //   T2 : 4-image temp [4,48,224,224]             @ 28901376 ( 9,633,792 f)
  float* R1 = (float*)d_ws;
  float* T1 = R1 + 19267584;
  float* T2 = R1 + 28901376;

  dim3 blk(256);
  const int IMG3  = 3 * 224 * 224;      // x per-image
  const int IMG24 = 24 * 224 * 224;     // 24-ch per-image

  // ---- region1 chain, 4-image chunks: conv5(x)->T1, region1(T1)->R1[g]
  for (int g = 0; g < 4; ++g) {
    convgemm_k<true, true, false><<<dim3(3136, 1), blk, 0, stream>>>(
        x + (size_t)g * 4 * IMG3, r1_w, r1_s, r1_b, T1,
        3, 224, 224, 5, 1, 2, 0, 224, 224, 24, 75, 0);
    region_k<24, 32, 32, 7><<<dim3(49, 16, 4), blk, 0, stream>>>(
        T1, r1_dw, r1_s1, r1_b1, r1_pw, r1_s2, r1_b2,
        R1 + (size_t)g * 4 * IMG24);
  }
  // ---- branch2: R1 -> T1 [16,48,56,56] -> out[ch 256:512]
  convgemm_k<false, true, false><<<dim3(784, 1), blk, 0, stream>>>(
      R1, h2_w1, h2_s1, h2_b1, T1, 24, 224, 224, 4, 4, 0, 2, 56, 56, 48, 384, 0);
  convgemm_k<false, false, true><<<dim3(49, 4), blk, 0, stream>>>(
      T1, h2_w2, h2_s2, h2_b2, out, 48, 56, 56, 4, 4, 0, 2, 14, 14, 256, 768, 256);
  // ---- branch1: x -> T1 [16,48,56,56] -> T2 [16,48,28,28] -> out[ch 0:256]
  convgemm_k<false, true, false><<<dim3(784, 1), blk, 0, stream>>>(
      x, h1_w1, h1_s1, h1_b1, T1, 3, 224, 224, 4, 4, 0, 2, 56, 56, 48, 48, 0);
  convgemm_k<false, true, false><<<dim3(196, 1), blk, 0, stream>>>(
      T1, h1_w2, h1_s2, h1_b2, T2, 48, 56, 56, 2, 2, 0, 1, 28, 28, 48, 192, 0);
  convgemm_k<false, false, true><<<dim3(49, 4), blk, 0, stream>>>(
      T2, h1_w3, h1_s3, h1_b3, out, 48, 28, 28, 2, 2, 0, 1, 14, 14, 256, 192, 0);
  // ---- init branch3 slice with bias, then region2 chain + split-K branch3
  init_b3<<<dim3(3136), blk, 0, stream>>>(out, h3_b);
  for (int g = 0; g < 4; ++g) {
    // conv3x3 24->48 s1 p1 + BN + GELU : R1[g] -> T1 [4,48,224,224]
    convgemm_k<true, true, false><<<dim3(3136, 1), blk, 0, stream>>>(
        R1 + (size_t)g * 4 * IMG24, r2_w, r2_s, r2_b, T1,
        24, 224, 224, 3, 1, 1, 0, 224, 224, 48, 216, 0);
    // RegionDW 4x4 + outer GELU : T1 -> T2
    region_k<48, 56, 56, 4><<<dim3(16, 49, 4), blk, 0, stream>>>(
        T1, r2_dw, r2_s1, r2_b1, r2_pw, r2_s2, r2_b2, T2);
    // branch3 k16s16 48->256, split-K (16 slices of 768): T2 -> out[ch 512:768]
    convgemm_splitk<<<dim3(13, 4, 16), blk, 0, stream>>>(
        T2, h3_w, h3_s, out + (size_t)g * 4 * 196 * 768,
        48, 224, 224, 16, 4, 14, 14, 256, 12288, 784, 768, 512);
  }
  (void)in_sizes; (void)n_in; (void)out_size; (void)ws_size;
}

// Round 3
// 2229.800 us; speedup vs baseline: 1.2635x; 1.2635x over previous
//
#include <hip/hip_runtime.h>
#include <math.h>

__device__ __forceinline__ float gelu_f(float x) {
  // exact erf GELU (torch nn.GELU default / jax approximate=False)
  return 0.5f * x * (1.0f + erff(x * 0.70710678118654752f));
}

// ---------------------------------------------------------------------------
// Generic conv-as-implicit-GEMM: C[m,n] = sum_k A[m,k]*W[n,k] + BN (+GELU)
// (unchanged from R2 — passing baseline)
// ---------------------------------------------------------------------------
template<bool TBL, bool GELU, bool TOOUT>
__global__ __launch_bounds__(256) void convgemm_k(
    const float* __restrict__ in, const float* __restrict__ w,
    const float* __restrict__ bns, const float* __restrict__ bnb,
    float* __restrict__ out,
    int Cin, int H, int W, int ks, int stride, int pad, int ls,
    int OH, int OW, int N, int K, int ch0) {
  __shared__ __align__(16) float sA[16][64];
  __shared__ __align__(16) float sB[16][64];
  __shared__ int sTbl[256];
  const int tid = threadIdx.x;
  if (TBL) {
    int kk2 = ks * ks;
    for (int k = tid; k < K; k += 256) {
      int ic = k / kk2, r = k - ic * kk2;
      sTbl[k] = (ic << 16) | ((r / ks) << 8) | (r % ks);
    }
  }
  const int m0 = blockIdx.x * 64, n0 = blockIdx.y * 64;
  const int mm = tid >> 2, kq = tid & 3;
  const int OHW = OH * OW, HW = H * W;
  int m = m0 + mm;
  int bI = m / OHW; int r = m - bI * OHW;
  int oh = r / OW;  int ow = r - oh * OW;
  const int ihBase = oh * stride - pad, iwBase = ow * stride - pad;
  const int inBase = bI * Cin * HW;
  const int tm = tid & 15, tn = tid >> 4;
  float acc[4][4] = {};
  for (int k0 = 0; k0 < K; k0 += 16) {
    __syncthreads();
#pragma unroll
    for (int i = 0; i < 4; ++i) {
      int kk = kq * 4 + i, k = k0 + kk;
      float v = 0.0f;
      if (k < K) {
        int ic, dy, dx;
        if (TBL) {
          int tv = sTbl[k]; ic = tv >> 16; dy = (tv >> 8) & 255; dx = tv & 255;
        } else {
          ic = k >> (2 * ls);
          int r2 = k & ((1 << (2 * ls)) - 1);
          dy = r2 >> ls; dx = r2 & ((1 << ls) - 1);
        }
        int ih = ihBase + dy, iw = iwBase + dx;
        if (ih >= 0 && ih < H && iw >= 0 && iw < W)
          v = in[inBase + ic * HW + ih * W + iw];
      }
      sA[kk][mm] = v;
    }
#pragma unroll
    for (int i = 0; i < 4; ++i) {
      int kk = kq * 4 + i, k = k0 + kk;
      int n = n0 + mm;
      float v = 0.0f;
      if (n < N && k < K) v = w[n * K + k];
      sB[kk][mm] = v;
    }
    __syncthreads();
#pragma unroll
    for (int kk = 0; kk < 16; ++kk) {
      float4 a4 = *(const float4*)&sA[kk][tm * 4];
      float4 b4 = *(const float4*)&sB[kk][tn * 4];
      acc[0][0] += a4.x * b4.x; acc[0][1] += a4.x * b4.y;
      acc[0][2] += a4.x * b4.z; acc[0][3] += a4.x * b4.w;
      acc[1][0] += a4.y * b4.x; acc[1][1] += a4.y * b4.y;
      acc[1][2] += a4.y * b4.z; acc[1][3] += a4.y * b4.w;
      acc[2][0] += a4.z * b4.x; acc[2][1] += a4.z * b4.y;
      acc[2][2] += a4.z * b4.z; acc[2][3] += a4.z * b4.w;
      acc[3][0] += a4.w * b4.x; acc[3][1] += a4.w * b4.y;
      acc[3][2] += a4.w * b4.z; acc[3][3] += a4.w * b4.w;
    }
  }
#pragma unroll
  for (int i = 0; i < 4; ++i) {
    int mI = m0 + tm * 4 + i;
    int bO = mI / OHW; int rr = mI - bO * OHW;
#pragma unroll
    for (int j = 0; j < 4; ++j) {
      int n = n0 + tn * 4 + j;
      if (n < N) {
        float v = acc[i][j] * bns[n] + bnb[n];
        if (GELU) v = gelu_f(v);
        if (TOOUT) {
          out[(bO * OHW + rr) * 768 + ch0 + n] = v;  // OHW==196
        } else {
          int oh2 = rr / OW, ow2 = rr - oh2 * OW;
          out[((bO * N + n) * OH + oh2) * OW + ow2] = v;
        }
      }
    }
  }
}

// ---------------------------------------------------------------------------
// Split-K conv-GEMM for branch3 (unchanged from R2)
// ---------------------------------------------------------------------------
__global__ __launch_bounds__(256) void convgemm_splitk(
    const float* __restrict__ in, const float* __restrict__ w,
    const float* __restrict__ scale, float* __restrict__ out,
    int Cin, int H, int W, int stride, int ls,
    int OH, int OW, int N, int K, int M, int kLen, int ch0) {
  __shared__ __align__(16) float sA[16][64];
  __shared__ __align__(16) float sB[16][64];
  const int tid = threadIdx.x;
  const int m0 = blockIdx.x * 64, n0 = blockIdx.y * 64;
  const int kBase = blockIdx.z * kLen;
  const int mm = tid >> 2, kq = tid & 3;
  const int OHW = OH * OW, HW = H * W;
  int m = m0 + mm;
  int mc = (m < M) ? m : 0;
  int bI = mc / OHW; int r = mc - bI * OHW;
  int oh = r / OW;  int ow = r - oh * OW;
  const int ihBase = oh * stride, iwBase = ow * stride;
  const int inBase = bI * Cin * HW;
  const int tm = tid & 15, tn = tid >> 4;
  float acc[4][4] = {};
  for (int k0 = kBase; k0 < kBase + kLen; k0 += 16) {
    __syncthreads();
#pragma unroll
    for (int i = 0; i < 4; ++i) {
      int kk = kq * 4 + i, k = k0 + kk;
      float v = 0.0f;
      if (m < M) {
        int ic = k >> (2 * ls);
        int r2 = k & ((1 << (2 * ls)) - 1);
        int dy = r2 >> ls, dx = r2 & ((1 << ls) - 1);
        v = in[inBase + ic * HW + (ihBase + dy) * W + (iwBase + dx)];
      }
      sA[kk][mm] = v;
    }
#pragma unroll
    for (int i = 0; i < 4; ++i) {
      int kk = kq * 4 + i, k = k0 + kk;
      int n = n0 + mm;
      sB[kk][mm] = (n < N) ? w[n * K + k] : 0.0f;
    }
    __syncthreads();
#pragma unroll
    for (int kk = 0; kk < 16; ++kk) {
      float4 a4 = *(const float4*)&sA[kk][tm * 4];
      float4 b4 = *(const float4*)&sB[kk][tn * 4];
      acc[0][0] += a4.x * b4.x; acc[0][1] += a4.x * b4.y;
      acc[0][2] += a4.x * b4.z; acc[0][3] += a4.x * b4.w;
      acc[1][0] += a4.y * b4.x; acc[1][1] += a4.y * b4.y;
      acc[1][2] += a4.y * b4.z; acc[1][3] += a4.y * b4.w;
      acc[2][0] += a4.z * b4.x; acc[2][1] += a4.z * b4.y;
      acc[2][2] += a4.z * b4.z; acc[2][3] += a4.z * b4.w;
      acc[3][0] += a4.w * b4.x; acc[3][1] += a4.w * b4.y;
      acc[3][2] += a4.w * b4.z; acc[3][3] += a4.w * b4.w;
    }
  }
#pragma unroll
  for (int i = 0; i < 4; ++i) {
    int mI = m0 + tm * 4 + i;
    if (mI < M) {
      int bO = mI / OHW; int rr = mI - bO * OHW;
#pragma unroll
      for (int j = 0; j < 4; ++j) {
        int n = n0 + tn * 4 + j;
        if (n < N)
          atomicAdd(&out[(bO * OHW + rr) * 768 + ch0 + n], acc[i][j] * scale[n]);
      }
    }
  }
}

__global__ void init_b3(float* __restrict__ out, const float* __restrict__ bias) {
  int i = blockIdx.x * 256 + threadIdx.x;
  if (i < 16 * 196 * 256) {
    int n = i & 255, bp = i >> 8;
    out[bp * 768 + 512 + n] = bias[n];
  }
}

// ---------------------------------------------------------------------------
// Fused RegionLayerDW v2 (+ trailing outer GELU).
// Block = 8-row x BWc-col pixel sub-block of one tile (p column-major:
// p = col*8 + row). pw micro-tile = 8 pixels (one column) x 4 outputs
// -> 48B LDS / 32 FMA. Layouts tuned for <=2-way bank aliasing (free):
//   sIn rows padded to PADW (odd/18), sH column-group stride 12 words,
//   sPWT reads are wave-broadcast.
// ---------------------------------------------------------------------------
template<int C, int TH, int TW, int G, int BWc, int MINW>
__global__ __launch_bounds__(256, MINW) void region_k(
    const float* __restrict__ in, const float* __restrict__ dww,
    const float* __restrict__ s1v, const float* __restrict__ b1v,
    const float* __restrict__ pwv, const float* __restrict__ s2v,
    const float* __restrict__ b2v, float* __restrict__ out) {
  constexpr int P = 8 * BWc;               // pixels per block
  constexpr int FULL = G * TH;             // full H (=W)
  constexpr int NBX = TW / BWc;            // sub-blocks per tile, x
  constexpr int PADW = (BWc == 14) ? 17 : 18;  // sIn row pad (conflict-free)
  constexpr int HROW = BWc * 12;           // sH row: 12-word column groups
  static_assert(TH % 8 == 0 && TW % BWc == 0, "tile divisibility");
  __shared__ __align__(16) float sIn[C][10][PADW];
  __shared__ __align__(16) float sH[C][HROW];
  __shared__ __align__(16) float sPWT[C][C];   // transposed: [c][o]
  __shared__ float sDW[C][9];
  __shared__ float sS1[C], sB1[C], sS2[C], sB2[C];
  const int t = blockIdx.x, sb = blockIdx.y, b = blockIdx.z;
  const int gy = t / G, gx = t % G;
  const int py0 = (sb / NBX) * 8, px0 = (sb % NBX) * BWc;  // offset in tile
  const int tid = threadIdx.x;
  // ---- parameter staging
  for (int i = tid; i < C * C; i += 256) {
    int o = i / C, c = i - o * C;
    sPWT[c][o] = pwv[t * C * C + i];
  }
  for (int i = tid; i < C * 9; i += 256) ((float*)sDW)[i] = dww[t * C * 9 + i];
  for (int i = tid; i < C; i += 256) {
    sS1[i] = s1v[t * C + i]; sB1[i] = b1v[t * C + i];
    sS2[i] = s2v[t * C + i]; sB2[i] = b2v[t * C + i];
  }
  // ---- input halo, zeros OUTSIDE the tile (dw conv pads per-tile)
  constexpr int HW2 = 10 * (BWc + 2);
  for (int i = tid; i < C * HW2; i += 256) {
    int c = i / HW2; int rr = i - c * HW2;
    int iy = rr / (BWc + 2), ix = rr - iy * (BWc + 2);
    int ly = py0 + iy - 1, lx = px0 + ix - 1;   // tile coords
    float v = 0.0f;
    if (ly >= 0 && ly < TH && lx >= 0 && lx < TW)
      v = in[((b * C + c) * FULL + gy * TH + ly) * FULL + gx * TW + lx];
    sIn[c][iy][ix] = v;
  }
  __syncthreads();
  // ---- depthwise 3x3 + BN + GELU  (p column-major: col=p>>3, row=p&7)
  for (int i = tid; i < C * P; i += 256) {
    int c = i / P, p = i - c * P;
    int col = p >> 3, row = p & 7;
    float a = 0.0f;
#pragma unroll
    for (int ky = 0; ky < 3; ++ky)
#pragma unroll
      for (int kx = 0; kx < 3; ++kx)
        a += sIn[c][row + ky][col + kx] * sDW[c][ky * 3 + kx];
    sH[c][col * 12 + row] = gelu_f(a * sS1[c] + sB1[c]);
  }
  __syncthreads();
  // ---- pointwise CxC + BN + residual + outer GELU
  // thread = 1 column (8 px) x 4 outputs; og = tid>>4, pg = tid&15
  const int og = tid >> 4, pg = tid & 15;
  if (pg < BWc && og < C / 4) {
    const int o0 = og * 4;
    float acc[4][8] = {};
#pragma unroll 4
    for (int c = 0; c < C; ++c) {
      float4 h0 = *(const float4*)&sH[c][pg * 12];
      float4 h1 = *(const float4*)&sH[c][pg * 12 + 4];
      float4 w4 = *(const float4*)&sPWT[c][o0];
      float hh[8] = {h0.x, h0.y, h0.z, h0.w, h1.x, h1.y, h1.z, h1.w};
      float ww[4] = {w4.x, w4.y, w4.z, w4.w};
#pragma unroll
      for (int j = 0; j < 4; ++j)
#pragma unroll
        for (int e = 0; e < 8; ++e) acc[j][e] += ww[j] * hh[e];
    }
    const int Ybase = gy * TH + py0, X = gx * TW + px0 + pg;
#pragma unroll
    for (int j = 0; j < 4; ++j) {
      int o = o0 + j;
      float s = sS2[o], bb = sB2[o];
#pragma unroll
      for (int e = 0; e < 8; ++e) {
        float v = acc[j][e] * s + bb + sIn[o][e + 1][pg + 1];
        v = gelu_f(v);
        out[((b * C + o) * FULL + Ybase + e) * FULL + X] = v;
      }
    }
  }
}

// ---------------------------------------------------------------------------
extern "C" void kernel_launch(void* const* d_in, const int* in_sizes, int n_in,
                              void* d_out, int out_size, void* d_ws, size_t ws_size,
                              hipStream_t stream) {
  const float* x     = (const float*)d_in[0];
  const float* r1_w  = (const float*)d_in[1];
  const float* r1_s  = (const float*)d_in[2];
  const float* r1_b  = (const float*)d_in[3];
  const float* r1_dw = (const float*)d_in[4];
  const float* r1_s1 = (const float*)d_in[5];
  const float* r1_b1 = (const float*)d_in[6];
  const float* r1_pw = (const float*)d_in[7];
  const float* r1_s2 = (const float*)d_in[8];
  const float* r1_b2 = (const float*)d_in[9];
  const float* r2_w  = (const float*)d_in[10];
  const float* r2_s  = (const float*)d_in[11];
  const float* r2_b  = (const float*)d_in[12];
  const float* r2_dw = (const float*)d_in[13];
  const float* r2_s1 = (const float*)d_in[14];
  const float* r2_b1 = (const float*)d_in[15];
  const float* r2_pw = (const float*)d_in[16];
  const float* r2_s2 = (const float*)d_in[17];
  const float* r2_b2 = (const float*)d_in[18];
  const float* h1_w1 = (const float*)d_in[19];
  const float* h1_s1 = (const float*)d_in[20];
  const float* h1_b1 = (const float*)d_in[21];
  const float* h1_w2 = (const float*)d_in[22];
  const float* h1_s2 = (const float*)d_in[23];
  const float* h1_b2 = (const float*)d_in[24];
  const float* h1_w3 = (const float*)d_in[25];
  const float* h1_s3 = (const float*)d_in[26];
  const float* h1_b3 = (const float*)d_in[27];
  const float* h2_w1 = (const float*)d_in[28];
  const float* h2_s1 = (const float*)d_in[29];
  const float* h2_b1 = (const float*)d_in[30];
  const float* h2_w2 = (const float*)d_in[31];
  const float* h2_s2 = (const float*)d_in[32];
  const float* h2_b2 = (const float*)d_in[33];
  const float* h3_w  = (const float*)d_in[34];
  const float* h3_s  = (const float*)d_in[35];
  const float* h3_b  = (const float*)d_in[36];
  float* out = (float*)d_out;

  // Workspace layout (floats). Peak = 38,535,168 f = 154.2 MB.
  float* R1 = (float*)d_ws;
  float* T1 = R1 + 19267584;
  float* T2 = R1 + 28901376;

  dim3 blk(256);
  const int IMG3  = 3 * 224 * 224;
  const int IMG24 = 24 * 224 * 224;

  // ---- region1 chain, 4-image chunks: conv5(x)->T1, region1(T1)->R1[g]
  for (int g = 0; g < 4; ++g) {
    convgemm_k<true, true, false><<<dim3(3136, 1), blk, 0, stream>>>(
        x + (size_t)g * 4 * IMG3, r1_w, r1_s, r1_b, T1,
        3, 224, 224, 5, 1, 2, 0, 224, 224, 24, 75, 0);
    // C=24, tile 32x32, G=7, sub-block 8x16 -> grid (49, 4*2, 4)
    region_k<24, 32, 32, 7, 16, 4><<<dim3(49, 8, 4), blk, 0, stream>>>(
        T1, r1_dw, r1_s1, r1_b1, r1_pw, r1_s2, r1_b2,
        R1 + (size_t)g * 4 * IMG24);
  }
  // ---- branch2: R1 -> T1 [16,48,56,56] -> out[ch 256:512]
  convgemm_k<false, true, false><<<dim3(784, 1), blk, 0, stream>>>(
      R1, h2_w1, h2_s1, h2_b1, T1, 24, 224, 224, 4, 4, 0, 2, 56, 56, 48, 384, 0);
  convgemm_k<false, false, true><<<dim3(49, 4), blk, 0, stream>>>(
      T1, h2_w2, h2_s2, h2_b2, out, 48, 56, 56, 4, 4, 0, 2, 14, 14, 256, 768, 256);
  // ---- branch1: x -> T1 [16,48,56,56] -> T2 [16,48,28,28] -> out[ch 0:256]
  convgemm_k<false, true, false><<<dim3(784, 1), blk, 0, stream>>>(
      x, h1_w1, h1_s1, h1_b1, T1, 3, 224, 224, 4, 4, 0, 2, 56, 56, 48, 48, 0);
  convgemm_k<false, true, false><<<dim3(196, 1), blk, 0, stream>>>(
      T1, h1_w2, h1_s2, h1_b2, T2, 48, 56, 56, 2, 2, 0, 1, 28, 28, 48, 192, 0);
  convgemm_k<false, false, true><<<dim3(49, 4), blk, 0, stream>>>(
      T2, h1_w3, h1_s3, h1_b3, out, 48, 28, 28, 2, 2, 0, 1, 14, 14, 256, 192, 0);
  // ---- init branch3 slice with bias, then region2 chain + split-K branch3
  init_b3<<<dim3(3136), blk, 0, stream>>>(out, h3_b);
  for (int g = 0; g < 4; ++g) {
    convgemm_k<true, true, false><<<dim3(3136, 1), blk, 0, stream>>>(
        R1 + (size_t)g * 4 * IMG24, r2_w, r2_s, r2_b, T1,
        24, 224, 224, 3, 1, 1, 0, 224, 224, 48, 216, 0);
    // C=48, tile 56x56, G=4, sub-block 8x14 -> grid (16, 7*4, 4)
    region_k<48, 56, 56, 4, 14, 2><<<dim3(16, 28, 4), blk, 0, stream>>>(
        T1, r2_dw, r2_s1, r2_b1, r2_pw, r2_s2, r2_b2, T2);
    convgemm_splitk<<<dim3(13, 4, 16), blk, 0, stream>>>(
        T2, h3_w, h3_s, out + (size_t)g * 4 * 196 * 768,
        48, 224, 224, 16, 4, 14, 14, 256, 12288, 784, 768, 512);
  }
  (void)in_sizes; (void)n_in; (void)out_size; (void)ws_size;
}

// Round 4
// 1675.073 us; speedup vs baseline: 1.6820x; 1.3312x over previous
//
#include <hip/hip_runtime.h>
#include <hip/hip_bf16.h>
#include <math.h>

typedef __attribute__((ext_vector_type(8))) short short8;
typedef __attribute__((ext_vector_type(4))) float f32x4;

__device__ __forceinline__ float gelu_f(float x) {
  return 0.5f * x * (1.0f + erff(x * 0.70710678118654752f));
}

// ---------------------------------------------------------------------------
// Generic conv-as-implicit-GEMM (unchanged from R3 — passing baseline)
// ---------------------------------------------------------------------------
template<bool TBL, bool GELU, bool TOOUT>
__global__ __launch_bounds__(256) void convgemm_k(
    const float* __restrict__ in, const float* __restrict__ w,
    const float* __restrict__ bns, const float* __restrict__ bnb,
    float* __restrict__ out,
    int Cin, int H, int W, int ks, int stride, int pad, int ls,
    int OH, int OW, int N, int K, int ch0) {
  __shared__ __align__(16) float sA[16][64];
  __shared__ __align__(16) float sB[16][64];
  __shared__ int sTbl[256];
  const int tid = threadIdx.x;
  if (TBL) {
    int kk2 = ks * ks;
    for (int k = tid; k < K; k += 256) {
      int ic = k / kk2, r = k - ic * kk2;
      sTbl[k] = (ic << 16) | ((r / ks) << 8) | (r % ks);
    }
  }
  const int m0 = blockIdx.x * 64, n0 = blockIdx.y * 64;
  const int mm = tid >> 2, kq = tid & 3;
  const int OHW = OH * OW, HW = H * W;
  int m = m0 + mm;
  int bI = m / OHW; int r = m - bI * OHW;
  int oh = r / OW;  int ow = r - oh * OW;
  const int ihBase = oh * stride - pad, iwBase = ow * stride - pad;
  const int inBase = bI * Cin * HW;
  const int tm = tid & 15, tn = tid >> 4;
  float acc[4][4] = {};
  for (int k0 = 0; k0 < K; k0 += 16) {
    __syncthreads();
#pragma unroll
    for (int i = 0; i < 4; ++i) {
      int kk = kq * 4 + i, k = k0 + kk;
      float v = 0.0f;
      if (k < K) {
        int ic, dy, dx;
        if (TBL) {
          int tv = sTbl[k]; ic = tv >> 16; dy = (tv >> 8) & 255; dx = tv & 255;
        } else {
          ic = k >> (2 * ls);
          int r2 = k & ((1 << (2 * ls)) - 1);
          dy = r2 >> ls; dx = r2 & ((1 << ls) - 1);
        }
        int ih = ihBase + dy, iw = iwBase + dx;
        if (ih >= 0 && ih < H && iw >= 0 && iw < W)
          v = in[inBase + ic * HW + ih * W + iw];
      }
      sA[kk][mm] = v;
    }
#pragma unroll
    for (int i = 0; i < 4; ++i) {
      int kk = kq * 4 + i, k = k0 + kk;
      int n = n0 + mm;
      float v = 0.0f;
      if (n < N && k < K) v = w[n * K + k];
      sB[kk][mm] = v;
    }
    __syncthreads();
#pragma unroll
    for (int kk = 0; kk < 16; ++kk) {
      float4 a4 = *(const float4*)&sA[kk][tm * 4];
      float4 b4 = *(const float4*)&sB[kk][tn * 4];
      acc[0][0] += a4.x * b4.x; acc[0][1] += a4.x * b4.y;
      acc[0][2] += a4.x * b4.z; acc[0][3] += a4.x * b4.w;
      acc[1][0] += a4.y * b4.x; acc[1][1] += a4.y * b4.y;
      acc[1][2] += a4.y * b4.z; acc[1][3] += a4.y * b4.w;
      acc[2][0] += a4.z * b4.x; acc[2][1] += a4.z * b4.y;
      acc[2][2] += a4.z * b4.z; acc[2][3] += a4.z * b4.w;
      acc[3][0] += a4.w * b4.x; acc[3][1] += a4.w * b4.y;
      acc[3][2] += a4.w * b4.z; acc[3][3] += a4.w * b4.w;
    }
  }
#pragma unroll
  for (int i = 0; i < 4; ++i) {
    int mI = m0 + tm * 4 + i;
    int bO = mI / OHW; int rr = mI - bO * OHW;
#pragma unroll
    for (int j = 0; j < 4; ++j) {
      int n = n0 + tn * 4 + j;
      if (n < N) {
        float v = acc[i][j] * bns[n] + bnb[n];
        if (GELU) v = gelu_f(v);
        if (TOOUT) {
          out[(bO * OHW + rr) * 768 + ch0 + n] = v;  // OHW==196
        } else {
          int oh2 = rr / OW, ow2 = rr - oh2 * OW;
          out[((bO * N + n) * OH + oh2) * OW + ow2] = v;
        }
      }
    }
  }
}

// ---------------------------------------------------------------------------
// branch3 as bf16 MFMA GEMM, split-K atomic.
//  A: region2 chunk [4,48,224,224] bf16 (NCHW). k = ic*256 + dy*16 + dx.
//  W: [256, 12288] bf16 (converted). C[m,n] += sum_k A[m,k]*W[n,k].
//  BM=BN=64, BK=64, 4 waves x (2x2 frags of 16x16x32). SPLIT=8 (kslice 1536).
//  LDS XOR-8 column-group swizzle -> conflict-free ds_read_b128.
// ---------------------------------------------------------------------------
__global__ __launch_bounds__(256) void b3_mfma(
    const __hip_bfloat16* __restrict__ A, const __hip_bfloat16* __restrict__ Wb,
    const float* __restrict__ scale, float* __restrict__ out, int M) {
  constexpr int K = 12288, KSL = 1536;  // split 8
  __shared__ __align__(16) __hip_bfloat16 sA[64][64];
  __shared__ __align__(16) __hip_bfloat16 sB[64][64];
  const int tid = threadIdx.x;
  const int m0 = blockIdx.x * 64, n0 = blockIdx.y * 64;
  const int kBase = blockIdx.z * KSL;
  // staging: thread -> (mi 0..63, seg 0..3); seg = 16 k's (one dy row)
  const int mi = tid >> 2, seg = tid & 3;
  int m = m0 + mi; int mc = (m < M) ? m : (M - 1);
  int bI = mc / 196; int r = mc - bI * 196;
  int oh = r / 14, ow = r - oh * 14;
  const __hip_bfloat16* Abase =
      A + (size_t)bI * 48 * 50176 + (size_t)(oh * 16) * 224 + ow * 16;
  const __hip_bfloat16* Wrow = Wb + (size_t)(n0 + mi) * K;
  // compute mapping
  const int wave = tid >> 6, lane = tid & 63;
  const int wm = (wave & 1) * 32, wn = (wave >> 1) * 32;
  const int fm = lane & 15, quad = lane >> 4;
  const int sw = fm & 7;  // xor key for frag reads
  f32x4 acc[2][2] = {};
  for (int k0 = kBase; k0 < kBase + KSL; k0 += 64) {
    int ic = k0 >> 8, dy0 = (k0 >> 4) & 15;
    __syncthreads();
    {  // stage A: row mi, k in [seg*16, seg*16+16) -> column groups seg*2, seg*2+1
      const __hip_bfloat16* p = Abase + (size_t)ic * 50176 + (dy0 + seg) * 224;
      float4 v0 = *(const float4*)p;
      float4 v1 = *(const float4*)(p + 8);
      int key = mi & 7;
      *(float4*)&sA[mi][((seg * 2) ^ key) * 8] = v0;
      *(float4*)&sA[mi][((seg * 2 + 1) ^ key) * 8] = v1;
      const __hip_bfloat16* q = Wrow + k0 + seg * 16;
      float4 w0 = *(const float4*)q;
      float4 w1 = *(const float4*)(q + 8);
      *(float4*)&sB[mi][((seg * 2) ^ key) * 8] = w0;
      *(float4*)&sB[mi][((seg * 2 + 1) ^ key) * 8] = w1;
    }
    __syncthreads();
#pragma unroll
    for (int ks = 0; ks < 2; ++ks) {
      int cg = (ks * 4 + quad) ^ sw;
#pragma unroll
      for (int i = 0; i < 2; ++i) {
        short8 a = *(const short8*)&sA[wm + i * 16 + fm][cg * 8];
#pragma unroll
        for (int j = 0; j < 2; ++j) {
          short8 b = *(const short8*)&sB[wn + j * 16 + fm][cg * 8];
          acc[i][j] = __builtin_amdgcn_mfma_f32_16x16x32_bf16(a, b, acc[i][j], 0, 0, 0);
        }
      }
    }
  }
  // epilogue: C row = quad*4+reg (m), col = fm (n); atomic add acc*scale
#pragma unroll
  for (int i = 0; i < 2; ++i) {
#pragma unroll
    for (int j = 0; j < 2; ++j) {
      int gn = n0 + wn + j * 16 + fm;
      float sc = scale[gn];
#pragma unroll
      for (int e = 0; e < 4; ++e) {
        int gm = m0 + wm + i * 16 + quad * 4 + e;
        if (gm < M)
          atomicAdd(&out[(size_t)gm * 768 + 512 + gn], acc[i][j][e] * sc);
      }
    }
  }
}

__global__ void init_b3(float* __restrict__ out, const float* __restrict__ bias) {
  int i = blockIdx.x * 256 + threadIdx.x;
  if (i < 16 * 196 * 256) {
    int n = i & 255, bp = i >> 8;
    out[bp * 768 + 512 + n] = bias[n];
  }
}

__global__ void f2bf_k(const float* __restrict__ in, __hip_bfloat16* __restrict__ o, int n) {
  int i = blockIdx.x * 256 + threadIdx.x;
  if (i < n) o[i] = (__hip_bfloat16)in[i];
}

// ---------------------------------------------------------------------------
// Fused RegionLayerDW v2 (R3 version + output-type template)
// ---------------------------------------------------------------------------
template<int C, int TH, int TW, int G, int BWc, int MINW, typename OutT>
__global__ __launch_bounds__(256, MINW) void region_k(
    const float* __restrict__ in, const float* __restrict__ dww,
    const float* __restrict__ s1v, const float* __restrict__ b1v,
    const float* __restrict__ pwv, const float* __restrict__ s2v,
    const float* __restrict__ b2v, OutT* __restrict__ out) {
  constexpr int P = 8 * BWc;
  constexpr int FULL = G * TH;
  constexpr int NBX = TW / BWc;
  constexpr int PADW = (BWc == 14) ? 17 : 18;
  constexpr int HROW = BWc * 12;
  static_assert(TH % 8 == 0 && TW % BWc == 0, "tile divisibility");
  __shared__ __align__(16) float sIn[C][10][PADW];
  __shared__ __align__(16) float sH[C][HROW];
  __shared__ __align__(16) float sPWT[C][C];
  __shared__ float sDW[C][9];
  __shared__ float sS1[C], sB1[C], sS2[C], sB2[C];
  const int t = blockIdx.x, sb = blockIdx.y, b = blockIdx.z;
  const int gy = t / G, gx = t % G;
  const int py0 = (sb / NBX) * 8, px0 = (sb % NBX) * BWc;
  const int tid = threadIdx.x;
  for (int i = tid; i < C * C; i += 256) {
    int o = i / C, c = i - o * C;
    sPWT[c][o] = pwv[t * C * C + i];
  }
  for (int i = tid; i < C * 9; i += 256) ((float*)sDW)[i] = dww[t * C * 9 + i];
  for (int i = tid; i < C; i += 256) {
    sS1[i] = s1v[t * C + i]; sB1[i] = b1v[t * C + i];
    sS2[i] = s2v[t * C + i]; sB2[i] = b2v[t * C + i];
  }
  constexpr int HW2 = 10 * (BWc + 2);
  for (int i = tid; i < C * HW2; i += 256) {
    int c = i / HW2; int rr = i - c * HW2;
    int iy = rr / (BWc + 2), ix = rr - iy * (BWc + 2);
    int ly = py0 + iy - 1, lx = px0 + ix - 1;
    float v = 0.0f;
    if (ly >= 0 && ly < TH && lx >= 0 && lx < TW)
      v = in[((b * C + c) * FULL + gy * TH + ly) * FULL + gx * TW + lx];
    sIn[c][iy][ix] = v;
  }
  __syncthreads();
  for (int i = tid; i < C * P; i += 256) {
    int c = i / P, p = i - c * P;
    int col = p >> 3, row = p & 7;
    float a = 0.0f;
#pragma unroll
    for (int ky = 0; ky < 3; ++ky)
#pragma unroll
      for (int kx = 0; kx < 3; ++kx)
        a += sIn[c][row + ky][col + kx] * sDW[c][ky * 3 + kx];
    sH[c][col * 12 + row] = gelu_f(a * sS1[c] + sB1[c]);
  }
  __syncthreads();
  const int og = tid >> 4, pg = tid & 15;
  if (pg < BWc && og < C / 4) {
    const int o0 = og * 4;
    float acc[4][8] = {};
#pragma unroll 4
    for (int c = 0; c < C; ++c) {
      float4 h0 = *(const float4*)&sH[c][pg * 12];
      float4 h1 = *(const float4*)&sH[c][pg * 12 + 4];
      float4 w4 = *(const float4*)&sPWT[c][o0];
      float hh[8] = {h0.x, h0.y, h0.z, h0.w, h1.x, h1.y, h1.z, h1.w};
      float ww[4] = {w4.x, w4.y, w4.z, w4.w};
#pragma unroll
      for (int j = 0; j < 4; ++j)
#pragma unroll
        for (int e = 0; e < 8; ++e) acc[j][e] += ww[j] * hh[e];
    }
    const int Ybase = gy * TH + py0, X = gx * TW + px0 + pg;
#pragma unroll
    for (int j = 0; j < 4; ++j) {
      int o = o0 + j;
      float s = sS2[o], bb = sB2[o];
#pragma unroll
      for (int e = 0; e < 8; ++e) {
        float v = acc[j][e] * s + bb + sIn[o][e + 1][pg + 1];
        v = gelu_f(v);
        out[((size_t)(b * C + o) * FULL + Ybase + e) * FULL + X] = (OutT)v;
      }
    }
  }
}

// ---------------------------------------------------------------------------
extern "C" void kernel_launch(void* const* d_in, const int* in_sizes, int n_in,
                              void* d_out, int out_size, void* d_ws, size_t ws_size,
                              hipStream_t stream) {
  const float* x     = (const float*)d_in[0];
  const float* r1_w  = (const float*)d_in[1];
  const float* r1_s  = (const float*)d_in[2];
  const float* r1_b  = (const float*)d_in[3];
  const float* r1_dw = (const float*)d_in[4];
  const float* r1_s1 = (const float*)d_in[5];
  const float* r1_b1 = (const float*)d_in[6];
  const float* r1_pw = (const float*)d_in[7];
  const float* r1_s2 = (const float*)d_in[8];
  const float* r1_b2 = (const float*)d_in[9];
  const float* r2_w  = (const float*)d_in[10];
  const float* r2_s  = (const float*)d_in[11];
  const float* r2_b  = (const float*)d_in[12];
  const float* r2_dw = (const float*)d_in[13];
  const float* r2_s1 = (const float*)d_in[14];
  const float* r2_b1 = (const float*)d_in[15];
  const float* r2_pw = (const float*)d_in[16];
  const float* r2_s2 = (const float*)d_in[17];
  const float* r2_b2 = (const float*)d_in[18];
  const float* h1_w1 = (const float*)d_in[19];
  const float* h1_s1 = (const float*)d_in[20];
  const float* h1_b1 = (const float*)d_in[21];
  const float* h1_w2 = (const float*)d_in[22];
  const float* h1_s2 = (const float*)d_in[23];
  const float* h1_b2 = (const float*)d_in[24];
  const float* h1_w3 = (const float*)d_in[25];
  const float* h1_s3 = (const float*)d_in[26];
  const float* h1_b3 = (const float*)d_in[27];
  const float* h2_w1 = (const float*)d_in[28];
  const float* h2_s1 = (const float*)d_in[29];
  const float* h2_b1 = (const float*)d_in[30];
  const float* h2_w2 = (const float*)d_in[31];
  const float* h2_s2 = (const float*)d_in[32];
  const float* h2_b2 = (const float*)d_in[33];
  const float* h3_w  = (const float*)d_in[34];
  const float* h3_s  = (const float*)d_in[35];
  const float* h3_b  = (const float*)d_in[36];
  float* out = (float*)d_out;

  // Workspace (float offsets). Peak 35,291,136 f = 141.2 MB (< proven 154.2).
  //   R1  fp32 region1 [16,24,224,224] @ 0          (19,267,584 f)
  //   T1  fp32 temp    [4,48,224,224]  @ 19,267,584 ( 9,633,792 f)
  //   T2b bf16 region2 [4,48,224,224]  @ 28,901,376 ( 4,816,896 f-slots)
  //   h3wb bf16 [256,12288]            @ 33,718,272 ( 1,572,864 f-slots)
  float* R1 = (float*)d_ws;
  float* T1 = R1 + 19267584;
  __hip_bfloat16* T2b = (__hip_bfloat16*)(R1 + 28901376);
  __hip_bfloat16* h3wb = (__hip_bfloat16*)(R1 + 33718272);
  float* S1 = T1;                 // branch temps alias T1 (free between loops)
  float* S2 = T1 + 2408448;

  dim3 blk(256);
  const int IMG3  = 3 * 224 * 224;
  const int IMG24 = 24 * 224 * 224;

  // weight conversion for branch3
  f2bf_k<<<dim3((3145728 + 255) / 256), blk, 0, stream>>>(h3_w, h3wb, 3145728);

  // ---- region1 chain, 4-image chunks
  for (int g = 0; g < 4; ++g) {
    convgemm_k<true, true, false><<<dim3(3136, 1), blk, 0, stream>>>(
        x + (size_t)g * 4 * IMG3, r1_w, r1_s, r1_b, T1,
        3, 224, 224, 5, 1, 2, 0, 224, 224, 24, 75, 0);
    region_k<24, 32, 32, 7, 16, 4, float><<<dim3(49, 8, 4), blk, 0, stream>>>(
        T1, r1_dw, r1_s1, r1_b1, r1_pw, r1_s2, r1_b2,
        R1 + (size_t)g * 4 * IMG24);
  }
  // ---- branch2: R1 -> S1 [16,48,56,56] -> out[ch 256:512]
  convgemm_k<false, true, false><<<dim3(784, 1), blk, 0, stream>>>(
      R1, h2_w1, h2_s1, h2_b1, S1, 24, 224, 224, 4, 4, 0, 2, 56, 56, 48, 384, 0);
  convgemm_k<false, false, true><<<dim3(49, 4), blk, 0, stream>>>(
      S1, h2_w2, h2_s2, h2_b2, out, 48, 56, 56, 4, 4, 0, 2, 14, 14, 256, 768, 256);
  // ---- branch1: x -> S1 -> S2 -> out[ch 0:256]
  convgemm_k<false, true, false><<<dim3(784, 1), blk, 0, stream>>>(
      x, h1_w1, h1_s1, h1_b1, S1, 3, 224, 224, 4, 4, 0, 2, 56, 56, 48, 48, 0);
  convgemm_k<false, true, false><<<dim3(196, 1), blk, 0, stream>>>(
      S1, h1_w2, h1_s2, h1_b2, S2, 48, 56, 56, 2, 2, 0, 1, 28, 28, 48, 192, 0);
  convgemm_k<false, false, true><<<dim3(49, 4), blk, 0, stream>>>(
      S2, h1_w3, h1_s3, h1_b3, out, 48, 28, 28, 2, 2, 0, 1, 14, 14, 256, 192, 0);
  // ---- branch3: init bias, then per-chunk conv3x3 -> region2(bf16) -> MFMA
  init_b3<<<dim3(3136), blk, 0, stream>>>(out, h3_b);
  for (int g = 0; g < 4; ++g) {
    convgemm_k<true, true, false><<<dim3(3136, 1), blk, 0, stream>>>(
        R1 + (size_t)g * 4 * IMG24, r2_w, r2_s, r2_b, T1,
        24, 224, 224, 3, 1, 1, 0, 224, 224, 48, 216, 0);
    region_k<48, 56, 56, 4, 14, 2, __hip_bfloat16><<<dim3(16, 28, 4), blk, 0, stream>>>(
        T1, r2_dw, r2_s1, r2_b1, r2_pw, r2_s2, r2_b2, T2b);
    b3_mfma<<<dim3(13, 4, 8), blk, 0, stream>>>(
        T2b, h3wb, h3_s, out + (size_t)g * 4 * 196 * 768, 784);
  }
  (void)in_sizes; (void)n_in; (void)out_size; (void)ws_size;
}

// Round 5
// 1314.543 us; speedup vs baseline: 2.1433x; 1.2743x over previous
//
#include <hip/hip_runtime.h>
#include <hip/hip_bf16.h>
#include <math.h>

typedef __attribute__((ext_vector_type(8))) short short8;
typedef __attribute__((ext_vector_type(4))) float f32x4;

__device__ __forceinline__ float gelu_f(float x) {
  return 0.5f * x * (1.0f + erff(x * 0.70710678118654752f));
}

// ---------------------------------------------------------------------------
// Generic conv-as-implicit-GEMM fp32 (unchanged — used for conv5x5, branch1,
// branch2 conv2)
// ---------------------------------------------------------------------------
template<bool TBL, bool GELU, bool TOOUT>
__global__ __launch_bounds__(256) void convgemm_k(
    const float* __restrict__ in, const float* __restrict__ w,
    const float* __restrict__ bns, const float* __restrict__ bnb,
    float* __restrict__ out,
    int Cin, int H, int W, int ks, int stride, int pad, int ls,
    int OH, int OW, int N, int K, int ch0) {
  __shared__ __align__(16) float sA[16][64];
  __shared__ __align__(16) float sB[16][64];
  __shared__ int sTbl[256];
  const int tid = threadIdx.x;
  if (TBL) {
    int kk2 = ks * ks;
    for (int k = tid; k < K; k += 256) {
      int ic = k / kk2, r = k - ic * kk2;
      sTbl[k] = (ic << 16) | ((r / ks) << 8) | (r % ks);
    }
  }
  const int m0 = blockIdx.x * 64, n0 = blockIdx.y * 64;
  const int mm = tid >> 2, kq = tid & 3;
  const int OHW = OH * OW, HW = H * W;
  int m = m0 + mm;
  int bI = m / OHW; int r = m - bI * OHW;
  int oh = r / OW;  int ow = r - oh * OW;
  const int ihBase = oh * stride - pad, iwBase = ow * stride - pad;
  const int inBase = bI * Cin * HW;
  const int tm = tid & 15, tn = tid >> 4;
  float acc[4][4] = {};
  for (int k0 = 0; k0 < K; k0 += 16) {
    __syncthreads();
#pragma unroll
    for (int i = 0; i < 4; ++i) {
      int kk = kq * 4 + i, k = k0 + kk;
      float v = 0.0f;
      if (k < K) {
        int ic, dy, dx;
        if (TBL) {
          int tv = sTbl[k]; ic = tv >> 16; dy = (tv >> 8) & 255; dx = tv & 255;
        } else {
          ic = k >> (2 * ls);
          int r2 = k & ((1 << (2 * ls)) - 1);
          dy = r2 >> ls; dx = r2 & ((1 << ls) - 1);
        }
        int ih = ihBase + dy, iw = iwBase + dx;
        if (ih >= 0 && ih < H && iw >= 0 && iw < W)
          v = in[inBase + ic * HW + ih * W + iw];
      }
      sA[kk][mm] = v;
    }
#pragma unroll
    for (int i = 0; i < 4; ++i) {
      int kk = kq * 4 + i, k = k0 + kk;
      int n = n0 + mm;
      float v = 0.0f;
      if (n < N && k < K) v = w[n * K + k];
      sB[kk][mm] = v;
    }
    __syncthreads();
#pragma unroll
    for (int kk = 0; kk < 16; ++kk) {
      float4 a4 = *(const float4*)&sA[kk][tm * 4];
      float4 b4 = *(const float4*)&sB[kk][tn * 4];
      acc[0][0] += a4.x * b4.x; acc[0][1] += a4.x * b4.y;
      acc[0][2] += a4.x * b4.z; acc[0][3] += a4.x * b4.w;
      acc[1][0] += a4.y * b4.x; acc[1][1] += a4.y * b4.y;
      acc[1][2] += a4.y * b4.z; acc[1][3] += a4.y * b4.w;
      acc[2][0] += a4.z * b4.x; acc[2][1] += a4.z * b4.y;
      acc[2][2] += a4.z * b4.z; acc[2][3] += a4.z * b4.w;
      acc[3][0] += a4.w * b4.x; acc[3][1] += a4.w * b4.y;
      acc[3][2] += a4.w * b4.z; acc[3][3] += a4.w * b4.w;
    }
  }
#pragma unroll
  for (int i = 0; i < 4; ++i) {
    int mI = m0 + tm * 4 + i;
    int bO = mI / OHW; int rr = mI - bO * OHW;
#pragma unroll
    for (int j = 0; j < 4; ++j) {
      int n = n0 + tn * 4 + j;
      if (n < N) {
        float v = acc[i][j] * bns[n] + bnb[n];
        if (GELU) v = gelu_f(v);
        if (TOOUT) {
          out[(bO * OHW + rr) * 768 + ch0 + n] = v;  // OHW==196
        } else {
          int oh2 = rr / OW, ow2 = rr - oh2 * OW;
          out[((bO * N + n) * OH + oh2) * OW + ow2] = v;
        }
      }
    }
  }
}

// ---------------------------------------------------------------------------
// NHWC bf16 implicit-GEMM conv via MFMA. Input [B,H,W,CIN] bf16; im2col rows
// are per-dy contiguous runs of KS*CIN bf16. Whole K resident in LDS.
// BM=64 (4 waves x 16 m), N = NN (NN/16 n-frags per wave). KP = K padded
// to 32. Weights pre-reordered: wb[n][(dy*KS+dx)*CIN+ic], KP-padded.
// Epilogue: BN (+GELU), NCHW fp32 float4 store (4 consecutive pixels/lane).
// ---------------------------------------------------------------------------
template<int CIN, int KS, int STRIDE, int PAD, int NN, int KP, bool GELU>
__global__ __launch_bounds__(256) void nhwc_conv_mfma(
    const __hip_bfloat16* __restrict__ in, const __hip_bfloat16* __restrict__ wb,
    const float* __restrict__ bns, const float* __restrict__ bnb,
    float* __restrict__ out, int Hin, int Win, int OW, int OHW) {
  constexpr int K = KS * KS * CIN;
  constexpr int LROW = KP + 8;               // +8 bf16 row pad (bank spread)
  __shared__ __align__(16) __hip_bfloat16 sA[64][LROW];
  __shared__ __align__(16) __hip_bfloat16 sB[NN][LROW];
  const int tid = threadIdx.x;
  const float4 f4z = make_float4(0.f, 0.f, 0.f, 0.f);
  // ---- stage A: task = (m = tid&63, dy = tid>>6)
  {
    const int m = tid & 63, dy = tid >> 6;
    const int mg = blockIdx.x * 64 + m;
    const int bI = mg / OHW; int pix = mg - bI * OHW;
    const int oh = pix / OW, ow = pix - oh * OW;
    if (dy < KS) {
      const int ih = oh * STRIDE - PAD + dy;
      __hip_bfloat16* dst = &sA[m][dy * KS * CIN];
      if (ih < 0 || ih >= Hin) {
#pragma unroll
        for (int i = 0; i < KS * CIN / 8; ++i) ((float4*)dst)[i] = f4z;
      } else {
        const __hip_bfloat16* srow = in + ((size_t)bI * Hin + ih) * Win * CIN;
#pragma unroll
        for (int j = 0; j < KS; ++j) {
          int iw = ow * STRIDE - PAD + j;
          if (PAD > 0 && (iw < 0 || iw >= Win)) {
#pragma unroll
            for (int i = 0; i < CIN / 8; ++i) ((float4*)(dst + j * CIN))[i] = f4z;
          } else {
            const float4* s4 = (const float4*)(srow + (size_t)iw * CIN);
#pragma unroll
            for (int i = 0; i < CIN / 8; ++i) ((float4*)(dst + j * CIN))[i] = s4[i];
          }
        }
      }
    } else if (K < KP) {
      // only reached when KS==3 (tids 192..255 cover every m once)
#pragma unroll
      for (int c = K; c < KP + 8; c += 8) *(float4*)&sA[m][c] = f4z;
    }
  }
  // ---- stage B: straight copy of KP-padded weight rows
  {
    constexpr int NV = NN * KP / 8;
    const float4* w4 = (const float4*)wb;
    for (int i = tid; i < NV; i += 256) {
      int n = i / (KP / 8), c = i - n * (KP / 8);
      *(float4*)&sB[n][c * 8] = w4[i];
    }
  }
  __syncthreads();
  // ---- MFMA over KP/32 k-steps
  constexpr int NT = NN / 16;
  const int wave = tid >> 6, lane = tid & 63;
  const int fm = lane & 15, quad = lane >> 4;
  const int wm = wave * 16;
  f32x4 acc[NT] = {};
#pragma unroll
  for (int ks = 0; ks < KP / 32; ++ks) {
    short8 a = *(const short8*)&sA[wm + fm][ks * 32 + quad * 8];
#pragma unroll
    for (int j = 0; j < NT; ++j) {
      short8 b = *(const short8*)&sB[j * 16 + fm][ks * 32 + quad * 8];
      acc[j] = __builtin_amdgcn_mfma_f32_16x16x32_bf16(a, b, acc[j], 0, 0, 0);
    }
  }
  // ---- epilogue: n = j*16+fm, m = wm + quad*4 + e (4 consecutive pixels)
  const int mg0 = blockIdx.x * 64 + wm + quad * 4;
  const int bI = mg0 / OHW, pix = mg0 - bI * OHW;
#pragma unroll
  for (int j = 0; j < NT; ++j) {
    int n = j * 16 + fm;
    float s = bns[n], bb = bnb[n];
    float4 v;
    v.x = acc[j][0] * s + bb; v.y = acc[j][1] * s + bb;
    v.z = acc[j][2] * s + bb; v.w = acc[j][3] * s + bb;
    if (GELU) { v.x = gelu_f(v.x); v.y = gelu_f(v.y); v.z = gelu_f(v.z); v.w = gelu_f(v.w); }
    *(float4*)&out[((size_t)(bI * NN + n)) * OHW + pix] = v;
  }
}

// ---------------------------------------------------------------------------
// branch3 bf16 MFMA GEMM, split-K atomic (unchanged from R4 — validated)
// ---------------------------------------------------------------------------
__global__ __launch_bounds__(256) void b3_mfma(
    const __hip_bfloat16* __restrict__ A, const __hip_bfloat16* __restrict__ Wb,
    const float* __restrict__ scale, float* __restrict__ out, int M) {
  constexpr int K = 12288, KSL = 1536;  // split 8
  __shared__ __align__(16) __hip_bfloat16 sA[64][64];
  __shared__ __align__(16) __hip_bfloat16 sB[64][64];
  const int tid = threadIdx.x;
  const int m0 = blockIdx.x * 64, n0 = blockIdx.y * 64;
  const int kBase = blockIdx.z * KSL;
  const int mi = tid >> 2, seg = tid & 3;
  int m = m0 + mi; int mc = (m < M) ? m : (M - 1);
  int bI = mc / 196; int r = mc - bI * 196;
  int oh = r / 14, ow = r - oh * 14;
  const __hip_bfloat16* Abase =
      A + (size_t)bI * 48 * 50176 + (size_t)(oh * 16) * 224 + ow * 16;
  const __hip_bfloat16* Wrow = Wb + (size_t)(n0 + mi) * K;
  const int wave = tid >> 6, lane = tid & 63;
  const int wm = (wave & 1) * 32, wn = (wave >> 1) * 32;
  const int fm = lane & 15, quad = lane >> 4;
  const int sw = fm & 7;
  f32x4 acc[2][2] = {};
  for (int k0 = kBase; k0 < kBase + KSL; k0 += 64) {
    int ic = k0 >> 8, dy0 = (k0 >> 4) & 15;
    __syncthreads();
    {
      const __hip_bfloat16* p = Abase + (size_t)ic * 50176 + (dy0 + seg) * 224;
      float4 v0 = *(const float4*)p;
      float4 v1 = *(const float4*)(p + 8);
      int key = mi & 7;
      *(float4*)&sA[mi][((seg * 2) ^ key) * 8] = v0;
      *(float4*)&sA[mi][((seg * 2 + 1) ^ key) * 8] = v1;
      const __hip_bfloat16* q = Wrow + k0 + seg * 16;
      float4 w0 = *(const float4*)q;
      float4 w1 = *(const float4*)(q + 8);
      *(float4*)&sB[mi][((seg * 2) ^ key) * 8] = w0;
      *(float4*)&sB[mi][((seg * 2 + 1) ^ key) * 8] = w1;
    }
    __syncthreads();
#pragma unroll
    for (int ks = 0; ks < 2; ++ks) {
      int cg = (ks * 4 + quad) ^ sw;
#pragma unroll
      for (int i = 0; i < 2; ++i) {
        short8 a = *(const short8*)&sA[wm + i * 16 + fm][cg * 8];
#pragma unroll
        for (int j = 0; j < 2; ++j) {
          short8 b = *(const short8*)&sB[wn + j * 16 + fm][cg * 8];
          acc[i][j] = __builtin_amdgcn_mfma_f32_16x16x32_bf16(a, b, acc[i][j], 0, 0, 0);
        }
      }
    }
  }
#pragma unroll
  for (int i = 0; i < 2; ++i) {
#pragma unroll
    for (int j = 0; j < 2; ++j) {
      int gn = n0 + wn + j * 16 + fm;
      float sc = scale[gn];
#pragma unroll
      for (int e = 0; e < 4; ++e) {
        int gm = m0 + wm + i * 16 + quad * 4 + e;
        if (gm < M)
          atomicAdd(&out[(size_t)gm * 768 + 512 + gn], acc[i][j][e] * sc);
      }
    }
  }
}

__global__ void init_b3(float* __restrict__ out, const float* __restrict__ bias) {
  int i = blockIdx.x * 256 + threadIdx.x;
  if (i < 16 * 196 * 256) {
    int n = i & 255, bp = i >> 8;
    out[bp * 768 + 512 + n] = bias[n];
  }
}

__global__ void f2bf_k(const float* __restrict__ in, __hip_bfloat16* __restrict__ o, int n) {
  int i = blockIdx.x * 256 + threadIdx.x;
  if (i < n) o[i] = (__hip_bfloat16)in[i];
}

// OIHW fp32 -> [N][KP] bf16 with k=(dy*ks+dx)*Cin+ic, zero-padded to KP
__global__ void reorder_w_k(const float* __restrict__ w, __hip_bfloat16* __restrict__ o,
                            int N, int Cin, int ks, int KP) {
  int i = blockIdx.x * 256 + threadIdx.x;
  if (i >= N * KP) return;
  int n = i / KP, k = i - n * KP;
  float v = 0.f;
  int K = ks * ks * Cin;
  if (k < K) {
    int dy = k / (ks * Cin); int r = k - dy * ks * Cin;
    int dx = r / Cin, ic = r - dx * Cin;
    v = w[((n * Cin + ic) * ks + dy) * ks + dx];
  }
  o[i] = (__hip_bfloat16)v;
}

// ---------------------------------------------------------------------------
// Fused RegionLayerDW (R4 version + NHWC-bf16 store option)
// ---------------------------------------------------------------------------
template<int C, int TH, int TW, int G, int BWc, int MINW, bool NHWC, typename OutT>
__global__ __launch_bounds__(256, MINW) void region_k(
    const float* __restrict__ in, const float* __restrict__ dww,
    const float* __restrict__ s1v, const float* __restrict__ b1v,
    const float* __restrict__ pwv, const float* __restrict__ s2v,
    const float* __restrict__ b2v, OutT* __restrict__ out) {
  constexpr int P = 8 * BWc;
  constexpr int FULL = G * TH;
  constexpr int NBX = TW / BWc;
  constexpr int PADW = (BWc == 14) ? 17 : 18;
  constexpr int HROW = BWc * 12;
  static_assert(TH % 8 == 0 && TW % BWc == 0, "tile divisibility");
  __shared__ __align__(16) float sIn[C][10][PADW];
  __shared__ __align__(16) float sH[C][HROW];
  __shared__ __align__(16) float sPWT[C][C];
  __shared__ float sDW[C][9];
  __shared__ float sS1[C], sB1[C], sS2[C], sB2[C];
  const int t = blockIdx.x, sb = blockIdx.y, b = blockIdx.z;
  const int gy = t / G, gx = t % G;
  const int py0 = (sb / NBX) * 8, px0 = (sb % NBX) * BWc;
  const int tid = threadIdx.x;
  for (int i = tid; i < C * C; i += 256) {
    int o = i / C, c = i - o * C;
    sPWT[c][o] = pwv[t * C * C + i];
  }
  for (int i = tid; i < C * 9; i += 256) ((float*)sDW)[i] = dww[t * C * 9 + i];
  for (int i = tid; i < C; i += 256) {
    sS1[i] = s1v[t * C + i]; sB1[i] = b1v[t * C + i];
    sS2[i] = s2v[t * C + i]; sB2[i] = b2v[t * C + i];
  }
  constexpr int HW2 = 10 * (BWc + 2);
  for (int i = tid; i < C * HW2; i += 256) {
    int c = i / HW2; int rr = i - c * HW2;
    int iy = rr / (BWc + 2), ix = rr - iy * (BWc + 2);
    int ly = py0 + iy - 1, lx = px0 + ix - 1;
    float v = 0.0f;
    if (ly >= 0 && ly < TH && lx >= 0 && lx < TW)
      v = in[((b * C + c) * FULL + gy * TH + ly) * FULL + gx * TW + lx];
    sIn[c][iy][ix] = v;
  }
  __syncthreads();
  for (int i = tid; i < C * P; i += 256) {
    int c = i / P, p = i - c * P;
    int col = p >> 3, row = p & 7;
    float a = 0.0f;
#pragma unroll
    for (int ky = 0; ky < 3; ++ky)
#pragma unroll
      for (int kx = 0; kx < 3; ++kx)
        a += sIn[c][row + ky][col + kx] * sDW[c][ky * 3 + kx];
    sH[c][col * 12 + row] = gelu_f(a * sS1[c] + sB1[c]);
  }
  __syncthreads();
  const int og = tid >> 4, pg = tid & 15;
  if (pg < BWc && og < C / 4) {
    const int o0 = og * 4;
    float acc[4][8] = {};
#pragma unroll 4
    for (int c = 0; c < C; ++c) {
      float4 h0 = *(const float4*)&sH[c][pg * 12];
      float4 h1 = *(const float4*)&sH[c][pg * 12 + 4];
      float4 w4 = *(const float4*)&sPWT[c][o0];
      float hh[8] = {h0.x, h0.y, h0.z, h0.w, h1.x, h1.y, h1.z, h1.w};
      float ww[4] = {w4.x, w4.y, w4.z, w4.w};
#pragma unroll
      for (int j = 0; j < 4; ++j)
#pragma unroll
        for (int e = 0; e < 8; ++e) acc[j][e] += ww[j] * hh[e];
    }
    const int Ybase = gy * TH + py0, X = gx * TW + px0 + pg;
    float vv[4][8];
#pragma unroll
    for (int j = 0; j < 4; ++j) {
      int o = o0 + j;
      float s = sS2[o], bb = sB2[o];
#pragma unroll
      for (int e = 0; e < 8; ++e)
        vv[j][e] = gelu_f(acc[j][e] * s + bb + sIn[o][e + 1][pg + 1]);
    }
    if (NHWC) {
#pragma unroll
      for (int e = 0; e < 8; ++e) {
        __hip_bfloat16 tmp[4];
#pragma unroll
        for (int j = 0; j < 4; ++j) tmp[j] = (__hip_bfloat16)vv[j][e];
        __hip_bfloat16* dst =
            (__hip_bfloat16*)out + (((size_t)b * FULL + Ybase + e) * FULL + X) * C + o0;
        *(uint2*)dst = *(uint2*)tmp;
      }
    } else {
#pragma unroll
      for (int j = 0; j < 4; ++j) {
        int o = o0 + j;
#pragma unroll
        for (int e = 0; e < 8; ++e)
          out[((size_t)(b * C + o) * FULL + Ybase + e) * FULL + X] = (OutT)vv[j][e];
      }
    }
  }
}

// ---------------------------------------------------------------------------
extern "C" void kernel_launch(void* const* d_in, const int* in_sizes, int n_in,
                              void* d_out, int out_size, void* d_ws, size_t ws_size,
                              hipStream_t stream) {
  const float* x     = (const float*)d_in[0];
  const float* r1_w  = (const float*)d_in[1];
  const float* r1_s  = (const float*)d_in[2];
  const float* r1_b  = (const float*)d_in[3];
  const float* r1_dw = (const float*)d_in[4];
  const float* r1_s1 = (const float*)d_in[5];
  const float* r1_b1 = (const float*)d_in[6];
  const float* r1_pw = (const float*)d_in[7];
  const float* r1_s2 = (const float*)d_in[8];
  const float* r1_b2 = (const float*)d_in[9];
  const float* r2_w  = (const float*)d_in[10];
  const float* r2_s  = (const float*)d_in[11];
  const float* r2_b  = (const float*)d_in[12];
  const float* r2_dw = (const float*)d_in[13];
  const float* r2_s1 = (const float*)d_in[14];
  const float* r2_b1 = (const float*)d_in[15];
  const float* r2_pw = (const float*)d_in[16];
  const float* r2_s2 = (const float*)d_in[17];
  const float* r2_b2 = (const float*)d_in[18];
  const float* h1_w1 = (const float*)d_in[19];
  const float* h1_s1 = (const float*)d_in[20];
  const float* h1_b1 = (const float*)d_in[21];
  const float* h1_w2 = (const float*)d_in[22];
  const float* h1_s2 = (const float*)d_in[23];
  const float* h1_b2 = (const float*)d_in[24];
  const float* h1_w3 = (const float*)d_in[25];
  const float* h1_s3 = (const float*)d_in[26];
  const float* h1_b3 = (const float*)d_in[27];
  const float* h2_w1 = (const float*)d_in[28];
  const float* h2_s1 = (const float*)d_in[29];
  const float* h2_b1 = (const float*)d_in[30];
  const float* h2_w2 = (const float*)d_in[31];
  const float* h2_s2 = (const float*)d_in[32];
  const float* h2_b2 = (const float*)d_in[33];
  const float* h3_w  = (const float*)d_in[34];
  const float* h3_s  = (const float*)d_in[35];
  const float* h3_b  = (const float*)d_in[36];
  float* out = (float*)d_out;

  // Workspace (float-slot offsets). Peak 28,682,496 f = 114.7 MB (< proven 154).
  //   R1b  bf16 NHWC region1 [16,224,224,24] @ 0           (9,633,792 f)
  //   T1   fp32 NCHW temp    [4,48,224,224]  @  9,633,792  (9,633,792 f)
  //   T2b  bf16 NCHW region2 [4,48,224,224]  @ 19,267,584  (4,816,896 f)
  //   h3wb bf16 [256,12288]                  @ 24,084,480  (1,572,864 f)
  //   r2wb bf16 [48,224]                     @ 25,657,344  (    5,376 f)
  //   h2w1b bf16 [48,384]                    @ 25,662,720  (    9,216 f)
  //   S1   fp32 [16,48,56,56]                @ 25,671,936  (2,408,448 f)
  //   S2   fp32 [16,48,28,28]                @ 28,080,384  (  602,112 f)
  float* F = (float*)d_ws;
  __hip_bfloat16* R1b  = (__hip_bfloat16*)F;
  float* T1            = F + 9633792;
  __hip_bfloat16* T2b  = (__hip_bfloat16*)(F + 19267584);
  __hip_bfloat16* h3wb = (__hip_bfloat16*)(F + 24084480);
  __hip_bfloat16* r2wb = (__hip_bfloat16*)(F + 25657344);
  __hip_bfloat16* h2w1b= (__hip_bfloat16*)(F + 25662720);
  float* S1            = F + 25671936;
  float* S2            = F + 28080384;

  dim3 blk(256);
  const int IMG3 = 3 * 224 * 224;

  // ---- weight conversions / reorders (cheap, once per launch)
  f2bf_k<<<dim3((3145728 + 255) / 256), blk, 0, stream>>>(h3_w, h3wb, 3145728);
  reorder_w_k<<<dim3((48 * 224 + 255) / 256), blk, 0, stream>>>(r2_w, r2wb, 48, 24, 3, 224);
  reorder_w_k<<<dim3((48 * 384 + 255) / 256), blk, 0, stream>>>(h2_w1, h2w1b, 48, 24, 4, 384);

  // ---- region1 chain, 4-image chunks: conv5(x)->T1 fp32, region1 -> R1b NHWC bf16
  for (int g = 0; g < 4; ++g) {
    convgemm_k<true, true, false><<<dim3(3136, 1), blk, 0, stream>>>(
        x + (size_t)g * 4 * IMG3, r1_w, r1_s, r1_b, T1,
        3, 224, 224, 5, 1, 2, 0, 224, 224, 24, 75, 0);
    region_k<24, 32, 32, 7, 16, 4, true, __hip_bfloat16>
        <<<dim3(49, 8, 4), blk, 0, stream>>>(
        T1, r1_dw, r1_s1, r1_b1, r1_pw, r1_s2, r1_b2,
        R1b + (size_t)g * 4 * 224 * 224 * 24);
  }
  // ---- branch2: R1b -> S1 fp32 [16,48,56,56] (MFMA) -> out[ch 256:512]
  nhwc_conv_mfma<24, 4, 4, 0, 48, 384, true><<<dim3(784), blk, 0, stream>>>(
      R1b, h2w1b, h2_s1, h2_b1, S1, 224, 224, 56, 3136);
  convgemm_k<false, false, true><<<dim3(49, 4), blk, 0, stream>>>(
      S1, h2_w2, h2_s2, h2_b2, out, 48, 56, 56, 4, 4, 0, 2, 14, 14, 256, 768, 256);
  // ---- branch1: x -> S1 -> S2 -> out[ch 0:256] (fp32, small)
  convgemm_k<false, true, false><<<dim3(784, 1), blk, 0, stream>>>(
      x, h1_w1, h1_s1, h1_b1, S1, 3, 224, 224, 4, 4, 0, 2, 56, 56, 48, 48, 0);
  convgemm_k<false, true, false><<<dim3(196, 1), blk, 0, stream>>>(
      S1, h1_w2, h1_s2, h1_b2, S2, 48, 56, 56, 2, 2, 0, 1, 28, 28, 48, 192, 0);
  convgemm_k<false, false, true><<<dim3(49, 4), blk, 0, stream>>>(
      S2, h1_w3, h1_s3, h1_b3, out, 48, 28, 28, 2, 2, 0, 1, 14, 14, 256, 192, 0);
  // ---- branch3: per-chunk conv3x3 (MFMA) -> region2 (bf16 NCHW) -> b3 MFMA
  init_b3<<<dim3(3136), blk, 0, stream>>>(out, h3_b);
  for (int g = 0; g < 4; ++g) {
    nhwc_conv_mfma<24, 3, 1, 1, 48, 224, true><<<dim3(3136), blk, 0, stream>>>(
        R1b + (size_t)g * 4 * 224 * 224 * 24, r2wb, r2_s, r2_b, T1,
        224, 224, 224, 50176);
    region_k<48, 56, 56, 4, 14, 2, false, __hip_bfloat16>
        <<<dim3(16, 28, 4), blk, 0, stream>>>(
        T1, r2_dw, r2_s1, r2_b1, r2_pw, r2_s2, r2_b2, T2b);
    b3_mfma<<<dim3(13, 4, 8), blk, 0, stream>>>(
        T2b, h3wb, h3_s, out + (size_t)g * 4 * 196 * 768, 784);
  }
  (void)in_sizes; (void)n_in; (void)out_size; (void)ws_size;
}

// Round 6
// 1092.870 us; speedup vs baseline: 2.5780x; 1.2028x over previous
//
#include <hip/hip_runtime.h>
#include <hip/hip_bf16.h>
#include <math.h>

typedef __attribute__((ext_vector_type(8))) short short8;
typedef __attribute__((ext_vector_type(4))) float f32x4;

__device__ __forceinline__ float gelu_f(float x) {
  return 0.5f * x * (1.0f + erff(x * 0.70710678118654752f));
}

// ---------------------------------------------------------------------------
// Generic conv-as-implicit-GEMM fp32 (unchanged — conv5x5, branch1, b2-conv2)
// ---------------------------------------------------------------------------
template<bool TBL, bool GELU, bool TOOUT>
__global__ __launch_bounds__(256) void convgemm_k(
    const float* __restrict__ in, const float* __restrict__ w,
    const float* __restrict__ bns, const float* __restrict__ bnb,
    float* __restrict__ out,
    int Cin, int H, int W, int ks, int stride, int pad, int ls,
    int OH, int OW, int N, int K, int ch0) {
  __shared__ __align__(16) float sA[16][64];
  __shared__ __align__(16) float sB[16][64];
  __shared__ int sTbl[256];
  const int tid = threadIdx.x;
  if (TBL) {
    int kk2 = ks * ks;
    for (int k = tid; k < K; k += 256) {
      int ic = k / kk2, r = k - ic * kk2;
      sTbl[k] = (ic << 16) | ((r / ks) << 8) | (r % ks);
    }
  }
  const int m0 = blockIdx.x * 64, n0 = blockIdx.y * 64;
  const int mm = tid >> 2, kq = tid & 3;
  const int OHW = OH * OW, HW = H * W;
  int m = m0 + mm;
  int bI = m / OHW; int r = m - bI * OHW;
  int oh = r / OW;  int ow = r - oh * OW;
  const int ihBase = oh * stride - pad, iwBase = ow * stride - pad;
  const int inBase = bI * Cin * HW;
  const int tm = tid & 15, tn = tid >> 4;
  float acc[4][4] = {};
  for (int k0 = 0; k0 < K; k0 += 16) {
    __syncthreads();
#pragma unroll
    for (int i = 0; i < 4; ++i) {
      int kk = kq * 4 + i, k = k0 + kk;
      float v = 0.0f;
      if (k < K) {
        int ic, dy, dx;
        if (TBL) {
          int tv = sTbl[k]; ic = tv >> 16; dy = (tv >> 8) & 255; dx = tv & 255;
        } else {
          ic = k >> (2 * ls);
          int r2 = k & ((1 << (2 * ls)) - 1);
          dy = r2 >> ls; dx = r2 & ((1 << ls) - 1);
        }
        int ih = ihBase + dy, iw = iwBase + dx;
        if (ih >= 0 && ih < H && iw >= 0 && iw < W)
          v = in[inBase + ic * HW + ih * W + iw];
      }
      sA[kk][mm] = v;
    }
#pragma unroll
    for (int i = 0; i < 4; ++i) {
      int kk = kq * 4 + i, k = k0 + kk;
      int n = n0 + mm;
      float v = 0.0f;
      if (n < N && k < K) v = w[n * K + k];
      sB[kk][mm] = v;
    }
    __syncthreads();
#pragma unroll
    for (int kk = 0; kk < 16; ++kk) {
      float4 a4 = *(const float4*)&sA[kk][tm * 4];
      float4 b4 = *(const float4*)&sB[kk][tn * 4];
      acc[0][0] += a4.x * b4.x; acc[0][1] += a4.x * b4.y;
      acc[0][2] += a4.x * b4.z; acc[0][3] += a4.x * b4.w;
      acc[1][0] += a4.y * b4.x; acc[1][1] += a4.y * b4.y;
      acc[1][2] += a4.y * b4.z; acc[1][3] += a4.y * b4.w;
      acc[2][0] += a4.z * b4.x; acc[2][1] += a4.z * b4.y;
      acc[2][2] += a4.z * b4.z; acc[2][3] += a4.z * b4.w;
      acc[3][0] += a4.w * b4.x; acc[3][1] += a4.w * b4.y;
      acc[3][2] += a4.w * b4.z; acc[3][3] += a4.w * b4.w;
    }
  }
#pragma unroll
  for (int i = 0; i < 4; ++i) {
    int mI = m0 + tm * 4 + i;
    int bO = mI / OHW; int rr = mI - bO * OHW;
#pragma unroll
    for (int j = 0; j < 4; ++j) {
      int n = n0 + tn * 4 + j;
      if (n < N) {
        float v = acc[i][j] * bns[n] + bnb[n];
        if (GELU) v = gelu_f(v);
        if (TOOUT) {
          out[(bO * OHW + rr) * 768 + ch0 + n] = v;  // OHW==196
        } else {
          int oh2 = rr / OW, ow2 = rr - oh2 * OW;
          out[((bO * N + n) * OH + oh2) * OW + ow2] = v;
        }
      }
    }
  }
}

// ---------------------------------------------------------------------------
// NHWC bf16 implicit-GEMM conv via MFMA. OUTMODE: 0 = NCHW fp32, 1 = NHWC bf16
// ---------------------------------------------------------------------------
template<int CIN, int KS, int STRIDE, int PAD, int NN, int KP, bool GELU, int OUTMODE>
__global__ __launch_bounds__(256) void nhwc_conv_mfma(
    const __hip_bfloat16* __restrict__ in, const __hip_bfloat16* __restrict__ wb,
    const float* __restrict__ bns, const float* __restrict__ bnb,
    float* __restrict__ out, int Hin, int Win, int OW, int OHW) {
  constexpr int K = KS * KS * CIN;
  constexpr int LROW = KP + 8;
  __shared__ __align__(16) __hip_bfloat16 sA[64][LROW];
  __shared__ __align__(16) __hip_bfloat16 sB[NN][LROW];
  const int tid = threadIdx.x;
  const float4 f4z = make_float4(0.f, 0.f, 0.f, 0.f);
  {
    const int m = tid & 63, dy = tid >> 6;
    const int mg = blockIdx.x * 64 + m;
    const int bI = mg / OHW; int pix = mg - bI * OHW;
    const int oh = pix / OW, ow = pix - oh * OW;
    if (dy < KS) {
      const int ih = oh * STRIDE - PAD + dy;
      __hip_bfloat16* dst = &sA[m][dy * KS * CIN];
      if (ih < 0 || ih >= Hin) {
#pragma unroll
        for (int i = 0; i < KS * CIN / 8; ++i) ((float4*)dst)[i] = f4z;
      } else {
        const __hip_bfloat16* srow = in + ((size_t)bI * Hin + ih) * Win * CIN;
#pragma unroll
        for (int j = 0; j < KS; ++j) {
          int iw = ow * STRIDE - PAD + j;
          if (PAD > 0 && (iw < 0 || iw >= Win)) {
#pragma unroll
            for (int i = 0; i < CIN / 8; ++i) ((float4*)(dst + j * CIN))[i] = f4z;
          } else {
            const float4* s4 = (const float4*)(srow + (size_t)iw * CIN);
#pragma unroll
            for (int i = 0; i < CIN / 8; ++i) ((float4*)(dst + j * CIN))[i] = s4[i];
          }
        }
      }
    } else if (K < KP) {
#pragma unroll
      for (int c = K; c < KP + 8; c += 8) *(float4*)&sA[m][c] = f4z;
    }
  }
  {
    constexpr int NV = NN * KP / 8;
    const float4* w4 = (const float4*)wb;
    for (int i = tid; i < NV; i += 256) {
      int n = i / (KP / 8), c = i - n * (KP / 8);
      *(float4*)&sB[n][c * 8] = w4[i];
    }
  }
  __syncthreads();
  constexpr int NT = NN / 16;
  const int wave = tid >> 6, lane = tid & 63;
  const int fm = lane & 15, quad = lane >> 4;
  const int wm = wave * 16;
  f32x4 acc[NT] = {};
#pragma unroll
  for (int ks = 0; ks < KP / 32; ++ks) {
    short8 a = *(const short8*)&sA[wm + fm][ks * 32 + quad * 8];
#pragma unroll
    for (int j = 0; j < NT; ++j) {
      short8 b = *(const short8*)&sB[j * 16 + fm][ks * 32 + quad * 8];
      acc[j] = __builtin_amdgcn_mfma_f32_16x16x32_bf16(a, b, acc[j], 0, 0, 0);
    }
  }
  const int mg0 = blockIdx.x * 64 + wm + quad * 4;
  const int bI = mg0 / OHW, pix = mg0 - bI * OHW;
#pragma unroll
  for (int j = 0; j < NT; ++j) {
    int n = j * 16 + fm;
    float s = bns[n], bb = bnb[n];
    float v[4];
#pragma unroll
    for (int e = 0; e < 4; ++e) {
      v[e] = acc[j][e] * s + bb;
      if (GELU) v[e] = gelu_f(v[e]);
    }
    if (OUTMODE == 0) {
      float4 v4 = make_float4(v[0], v[1], v[2], v[3]);
      *(float4*)&out[((size_t)(bI * NN + n)) * OHW + pix] = v4;
    } else {
      __hip_bfloat16* ob = (__hip_bfloat16*)out;
#pragma unroll
      for (int e = 0; e < 4; ++e)
        ob[((size_t)(bI * OHW + pix + e)) * NN + n] = (__hip_bfloat16)v[e];
    }
  }
}

// ---------------------------------------------------------------------------
// Fused RegionLayerDW for region2, MFMA pointwise. Input/output NHWC bf16
// [4,224,224,48]. Block = 8x8 pixels of one tile (56x56, G=4). LDS ~29KB ->
// 5 blocks/CU. dw3x3 on VALU, pw 48x48 via 16x16x32 MFMA (K padded to 64).
// ---------------------------------------------------------------------------
__global__ __launch_bounds__(256) void region2_mfma(
    const __hip_bfloat16* __restrict__ in, const float* __restrict__ dww,
    const float* __restrict__ s1v, const float* __restrict__ b1v,
    const __hip_bfloat16* __restrict__ pwb,  // [16][48][64] bf16, K-padded
    const float* __restrict__ s2v, const float* __restrict__ b2v,
    __hip_bfloat16* __restrict__ out) {
  __shared__ __hip_bfloat16 sIn[48][10][13];
  __shared__ __align__(16) __hip_bfloat16 sH[64][64];  // A-layout, XOR-8 cgroups
  __shared__ __align__(16) __hip_bfloat16 sW[48][64];  // B-layout, XOR-8 cgroups
  __shared__ float sDW[48][9];
  __shared__ float sS1[48], sB1[48], sS2[48], sB2[48];
  const int t = blockIdx.x, sb = blockIdx.y, b = blockIdx.z;
  const int gy = t >> 2, gx = t & 3;
  const int py0 = (sb / 7) * 8, px0 = (sb % 7) * 8;
  const int Y0 = gy * 56, X0 = gx * 56;
  const int tid = threadIdx.x;
  // pw weights -> sW with XOR-8 swizzle
  for (int i = tid; i < 48 * 8; i += 256) {
    int n = i >> 3, g = i & 7;
    float4 v = *(const float4*)&pwb[(size_t)(t * 48 + n) * 64 + g * 8];
    *(float4*)&sW[n][((g ^ (n & 7)) * 8)] = v;
  }
  for (int i = tid; i < 432; i += 256) ((float*)sDW)[i] = dww[t * 432 + i];
  if (tid < 48) {
    sS1[tid] = s1v[t * 48 + tid]; sB1[tid] = b1v[t * 48 + tid];
    sS2[tid] = s2v[t * 48 + tid]; sB2[tid] = b2v[t * 48 + tid];
  }
  // input halo 10x10x48 (zero outside tile), ch-major in LDS
  for (int i = tid; i < 4800; i += 256) {
    int p = i / 48, ch = i - p * 48;
    int r = p / 10, c = p - r * 10;
    int ly = py0 + r - 1, lx = px0 + c - 1;
    __hip_bfloat16 v = (__hip_bfloat16)0.0f;
    if (ly >= 0 && ly < 56 && lx >= 0 && lx < 56)
      v = in[(((size_t)b * 224 + Y0 + ly) * 224 + X0 + lx) * 48 + ch];
    sIn[ch][r][c] = v;
  }
  __syncthreads();
  // dw 3x3 + BN + GELU -> sH (bf16, A-layout); zero-pad ch 48..63
  {
    const int px = tid & 63, row = (tid & 63) >> 3, col = tid & 7;
#pragma unroll 2
    for (int k = 0; k < 12; ++k) {
      int ch = (tid >> 6) + k * 4;
      float a = 0.f;
#pragma unroll
      for (int ky = 0; ky < 3; ++ky)
#pragma unroll
        for (int kx = 0; kx < 3; ++kx)
          a += (float)sIn[ch][row + ky][col + kx] * sDW[ch][ky * 3 + kx];
      float h = gelu_f(a * sS1[ch] + sB1[ch]);
      sH[px][((ch >> 3) ^ (px & 7)) * 8 + (ch & 7)] = (__hip_bfloat16)h;
    }
    for (int i = tid; i < 64 * 16; i += 256) {
      int px2 = i >> 4, ch = 48 + (i & 15);
      sH[px2][((ch >> 3) ^ (px2 & 7)) * 8 + (ch & 7)] = (__hip_bfloat16)0.0f;
    }
  }
  __syncthreads();
  // pw MFMA: M=64 (1 frag/wave), N=48 (3 frags), K=64 (2 steps)
  const int wave = tid >> 6, lane = tid & 63;
  const int fm = lane & 15, quad = lane >> 4;
  const int am = wave * 16 + fm;
  f32x4 acc[3] = {};
#pragma unroll
  for (int ks = 0; ks < 2; ++ks) {
    short8 a = *(const short8*)&sH[am][(((ks * 4 + quad) ^ (am & 7)) * 8)];
#pragma unroll
    for (int j = 0; j < 3; ++j) {
      int n = j * 16 + fm;
      short8 bf = *(const short8*)&sW[n][(((ks * 4 + quad) ^ (n & 7)) * 8)];
      acc[j] = __builtin_amdgcn_mfma_f32_16x16x32_bf16(a, bf, acc[j], 0, 0, 0);
    }
  }
  // epilogue: px = wave*16+quad*4+e, ch = j*16+fm; BN + residual + GELU
  const int pxb = wave * 16 + quad * 4;
#pragma unroll
  for (int j = 0; j < 3; ++j) {
    int n = j * 16 + fm;
    float s = sS2[n], bb = sB2[n];
#pragma unroll
    for (int e = 0; e < 4; ++e) {
      int px = pxb + e, row = px >> 3, col = px & 7;
      float v = acc[j][e] * s + bb + (float)sIn[n][row + 1][col + 1];
      v = gelu_f(v);
      out[(((size_t)b * 224 + Y0 + py0 + row) * 224 + X0 + px0 + col) * 48 + n] =
          (__hip_bfloat16)v;
    }
  }
}

// ---------------------------------------------------------------------------
// branch3 bf16 MFMA GEMM, split-K atomic. A now NHWC bf16 [4,224,224,48];
// k = dy*768 + dx*48 + ic (matches reorder_w_k ordering) -> contiguous rows.
// ---------------------------------------------------------------------------
__global__ __launch_bounds__(256) void b3_mfma(
    const __hip_bfloat16* __restrict__ A, const __hip_bfloat16* __restrict__ Wb,
    const float* __restrict__ scale, float* __restrict__ out, int M) {
  constexpr int K = 12288, KSL = 1536;  // split 8
  __shared__ __align__(16) __hip_bfloat16 sA[64][64];
  __shared__ __align__(16) __hip_bfloat16 sB[64][64];
  const int tid = threadIdx.x;
  const int m0 = blockIdx.x * 64, n0 = blockIdx.y * 64;
  const int kBase = blockIdx.z * KSL;
  const int mi = tid >> 2, seg = tid & 3;
  int m = m0 + mi; int mc = (m < M) ? m : (M - 1);
  int bI = mc / 196; int r = mc - bI * 196;
  int oh = r / 14, ow = r - oh * 14;
  const __hip_bfloat16* Abase =
      A + (((size_t)bI * 224 + oh * 16) * 224 + ow * 16) * 48;
  const __hip_bfloat16* Wrow = Wb + (size_t)(n0 + mi) * K;
  const int wave = tid >> 6, lane = tid & 63;
  const int wm = (wave & 1) * 32, wn = (wave >> 1) * 32;
  const int fm = lane & 15, quad = lane >> 4;
  const int sw = fm & 7;
  f32x4 acc[2][2] = {};
  for (int k0 = kBase; k0 < kBase + KSL; k0 += 64) {
    int dy = k0 / 768, rem = k0 - dy * 768;
    __syncthreads();
    {
      const __hip_bfloat16* p = Abase + ((size_t)dy * 224) * 48 + rem + seg * 16;
      float4 v0 = *(const float4*)p;
      float4 v1 = *(const float4*)(p + 8);
      int key = mi & 7;
      *(float4*)&sA[mi][((seg * 2) ^ key) * 8] = v0;
      *(float4*)&sA[mi][((seg * 2 + 1) ^ key) * 8] = v1;
      const __hip_bfloat16* q = Wrow + k0 + seg * 16;
      float4 w0 = *(const float4*)q;
      float4 w1 = *(const float4*)(q + 8);
      *(float4*)&sB[mi][((seg * 2) ^ key) * 8] = w0;
      *(float4*)&sB[mi][((seg * 2 + 1) ^ key) * 8] = w1;
    }
    __syncthreads();
#pragma unroll
    for (int ks = 0; ks < 2; ++ks) {
      int cg = (ks * 4 + quad) ^ sw;
#pragma unroll
      for (int i = 0; i < 2; ++i) {
        short8 a = *(const short8*)&sA[wm + i * 16 + fm][cg * 8];
#pragma unroll
        for (int j = 0; j < 2; ++j) {
          short8 b = *(const short8*)&sB[wn + j * 16 + fm][cg * 8];
          acc[i][j] = __builtin_amdgcn_mfma_f32_16x16x32_bf16(a, b, acc[i][j], 0, 0, 0);
        }
      }
    }
  }
#pragma unroll
  for (int i = 0; i < 2; ++i) {
#pragma unroll
    for (int j = 0; j < 2; ++j) {
      int gn = n0 + wn + j * 16 + fm;
      float sc = scale[gn];
#pragma unroll
      for (int e = 0; e < 4; ++e) {
        int gm = m0 + wm + i * 16 + quad * 4 + e;
        if (gm < M)
          atomicAdd(&out[(size_t)gm * 768 + 512 + gn], acc[i][j][e] * sc);
      }
    }
  }
}

__global__ void init_b3(float* __restrict__ out, const float* __restrict__ bias) {
  int i = blockIdx.x * 256 + threadIdx.x;
  if (i < 16 * 196 * 256) {
    int n = i & 255, bp = i >> 8;
    out[bp * 768 + 512 + n] = bias[n];
  }
}

// OIHW fp32 -> [N][KP] bf16 with k=(dy*ks+dx)*Cin+ic, zero-padded to KP
__global__ void reorder_w_k(const float* __restrict__ w, __hip_bfloat16* __restrict__ o,
                            int N, int Cin, int ks, int KP) {
  int i = blockIdx.x * 256 + threadIdx.x;
  if (i >= N * KP) return;
  int n = i / KP, k = i - n * KP;
  float v = 0.f;
  int K = ks * ks * Cin;
  if (k < K) {
    int dy = k / (ks * Cin); int r = k - dy * ks * Cin;
    int dx = r / Cin, ic = r - dx * Cin;
    v = w[((n * Cin + ic) * ks + dy) * ks + dx];
  }
  o[i] = (__hip_bfloat16)v;
}

// region2 pw weights [16][48][48] fp32 -> [16][48][64] bf16 (K-padded)
__global__ void rw_pw(const float* __restrict__ pw, __hip_bfloat16* __restrict__ o) {
  int i = blockIdx.x * 256 + threadIdx.x;
  if (i >= 16 * 48 * 64) return;
  int t = i >> 11, r = i & 2047;      // 48*64 = 3072? no: use explicit
  t = i / 3072; r = i - t * 3072;
  int n = r >> 6, k = r & 63;
  float v = (k < 48) ? pw[(t * 48 + n) * 48 + k] : 0.f;
  o[i] = (__hip_bfloat16)v;
}

// ---------------------------------------------------------------------------
// Fused RegionLayerDW (VALU version — used for region1 only)
// ---------------------------------------------------------------------------
template<int C, int TH, int TW, int G, int BWc, int MINW, bool NHWC, typename OutT>
__global__ __launch_bounds__(256, MINW) void region_k(
    const float* __restrict__ in, const float* __restrict__ dww,
    const float* __restrict__ s1v, const float* __restrict__ b1v,
    const float* __restrict__ pwv, const float* __restrict__ s2v,
    const float* __restrict__ b2v, OutT* __restrict__ out) {
  constexpr int P = 8 * BWc;
  constexpr int FULL = G * TH;
  constexpr int NBX = TW / BWc;
  constexpr int PADW = (BWc == 14) ? 17 : 18;
  constexpr int HROW = BWc * 12;
  static_assert(TH % 8 == 0 && TW % BWc == 0, "tile divisibility");
  __shared__ __align__(16) float sIn[C][10][PADW];
  __shared__ __align__(16) float sH[C][HROW];
  __shared__ __align__(16) float sPWT[C][C];
  __shared__ float sDW[C][9];
  __shared__ float sS1[C], sB1[C], sS2[C], sB2[C];
  const int t = blockIdx.x, sb = blockIdx.y, b = blockIdx.z;
  const int gy = t / G, gx = t % G;
  const int py0 = (sb / NBX) * 8, px0 = (sb % NBX) * BWc;
  const int tid = threadIdx.x;
  for (int i = tid; i < C * C; i += 256) {
    int o = i / C, c = i - o * C;
    sPWT[c][o] = pwv[t * C * C + i];
  }
  for (int i = tid; i < C * 9; i += 256) ((float*)sDW)[i] = dww[t * C * 9 + i];
  for (int i = tid; i < C; i += 256) {
    sS1[i] = s1v[t * C + i]; sB1[i] = b1v[t * C + i];
    sS2[i] = s2v[t * C + i]; sB2[i] = b2v[t * C + i];
  }
  constexpr int HW2 = 10 * (BWc + 2);
  for (int i = tid; i < C * HW2; i += 256) {
    int c = i / HW2; int rr = i - c * HW2;
    int iy = rr / (BWc + 2), ix = rr - iy * (BWc + 2);
    int ly = py0 + iy - 1, lx = px0 + ix - 1;
    float v = 0.0f;
    if (ly >= 0 && ly < TH && lx >= 0 && lx < TW)
      v = in[((b * C + c) * FULL + gy * TH + ly) * FULL + gx * TW + lx];
    sIn[c][iy][ix] = v;
  }
  __syncthreads();
  for (int i = tid; i < C * P; i += 256) {
    int c = i / P, p = i - c * P;
    int col = p >> 3, row = p & 7;
    float a = 0.0f;
#pragma unroll
    for (int ky = 0; ky < 3; ++ky)
#pragma unroll
      for (int kx = 0; kx < 3; ++kx)
        a += sIn[c][row + ky][col + kx] * sDW[c][ky * 3 + kx];
    sH[c][col * 12 + row] = gelu_f(a * sS1[c] + sB1[c]);
  }
  __syncthreads();
  const int og = tid >> 4, pg = tid & 15;
  if (pg < BWc && og < C / 4) {
    const int o0 = og * 4;
    float acc[4][8] = {};
#pragma unroll 4
    for (int c = 0; c < C; ++c) {
      float4 h0 = *(const float4*)&sH[c][pg * 12];
      float4 h1 = *(const float4*)&sH[c][pg * 12 + 4];
      float4 w4 = *(const float4*)&sPWT[c][o0];
      float hh[8] = {h0.x, h0.y, h0.z, h0.w, h1.x, h1.y, h1.z, h1.w};
      float ww[4] = {w4.x, w4.y, w4.z, w4.w};
#pragma unroll
      for (int j = 0; j < 4; ++j)
#pragma unroll
        for (int e = 0; e < 8; ++e) acc[j][e] += ww[j] * hh[e];
    }
    const int Ybase = gy * TH + py0, X = gx * TW + px0 + pg;
    float vv[4][8];
#pragma unroll
    for (int j = 0; j < 4; ++j) {
      int o = o0 + j;
      float s = sS2[o], bb = sB2[o];
#pragma unroll
      for (int e = 0; e < 8; ++e)
        vv[j][e] = gelu_f(acc[j][e] * s + bb + sIn[o][e + 1][pg + 1]);
    }
    if (NHWC) {
#pragma unroll
      for (int e = 0; e < 8; ++e) {
        __hip_bfloat16 tmp[4];
#pragma unroll
        for (int j = 0; j < 4; ++j) tmp[j] = (__hip_bfloat16)vv[j][e];
        __hip_bfloat16* dst =
            (__hip_bfloat16*)out + (((size_t)b * FULL + Ybase + e) * FULL + X) * C + o0;
        *(uint2*)dst = *(uint2*)tmp;
      }
    } else {
#pragma unroll
      for (int j = 0; j < 4; ++j) {
        int o = o0 + j;
#pragma unroll
        for (int e = 0; e < 8; ++e)
          out[((size_t)(b * C + o) * FULL + Ybase + e) * FULL + X] = (OutT)vv[j][e];
      }
    }
  }
}

// ---------------------------------------------------------------------------
extern "C" void kernel_launch(void* const* d_in, const int* in_sizes, int n_in,
                              void* d_out, int out_size, void* d_ws, size_t ws_size,
                              hipStream_t stream) {
  const float* x     = (const float*)d_in[0];
  const float* r1_w  = (const float*)d_in[1];
  const float* r1_s  = (const float*)d_in[2];
  const float* r1_b  = (const float*)d_in[3];
  const float* r1_dw = (const float*)d_in[4];
  const float* r1_s1 = (const float*)d_in[5];
  const float* r1_b1 = (const float*)d_in[6];
  const float* r1_pw = (const float*)d_in[7];
  const float* r1_s2 = (const float*)d_in[8];
  const float* r1_b2 = (const float*)d_in[9];
  const float* r2_w  = (const float*)d_in[10];
  const float* r2_s  = (const float*)d_in[11];
  const float* r2_b  = (const float*)d_in[12];
  const float* r2_dw = (const float*)d_in[13];
  const float* r2_s1 = (const float*)d_in[14];
  const float* r2_b1 = (const float*)d_in[15];
  const float* r2_pw = (const float*)d_in[16];
  const float* r2_s2 = (const float*)d_in[17];
  const float* r2_b2 = (const float*)d_in[18];
  const float* h1_w1 = (const float*)d_in[19];
  const float* h1_s1 = (const float*)d_in[20];
  const float* h1_b1 = (const float*)d_in[21];
  const float* h1_w2 = (const float*)d_in[22];
  const float* h1_s2 = (const float*)d_in[23];
  const float* h1_b2 = (const float*)d_in[24];
  const float* h1_w3 = (const float*)d_in[25];
  const float* h1_s3 = (const float*)d_in[26];
  const float* h1_b3 = (const float*)d_in[27];
  const float* h2_w1 = (const float*)d_in[28];
  const float* h2_s1 = (const float*)d_in[29];
  const float* h2_b1 = (const float*)d_in[30];
  const float* h2_w2 = (const float*)d_in[31];
  const float* h2_s2 = (const float*)d_in[32];
  const float* h2_b2 = (const float*)d_in[33];
  const float* h3_w  = (const float*)d_in[34];
  const float* h3_s  = (const float*)d_in[35];
  const float* h3_b  = (const float*)d_in[36];
  float* out = (float*)d_out;

  // Workspace (float-slot offsets). Peak 23,890,176 f = 95.6 MB.
  float* F = (float*)d_ws;
  __hip_bfloat16* R1b   = (__hip_bfloat16*)F;                  // [16,224,224,24]
  __hip_bfloat16* T1b   = (__hip_bfloat16*)(F + 9633792);      // [4,224,224,48]
  __hip_bfloat16* T2b   = (__hip_bfloat16*)(F + 14450688);     // [4,224,224,48]
  __hip_bfloat16* h3wb  = (__hip_bfloat16*)(F + 19267584);     // [256][12288]
  __hip_bfloat16* r2wb  = (__hip_bfloat16*)(F + 20840448);     // [48][224]
  __hip_bfloat16* h2w1b = (__hip_bfloat16*)(F + 20845824);     // [48][384]
  __hip_bfloat16* pw2wb = (__hip_bfloat16*)(F + 20855040);     // [16][48][64]
  float* S1             = F + 20879616;                        // [16,48,56,56]
  float* S2             = F + 23288064;                        // [16,48,28,28]
  float* T1f            = F + 9633792;  // fp32 alias for conv5 temp [4,24,224,224]
  // NOTE: T1f ([4,24,224,224] = 4,816,896 f) fits exactly in T1b's slot; they
  // are never live simultaneously (region1 loop vs branch3 loop).

  dim3 blk(256);
  const int IMG3 = 3 * 224 * 224;

  // ---- weight conversions / reorders
  reorder_w_k<<<dim3(12288), blk, 0, stream>>>(h3_w, h3wb, 256, 48, 16, 12288);
  reorder_w_k<<<dim3(42), blk, 0, stream>>>(r2_w, r2wb, 48, 24, 3, 224);
  reorder_w_k<<<dim3(72), blk, 0, stream>>>(h2_w1, h2w1b, 48, 24, 4, 384);
  rw_pw<<<dim3(192), blk, 0, stream>>>(r2_pw, pw2wb);

  // ---- region1 chain, 4-image chunks: conv5(x)->T1f fp32, region1 -> R1b
  for (int g = 0; g < 4; ++g) {
    convgemm_k<true, true, false><<<dim3(3136, 1), blk, 0, stream>>>(
        x + (size_t)g * 4 * IMG3, r1_w, r1_s, r1_b, T1f,
        3, 224, 224, 5, 1, 2, 0, 224, 224, 24, 75, 0);
    region_k<24, 32, 32, 7, 16, 4, true, __hip_bfloat16>
        <<<dim3(49, 8, 4), blk, 0, stream>>>(
        T1f, r1_dw, r1_s1, r1_b1, r1_pw, r1_s2, r1_b2,
        R1b + (size_t)g * 4 * 224 * 224 * 24);
  }
  // ---- branch2: R1b -> S1 fp32 [16,48,56,56] (MFMA) -> out[ch 256:512]
  nhwc_conv_mfma<24, 4, 4, 0, 48, 384, true, 0><<<dim3(784), blk, 0, stream>>>(
      R1b, h2w1b, h2_s1, h2_b1, S1, 224, 224, 56, 3136);
  convgemm_k<false, false, true><<<dim3(49, 4), blk, 0, stream>>>(
      S1, h2_w2, h2_s2, h2_b2, out, 48, 56, 56, 4, 4, 0, 2, 14, 14, 256, 768, 256);
  // ---- branch1: x -> S1 -> S2 -> out[ch 0:256] (fp32, small)
  convgemm_k<false, true, false><<<dim3(784, 1), blk, 0, stream>>>(
      x, h1_w1, h1_s1, h1_b1, S1, 3, 224, 224, 4, 4, 0, 2, 56, 56, 48, 48, 0);
  convgemm_k<false, true, false><<<dim3(196, 1), blk, 0, stream>>>(
      S1, h1_w2, h1_s2, h1_b2, S2, 48, 56, 56, 2, 2, 0, 1, 28, 28, 48, 192, 0);
  convgemm_k<false, false, true><<<dim3(49, 4), blk, 0, stream>>>(
      S2, h1_w3, h1_s3, h1_b3, out, 48, 28, 28, 2, 2, 0, 1, 14, 14, 256, 192, 0);
  // ---- branch3: conv3 (MFMA, NHWC bf16) -> region2 (MFMA) -> b3 MFMA
  init_b3<<<dim3(3136), blk, 0, stream>>>(out, h3_b);
  for (int g = 0; g < 4; ++g) {
    nhwc_conv_mfma<24, 3, 1, 1, 48, 224, true, 1><<<dim3(3136), blk, 0, stream>>>(
        R1b + (size_t)g * 4 * 224 * 224 * 24, r2wb, r2_s, r2_b, (float*)T1b,
        224, 224, 224, 50176);
    region2_mfma<<<dim3(16, 49, 4), blk, 0, stream>>>(
        T1b, r2_dw, r2_s1, r2_b1, pw2wb, r2_s2, r2_b2, T2b);
    b3_mfma<<<dim3(13, 4, 8), blk, 0, stream>>>(
        T2b, h3wb, h3_s, out + (size_t)g * 4 * 196 * 768, 784);
  }
  (void)in_sizes; (void)n_in; (void)out_size; (void)ws_size;
}

// Round 7
// 879.466 us; speedup vs baseline: 3.2035x; 1.2427x over previous
//
#include <hip/hip_runtime.h>
#include <hip/hip_bf16.h>
#include <math.h>

typedef __attribute__((ext_vector_type(8))) short short8;
typedef __attribute__((ext_vector_type(4))) float f32x4;

__device__ __forceinline__ float gelu_f(float x) {
  return 0.5f * x * (1.0f + erff(x * 0.70710678118654752f));
}

// ---------------------------------------------------------------------------
// Generic conv-as-implicit-GEMM fp32 (unchanged — branch1 only now)
// ---------------------------------------------------------------------------
template<bool TBL, bool GELU, bool TOOUT>
__global__ __launch_bounds__(256) void convgemm_k(
    const float* __restrict__ in, const float* __restrict__ w,
    const float* __restrict__ bns, const float* __restrict__ bnb,
    float* __restrict__ out,
    int Cin, int H, int W, int ks, int stride, int pad, int ls,
    int OH, int OW, int N, int K, int ch0) {
  __shared__ __align__(16) float sA[16][64];
  __shared__ __align__(16) float sB[16][64];
  __shared__ int sTbl[256];
  const int tid = threadIdx.x;
  if (TBL) {
    int kk2 = ks * ks;
    for (int k = tid; k < K; k += 256) {
      int ic = k / kk2, r = k - ic * kk2;
      sTbl[k] = (ic << 16) | ((r / ks) << 8) | (r % ks);
    }
  }
  const int m0 = blockIdx.x * 64, n0 = blockIdx.y * 64;
  const int mm = tid >> 2, kq = tid & 3;
  const int OHW = OH * OW, HW = H * W;
  int m = m0 + mm;
  int bI = m / OHW; int r = m - bI * OHW;
  int oh = r / OW;  int ow = r - oh * OW;
  const int ihBase = oh * stride - pad, iwBase = ow * stride - pad;
  const int inBase = bI * Cin * HW;
  const int tm = tid & 15, tn = tid >> 4;
  float acc[4][4] = {};
  for (int k0 = 0; k0 < K; k0 += 16) {
    __syncthreads();
#pragma unroll
    for (int i = 0; i < 4; ++i) {
      int kk = kq * 4 + i, k = k0 + kk;
      float v = 0.0f;
      if (k < K) {
        int ic, dy, dx;
        if (TBL) {
          int tv = sTbl[k]; ic = tv >> 16; dy = (tv >> 8) & 255; dx = tv & 255;
        } else {
          ic = k >> (2 * ls);
          int r2 = k & ((1 << (2 * ls)) - 1);
          dy = r2 >> ls; dx = r2 & ((1 << ls) - 1);
        }
        int ih = ihBase + dy, iw = iwBase + dx;
        if (ih >= 0 && ih < H && iw >= 0 && iw < W)
          v = in[inBase + ic * HW + ih * W + iw];
      }
      sA[kk][mm] = v;
    }
#pragma unroll
    for (int i = 0; i < 4; ++i) {
      int kk = kq * 4 + i, k = k0 + kk;
      int n = n0 + mm;
      float v = 0.0f;
      if (n < N && k < K) v = w[n * K + k];
      sB[kk][mm] = v;
    }
    __syncthreads();
#pragma unroll
    for (int kk = 0; kk < 16; ++kk) {
      float4 a4 = *(const float4*)&sA[kk][tm * 4];
      float4 b4 = *(const float4*)&sB[kk][tn * 4];
      acc[0][0] += a4.x * b4.x; acc[0][1] += a4.x * b4.y;
      acc[0][2] += a4.x * b4.z; acc[0][3] += a4.x * b4.w;
      acc[1][0] += a4.y * b4.x; acc[1][1] += a4.y * b4.y;
      acc[1][2] += a4.y * b4.z; acc[1][3] += a4.y * b4.w;
      acc[2][0] += a4.z * b4.x; acc[2][1] += a4.z * b4.y;
      acc[2][2] += a4.z * b4.z; acc[2][3] += a4.z * b4.w;
      acc[3][0] += a4.w * b4.x; acc[3][1] += a4.w * b4.y;
      acc[3][2] += a4.w * b4.z; acc[3][3] += a4.w * b4.w;
    }
  }
#pragma unroll
  for (int i = 0; i < 4; ++i) {
    int mI = m0 + tm * 4 + i;
    int bO = mI / OHW; int rr = mI - bO * OHW;
#pragma unroll
    for (int j = 0; j < 4; ++j) {
      int n = n0 + tn * 4 + j;
      if (n < N) {
        float v = acc[i][j] * bns[n] + bnb[n];
        if (GELU) v = gelu_f(v);
        if (TOOUT) {
          out[(bO * OHW + rr) * 768 + ch0 + n] = v;  // OHW==196
        } else {
          int oh2 = rr / OW, ow2 = rr - oh2 * OW;
          out[((bO * N + n) * OH + oh2) * OW + ow2] = v;
        }
      }
    }
  }
}

// ---------------------------------------------------------------------------
// NHWC bf16 implicit-GEMM conv via MFMA.
// OUTMODE: 0 = NCHW fp32 (channel stride NVALID), 1 = NHWC bf16.
// CIN==4 uses an 8B-per-pixel staging path (conv5 on NHWC4-padded x).
// ---------------------------------------------------------------------------
template<int CIN, int KS, int STRIDE, int PAD, int NN, int KP, bool GELU,
         int OUTMODE, int NVALID = NN>
__global__ __launch_bounds__(256) void nhwc_conv_mfma(
    const __hip_bfloat16* __restrict__ in, const __hip_bfloat16* __restrict__ wb,
    const float* __restrict__ bns, const float* __restrict__ bnb,
    float* __restrict__ out, int Hin, int Win, int OW, int OHW) {
  constexpr int K = KS * KS * CIN;
  constexpr int LROW = KP + 8;
  __shared__ __align__(16) __hip_bfloat16 sA[64][LROW];
  __shared__ __align__(16) __hip_bfloat16 sB[NN][LROW];
  const int tid = threadIdx.x;
  const float4 f4z = make_float4(0.f, 0.f, 0.f, 0.f);
  if constexpr (CIN == 4) {
    const int m = tid & 63, tg = tid >> 6;
    const int mg = blockIdx.x * 64 + m;
    const int bI = mg / OHW; int pix = mg - bI * OHW;
    const int oh = pix / OW, ow = pix - oh * OW;
    for (int dy = tg; dy < KS; dy += 4) {
      const int ih = oh * STRIDE - PAD + dy;
      __hip_bfloat16* dst = &sA[m][dy * KS * 4];
#pragma unroll
      for (int j = 0; j < KS; ++j) {
        int iw = ow * STRIDE - PAD + j;
        uint2 v = make_uint2(0u, 0u);
        if (ih >= 0 && ih < Hin && iw >= 0 && iw < Win)
          v = *(const uint2*)(in + (((size_t)bI * Hin + ih) * Win + iw) * 4);
        *(uint2*)(dst + j * 4) = v;
      }
    }
    if (tg == 3) {
      for (int c = K; c < KP; c += 4) *(uint2*)&sA[m][c] = make_uint2(0u, 0u);
    }
  } else {
    const int m = tid & 63, dy = tid >> 6;
    const int mg = blockIdx.x * 64 + m;
    const int bI = mg / OHW; int pix = mg - bI * OHW;
    const int oh = pix / OW, ow = pix - oh * OW;
    if (dy < KS) {
      const int ih = oh * STRIDE - PAD + dy;
      __hip_bfloat16* dst = &sA[m][dy * KS * CIN];
      if (ih < 0 || ih >= Hin) {
#pragma unroll
        for (int i = 0; i < KS * CIN / 8; ++i) ((float4*)dst)[i] = f4z;
      } else {
        const __hip_bfloat16* srow = in + ((size_t)bI * Hin + ih) * Win * CIN;
#pragma unroll
        for (int j = 0; j < KS; ++j) {
          int iw = ow * STRIDE - PAD + j;
          if (PAD > 0 && (iw < 0 || iw >= Win)) {
#pragma unroll
            for (int i = 0; i < CIN / 8; ++i) ((float4*)(dst + j * CIN))[i] = f4z;
          } else {
            const float4* s4 = (const float4*)(srow + (size_t)iw * CIN);
#pragma unroll
            for (int i = 0; i < CIN / 8; ++i) ((float4*)(dst + j * CIN))[i] = s4[i];
          }
        }
      }
    } else if (K < KP) {
#pragma unroll
      for (int c = K; c < KP + 8; c += 8) *(float4*)&sA[m][c] = f4z;
    }
  }
  {
    constexpr int NV = NN * KP / 8;
    const float4* w4 = (const float4*)wb;
    for (int i = tid; i < NV; i += 256) {
      int n = i / (KP / 8), c = i - n * (KP / 8);
      *(float4*)&sB[n][c * 8] = w4[i];
    }
  }
  __syncthreads();
  constexpr int NT = NN / 16;
  const int wave = tid >> 6, lane = tid & 63;
  const int fm = lane & 15, quad = lane >> 4;
  const int wm = wave * 16;
  f32x4 acc[NT] = {};
#pragma unroll
  for (int ks = 0; ks < KP / 32; ++ks) {
    short8 a = *(const short8*)&sA[wm + fm][ks * 32 + quad * 8];
#pragma unroll
    for (int j = 0; j < NT; ++j) {
      short8 b = *(const short8*)&sB[j * 16 + fm][ks * 32 + quad * 8];
      acc[j] = __builtin_amdgcn_mfma_f32_16x16x32_bf16(a, b, acc[j], 0, 0, 0);
    }
  }
  const int mg0 = blockIdx.x * 64 + wm + quad * 4;
  const int bI = mg0 / OHW, pix = mg0 - bI * OHW;
#pragma unroll
  for (int j = 0; j < NT; ++j) {
    int n = j * 16 + fm;
    if (n >= NVALID) continue;
    float s = bns[n], bb = bnb[n];
    float v[4];
#pragma unroll
    for (int e = 0; e < 4; ++e) {
      v[e] = acc[j][e] * s + bb;
      if (GELU) v[e] = gelu_f(v[e]);
    }
    if (OUTMODE == 0) {
      float4 v4 = make_float4(v[0], v[1], v[2], v[3]);
      *(float4*)&out[((size_t)(bI * NVALID + n)) * OHW + pix] = v4;
    } else {
      __hip_bfloat16* ob = (__hip_bfloat16*)out;
#pragma unroll
      for (int e = 0; e < 4; ++e)
        ob[((size_t)(bI * OHW + pix + e)) * NN + n] = (__hip_bfloat16)v[e];
    }
  }
}

// ---------------------------------------------------------------------------
// Fused RegionLayerDW for region2, MFMA pointwise (unchanged from R6)
// ---------------------------------------------------------------------------
__global__ __launch_bounds__(256) void region2_mfma(
    const __hip_bfloat16* __restrict__ in, const float* __restrict__ dww,
    const float* __restrict__ s1v, const float* __restrict__ b1v,
    const __hip_bfloat16* __restrict__ pwb,
    const float* __restrict__ s2v, const float* __restrict__ b2v,
    __hip_bfloat16* __restrict__ out) {
  __shared__ __hip_bfloat16 sIn[48][10][13];
  __shared__ __align__(16) __hip_bfloat16 sH[64][64];
  __shared__ __align__(16) __hip_bfloat16 sW[48][64];
  __shared__ float sDW[48][9];
  __shared__ float sS1[48], sB1[48], sS2[48], sB2[48];
  const int t = blockIdx.x, sb = blockIdx.y, b = blockIdx.z;
  const int gy = t >> 2, gx = t & 3;
  const int py0 = (sb / 7) * 8, px0 = (sb % 7) * 8;
  const int Y0 = gy * 56, X0 = gx * 56;
  const int tid = threadIdx.x;
  for (int i = tid; i < 48 * 8; i += 256) {
    int n = i >> 3, g = i & 7;
    float4 v = *(const float4*)&pwb[(size_t)(t * 48 + n) * 64 + g * 8];
    *(float4*)&sW[n][((g ^ (n & 7)) * 8)] = v;
  }
  for (int i = tid; i < 432; i += 256) ((float*)sDW)[i] = dww[t * 432 + i];
  if (tid < 48) {
    sS1[tid] = s1v[t * 48 + tid]; sB1[tid] = b1v[t * 48 + tid];
    sS2[tid] = s2v[t * 48 + tid]; sB2[tid] = b2v[t * 48 + tid];
  }
  for (int i = tid; i < 4800; i += 256) {
    int p = i / 48, ch = i - p * 48;
    int r = p / 10, c = p - r * 10;
    int ly = py0 + r - 1, lx = px0 + c - 1;
    __hip_bfloat16 v = (__hip_bfloat16)0.0f;
    if (ly >= 0 && ly < 56 && lx >= 0 && lx < 56)
      v = in[(((size_t)b * 224 + Y0 + ly) * 224 + X0 + lx) * 48 + ch];
    sIn[ch][r][c] = v;
  }
  __syncthreads();
  {
    const int px = tid & 63, row = (tid & 63) >> 3, col = tid & 7;
#pragma unroll 2
    for (int k = 0; k < 12; ++k) {
      int ch = (tid >> 6) + k * 4;
      float a = 0.f;
#pragma unroll
      for (int ky = 0; ky < 3; ++ky)
#pragma unroll
        for (int kx = 0; kx < 3; ++kx)
          a += (float)sIn[ch][row + ky][col + kx] * sDW[ch][ky * 3 + kx];
      float h = gelu_f(a * sS1[ch] + sB1[ch]);
      sH[px][((ch >> 3) ^ (px & 7)) * 8 + (ch & 7)] = (__hip_bfloat16)h;
    }
    for (int i = tid; i < 64 * 16; i += 256) {
      int px2 = i >> 4, ch = 48 + (i & 15);
      sH[px2][((ch >> 3) ^ (px2 & 7)) * 8 + (ch & 7)] = (__hip_bfloat16)0.0f;
    }
  }
  __syncthreads();
  const int wave = tid >> 6, lane = tid & 63;
  const int fm = lane & 15, quad = lane >> 4;
  const int am = wave * 16 + fm;
  f32x4 acc[3] = {};
#pragma unroll
  for (int ks = 0; ks < 2; ++ks) {
    short8 a = *(const short8*)&sH[am][(((ks * 4 + quad) ^ (am & 7)) * 8)];
#pragma unroll
    for (int j = 0; j < 3; ++j) {
      int n = j * 16 + fm;
      short8 bf = *(const short8*)&sW[n][(((ks * 4 + quad) ^ (n & 7)) * 8)];
      acc[j] = __builtin_amdgcn_mfma_f32_16x16x32_bf16(a, bf, acc[j], 0, 0, 0);
    }
  }
  const int pxb = wave * 16 + quad * 4;
#pragma unroll
  for (int j = 0; j < 3; ++j) {
    int n = j * 16 + fm;
    float s = sS2[n], bb = sB2[n];
#pragma unroll
    for (int e = 0; e < 4; ++e) {
      int px = pxb + e, row = px >> 3, col = px & 7;
      float v = acc[j][e] * s + bb + (float)sIn[n][row + 1][col + 1];
      v = gelu_f(v);
      out[(((size_t)b * 224 + Y0 + py0 + row) * 224 + X0 + px0 + col) * 48 + n] =
          (__hip_bfloat16)v;
    }
  }
}

// ---------------------------------------------------------------------------
// Patch-GEMM via MFMA (generalized b3_mfma). A: NHWC bf16 [*,IMGW,IMGW,48],
// patches PS x PS (IMGW/PS == 14), k = dy*PS*48 + dx*48 + ic.
// ATOMIC: split-K atomicAdd of acc*scale (bias pre-written).
// else: direct store acc*scale + bias. Output channel offset ch0, stride 768.
// ---------------------------------------------------------------------------
template<int PS, int IMGW, int KTOT, int KSL, bool ATOMIC>
__global__ __launch_bounds__(256) void patch_gemm_mfma(
    const __hip_bfloat16* __restrict__ A, const __hip_bfloat16* __restrict__ Wb,
    const float* __restrict__ scale, const float* __restrict__ bias,
    float* __restrict__ out, int M, int ch0) {
  constexpr int RUN = PS * 48;  // bf16 per dy row of a patch (64 | RUN)
  __shared__ __align__(16) __hip_bfloat16 sA[64][64];
  __shared__ __align__(16) __hip_bfloat16 sB[64][64];
  const int tid = threadIdx.x;
  const int m0 = blockIdx.x * 64, n0 = blockIdx.y * 64;
  const int kBase = blockIdx.z * KSL;
  const int mi = tid >> 2, seg = tid & 3;
  int m = m0 + mi; int mc = (m < M) ? m : (M - 1);
  int bI = mc / 196; int r = mc - bI * 196;
  int oh = r / 14, ow = r - oh * 14;
  const __hip_bfloat16* Abase =
      A + (((size_t)bI * IMGW + oh * PS) * IMGW + ow * PS) * 48;
  const __hip_bfloat16* Wrow = Wb + (size_t)(n0 + mi) * KTOT;
  const int wave = tid >> 6, lane = tid & 63;
  const int wm = (wave & 1) * 32, wn = (wave >> 1) * 32;
  const int fm = lane & 15, quad = lane >> 4;
  const int sw = fm & 7;
  f32x4 acc[2][2] = {};
  for (int k0 = kBase; k0 < kBase + KSL; k0 += 64) {
    int dy = k0 / RUN, rem = k0 - dy * RUN;
    __syncthreads();
    {
      const __hip_bfloat16* p = Abase + (size_t)dy * IMGW * 48 + rem + seg * 16;
      float4 v0 = *(const float4*)p;
      float4 v1 = *(const float4*)(p + 8);
      int key = mi & 7;
      *(float4*)&sA[mi][((seg * 2) ^ key) * 8] = v0;
      *(float4*)&sA[mi][((seg * 2 + 1) ^ key) * 8] = v1;
      const __hip_bfloat16* q = Wrow + k0 + seg * 16;
      float4 w0 = *(const float4*)q;
      float4 w1 = *(const float4*)(q + 8);
      *(float4*)&sB[mi][((seg * 2) ^ key) * 8] = w0;
      *(float4*)&sB[mi][((seg * 2 + 1) ^ key) * 8] = w1;
    }
    __syncthreads();
#pragma unroll
    for (int ks = 0; ks < 2; ++ks) {
      int cg = (ks * 4 + quad) ^ sw;
#pragma unroll
      for (int i = 0; i < 2; ++i) {
        short8 a = *(const short8*)&sA[wm + i * 16 + fm][cg * 8];
#pragma unroll
        for (int j = 0; j < 2; ++j) {
          short8 b = *(const short8*)&sB[wn + j * 16 + fm][cg * 8];
          acc[i][j] = __builtin_amdgcn_mfma_f32_16x16x32_bf16(a, b, acc[i][j], 0, 0, 0);
        }
      }
    }
  }
#pragma unroll
  for (int i = 0; i < 2; ++i) {
#pragma unroll
    for (int j = 0; j < 2; ++j) {
      int gn = n0 + wn + j * 16 + fm;
      float sc = scale[gn];
#pragma unroll
      for (int e = 0; e < 4; ++e) {
        int gm = m0 + wm + i * 16 + quad * 4 + e;
        if (gm < M) {
          if (ATOMIC)
            atomicAdd(&out[(size_t)gm * 768 + ch0 + gn], acc[i][j][e] * sc);
          else
            out[(size_t)gm * 768 + ch0 + gn] = acc[i][j][e] * sc + bias[gn];
        }
      }
    }
  }
}

__global__ void init_b3(float* __restrict__ out, const float* __restrict__ bias) {
  int i = blockIdx.x * 256 + threadIdx.x;
  if (i < 16 * 196 * 256) {
    int n = i & 255, bp = i >> 8;
    out[bp * 768 + 512 + n] = bias[n];
  }
}

// OIHW fp32 -> [N][KP] bf16 with k=(dy*ks+dx)*Cin+ic, zero-padded to KP
__global__ void reorder_w_k(const float* __restrict__ w, __hip_bfloat16* __restrict__ o,
                            int N, int Cin, int ks, int KP) {
  int i = blockIdx.x * 256 + threadIdx.x;
  if (i >= N * KP) return;
  int n = i / KP, k = i - n * KP;
  float v = 0.f;
  int K = ks * ks * Cin;
  if (k < K) {
    int dy = k / (ks * Cin); int r = k - dy * ks * Cin;
    int dx = r / Cin, ic = r - dx * Cin;
    v = w[((n * Cin + ic) * ks + dy) * ks + dx];
  }
  o[i] = (__hip_bfloat16)v;
}

// OIHW fp32 -> [Nout][KP] bf16 with channel padding: k=(dy*ks+dx)*Cp+ic,
// rows >= Nreal and ic >= Cr are zero.
__global__ void reorder_w4(const float* __restrict__ w, __hip_bfloat16* __restrict__ o,
                           int Nout, int Nreal, int Cp, int Cr, int ks, int KP) {
  int i = blockIdx.x * 256 + threadIdx.x;
  if (i >= Nout * KP) return;
  int n = i / KP, k = i - n * KP;
  float v = 0.f;
  if (n < Nreal && k < ks * ks * Cp) {
    int dy = k / (ks * Cp); int r = k - dy * ks * Cp;
    int dx = r / Cp, ic = r - dx * Cp;
    if (ic < Cr) v = w[((n * Cr + ic) * ks + dy) * ks + dx];
  }
  o[i] = (__hip_bfloat16)v;
}

// region2 pw weights [16][48][48] fp32 -> [16][48][64] bf16 (K-padded)
__global__ void rw_pw(const float* __restrict__ pw, __hip_bfloat16* __restrict__ o) {
  int i = blockIdx.x * 256 + threadIdx.x;
  if (i >= 16 * 48 * 64) return;
  int t = i / 3072, r = i - t * 3072;
  int n = r >> 6, k = r & 63;
  float v = (k < 48) ? pw[(t * 48 + n) * 48 + k] : 0.f;
  o[i] = (__hip_bfloat16)v;
}

// x [16,3,224,224] fp32 -> [16,224,224,4] bf16 (ch3 = 0)
__global__ void xcvt(const float* __restrict__ x, __hip_bfloat16* __restrict__ o) {
  int i = blockIdx.x * 256 + threadIdx.x;
  if (i >= 802816) return;
  int b = i / 50176, p = i - b * 50176;
  const float* src = x + (size_t)b * 150528 + p;
  __hip_bfloat16 v[4];
  v[0] = (__hip_bfloat16)src[0];
  v[1] = (__hip_bfloat16)src[50176];
  v[2] = (__hip_bfloat16)src[100352];
  v[3] = (__hip_bfloat16)0.0f;
  *(uint2*)&o[(size_t)i * 4] = *(uint2*)v;
}

// ---------------------------------------------------------------------------
// Fused RegionLayerDW (VALU version — region1 only, unchanged)
// ---------------------------------------------------------------------------
template<int C, int TH, int TW, int G, int BWc, int MINW, bool NHWC, typename OutT>
__global__ __launch_bounds__(256, MINW) void region_k(
    const float* __restrict__ in, const float* __restrict__ dww,
    const float* __restrict__ s1v, const float* __restrict__ b1v,
    const float* __restrict__ pwv, const float* __restrict__ s2v,
    const float* __restrict__ b2v, OutT* __restrict__ out) {
  constexpr int P = 8 * BWc;
  constexpr int FULL = G * TH;
  constexpr int NBX = TW / BWc;
  constexpr int PADW = (BWc == 14) ? 17 : 18;
  constexpr int HROW = BWc * 12;
  static_assert(TH % 8 == 0 && TW % BWc == 0, "tile divisibility");
  __shared__ __align__(16) float sIn[C][10][PADW];
  __shared__ __align__(16) float sH[C][HROW];
  __shared__ __align__(16) float sPWT[C][C];
  __shared__ float sDW[C][9];
  __shared__ float sS1[C], sB1[C], sS2[C], sB2[C];
  const int t = blockIdx.x, sb = blockIdx.y, b = blockIdx.z;
  const int gy = t / G, gx = t % G;
  const int py0 = (sb / NBX) * 8, px0 = (sb % NBX) * BWc;
  const int tid = threadIdx.x;
  for (int i = tid; i < C * C; i += 256) {
    int o = i / C, c = i - o * C;
    sPWT[c][o] = pwv[t * C * C + i];
  }
  for (int i = tid; i < C * 9; i += 256) ((float*)sDW)[i] = dww[t * C * 9 + i];
  for (int i = tid; i < C; i += 256) {
    sS1[i] = s1v[t * C + i]; sB1[i] = b1v[t * C + i];
    sS2[i] = s2v[t * C + i]; sB2[i] = b2v[t * C + i];
  }
  constexpr int HW2 = 10 * (BWc + 2);
  for (int i = tid; i < C * HW2; i += 256) {
    int c = i / HW2; int rr = i - c * HW2;
    int iy = rr / (BWc + 2), ix = rr - iy * (BWc + 2);
    int ly = py0 + iy - 1, lx = px0 + ix - 1;
    float v = 0.0f;
    if (ly >= 0 && ly < TH && lx >= 0 && lx < TW)
      v = in[((b * C + c) * FULL + gy * TH + ly) * FULL + gx * TW + lx];
    sIn[c][iy][ix] = v;
  }
  __syncthreads();
  for (int i = tid; i < C * P; i += 256) {
    int c = i / P, p = i - c * P;
    int col = p >> 3, row = p & 7;
    float a = 0.0f;
#pragma unroll
    for (int ky = 0; ky < 3; ++ky)
#pragma unroll
      for (int kx = 0; kx < 3; ++kx)
        a += sIn[c][row + ky][col + kx] * sDW[c][ky * 3 + kx];
    sH[c][col * 12 + row] = gelu_f(a * sS1[c] + sB1[c]);
  }
  __syncthreads();
  const int og = tid >> 4, pg = tid & 15;
  if (pg < BWc && og < C / 4) {
    const int o0 = og * 4;
    float acc[4][8] = {};
#pragma unroll 4
    for (int c = 0; c < C; ++c) {
      float4 h0 = *(const float4*)&sH[c][pg * 12];
      float4 h1 = *(const float4*)&sH[c][pg * 12 + 4];
      float4 w4 = *(const float4*)&sPWT[c][o0];
      float hh[8] = {h0.x, h0.y, h0.z, h0.w, h1.x, h1.y, h1.z, h1.w};
      float ww[4] = {w4.x, w4.y, w4.z, w4.w};
#pragma unroll
      for (int j = 0; j < 4; ++j)
#pragma unroll
        for (int e = 0; e < 8; ++e) acc[j][e] += ww[j] * hh[e];
    }
    const int Ybase = gy * TH + py0, X = gx * TW + px0 + pg;
    float vv[4][8];
#pragma unroll
    for (int j = 0; j < 4; ++j) {
      int o = o0 + j;
      float s = sS2[o], bb = sB2[o];
#pragma unroll
      for (int e = 0; e < 8; ++e)
        vv[j][e] = gelu_f(acc[j][e] * s + bb + sIn[o][e + 1][pg + 1]);
    }
    if (NHWC) {
#pragma unroll
      for (int e = 0; e < 8; ++e) {
        __hip_bfloat16 tmp[4];
#pragma unroll
        for (int j = 0; j < 4; ++j) tmp[j] = (__hip_bfloat16)vv[j][e];
        __hip_bfloat16* dst =
            (__hip_bfloat16*)out + (((size_t)b * FULL + Ybase + e) * FULL + X) * C + o0;
        *(uint2*)dst = *(uint2*)tmp;
      }
    } else {
#pragma unroll
      for (int j = 0; j < 4; ++j) {
        int o = o0 + j;
#pragma unroll
        for (int e = 0; e < 8; ++e)
          out[((size_t)(b * C + o) * FULL + Ybase + e) * FULL + X] = (OutT)vv[j][e];
      }
    }
  }
}

// ---------------------------------------------------------------------------
extern "C" void kernel_launch(void* const* d_in, const int* in_sizes, int n_in,
                              void* d_out, int out_size, void* d_ws, size_t ws_size,
                              hipStream_t stream) {
  const float* x     = (const float*)d_in[0];
  const float* r1_w  = (const float*)d_in[1];
  const float* r1_s  = (const float*)d_in[2];
  const float* r1_b  = (const float*)d_in[3];
  const float* r1_dw = (const float*)d_in[4];
  const float* r1_s1 = (const float*)d_in[5];
  const float* r1_b1 = (const float*)d_in[6];
  const float* r1_pw = (const float*)d_in[7];
  const float* r1_s2 = (const float*)d_in[8];
  const float* r1_b2 = (const float*)d_in[9];
  const float* r2_w  = (const float*)d_in[10];
  const float* r2_s  = (const float*)d_in[11];
  const float* r2_b  = (const float*)d_in[12];
  const float* r2_dw = (const float*)d_in[13];
  const float* r2_s1 = (const float*)d_in[14];
  const float* r2_b1 = (const float*)d_in[15];
  const float* r2_pw = (const float*)d_in[16];
  const float* r2_s2 = (const float*)d_in[17];
  const float* r2_b2 = (const float*)d_in[18];
  const float* h1_w1 = (const float*)d_in[19];
  const float* h1_s1 = (const float*)d_in[20];
  const float* h1_b1 = (const float*)d_in[21];
  const float* h1_w2 = (const float*)d_in[22];
  const float* h1_s2 = (const float*)d_in[23];
  const float* h1_b2 = (const float*)d_in[24];
  const float* h1_w3 = (const float*)d_in[25];
  const float* h1_s3 = (const float*)d_in[26];
  const float* h1_b3 = (const float*)d_in[27];
  const float* h2_w1 = (const float*)d_in[28];
  const float* h2_s1 = (const float*)d_in[29];
  const float* h2_b1 = (const float*)d_in[30];
  const float* h2_w2 = (const float*)d_in[31];
  const float* h2_s2 = (const float*)d_in[32];
  const float* h2_b2 = (const float*)d_in[33];
  const float* h3_w  = (const float*)d_in[34];
  const float* h3_s  = (const float*)d_in[35];
  const float* h3_b  = (const float*)d_in[36];
  float* out = (float*)d_out;

  // Workspace (float-slot offsets). Peak 26,800,384 f = 107.2 MB.
  float* F = (float*)d_ws;
  __hip_bfloat16* R1b   = (__hip_bfloat16*)F;                  // [16,224,224,24]
  __hip_bfloat16* T1b   = (__hip_bfloat16*)(F + 9633792);      // [4,224,224,48]
  float* T1f            = F + 9633792;   // fp32 alias [4,24,224,224] (region1 loop)
  __hip_bfloat16* T2b   = (__hip_bfloat16*)(F + 14450688);     // [4,224,224,48]
  __hip_bfloat16* h3wb  = (__hip_bfloat16*)(F + 19267584);     // [256][12288]
  __hip_bfloat16* r2wb  = (__hip_bfloat16*)(F + 20840448);     // [48][224]
  __hip_bfloat16* h2w1b = (__hip_bfloat16*)(F + 20845824);     // [48][384]
  __hip_bfloat16* pw2wb = (__hip_bfloat16*)(F + 20855040);     // [16][48][64]
  __hip_bfloat16* r1wb  = (__hip_bfloat16*)(F + 20879616);     // [32][128]
  __hip_bfloat16* h2w2b = (__hip_bfloat16*)(F + 20881664);     // [256][768]
  __hip_bfloat16* xb    = (__hip_bfloat16*)(F + 20979968);     // [16,224,224,4]
  __hip_bfloat16* S1b   = (__hip_bfloat16*)(F + 22585600);     // [16,56,56,48]
  float* S1             = F + 23789824;                        // [16,48,56,56]
  float* S2             = F + 26198272;                        // [16,48,28,28]

  dim3 blk(256);

  // ---- input conversion + weight reorders
  xcvt<<<dim3(3136), blk, 0, stream>>>(x, xb);
  reorder_w_k<<<dim3(12288), blk, 0, stream>>>(h3_w, h3wb, 256, 48, 16, 12288);
  reorder_w_k<<<dim3(42), blk, 0, stream>>>(r2_w, r2wb, 48, 24, 3, 224);
  reorder_w_k<<<dim3(72), blk, 0, stream>>>(h2_w1, h2w1b, 48, 24, 4, 384);
  reorder_w_k<<<dim3(768), blk, 0, stream>>>(h2_w2, h2w2b, 256, 48, 4, 768);
  reorder_w4<<<dim3(16), blk, 0, stream>>>(r1_w, r1wb, 32, 24, 4, 3, 5, 128);
  rw_pw<<<dim3(192), blk, 0, stream>>>(r2_pw, pw2wb);

  // ---- region1 chain, 4-image chunks: conv5 MFMA (xb -> T1f), region1 -> R1b
  for (int g = 0; g < 4; ++g) {
    nhwc_conv_mfma<4, 5, 1, 2, 32, 128, true, 0, 24><<<dim3(3136), blk, 0, stream>>>(
        xb + (size_t)g * 4 * 224 * 224 * 4, r1wb, r1_s, r1_b, T1f,
        224, 224, 224, 50176);
    region_k<24, 32, 32, 7, 16, 4, true, __hip_bfloat16>
        <<<dim3(49, 8, 4), blk, 0, stream>>>(
        T1f, r1_dw, r1_s1, r1_b1, r1_pw, r1_s2, r1_b2,
        R1b + (size_t)g * 4 * 224 * 224 * 24);
  }
  // ---- branch2: R1b -> S1b bf16 NHWC [16,56,56,48] -> out[ch 256:512]
  nhwc_conv_mfma<24, 4, 4, 0, 48, 384, true, 1><<<dim3(784), blk, 0, stream>>>(
      R1b, h2w1b, h2_s1, h2_b1, (float*)S1b, 224, 224, 56, 3136);
  patch_gemm_mfma<4, 56, 768, 768, false><<<dim3(49, 4, 1), blk, 0, stream>>>(
      S1b, h2w2b, h2_s2, h2_b2, out, 3136, 256);
  // ---- branch1: x -> S1 -> S2 -> out[ch 0:256] (fp32, small)
  convgemm_k<false, true, false><<<dim3(784, 1), blk, 0, stream>>>(
      x, h1_w1, h1_s1, h1_b1, S1, 3, 224, 224, 4, 4, 0, 2, 56, 56, 48, 48, 0);
  convgemm_k<false, true, false><<<dim3(196, 1), blk, 0, stream>>>(
      S1, h1_w2, h1_s2, h1_b2, S2, 48, 56, 56, 2, 2, 0, 1, 28, 28, 48, 192, 0);
  convgemm_k<false, false, true><<<dim3(49, 4), blk, 0, stream>>>(
      S2, h1_w3, h1_s3, h1_b3, out, 48, 28, 28, 2, 2, 0, 1, 14, 14, 256, 192, 0);
  // ---- branch3: conv3 (MFMA) -> region2 (MFMA) -> b3 patch-GEMM (split-K)
  init_b3<<<dim3(3136), blk, 0, stream>>>(out, h3_b);
  for (int g = 0; g < 4; ++g) {
    nhwc_conv_mfma<24, 3, 1, 1, 48, 224, true, 1><<<dim3(3136), blk, 0, stream>>>(
        R1b + (size_t)g * 4 * 224 * 224 * 24, r2wb, r2_s, r2_b, (float*)T1b,
        224, 224, 224, 50176);
    region2_mfma<<<dim3(16, 49, 4), blk, 0, stream>>>(
        T1b, r2_dw, r2_s1, r2_b1, pw2wb, r2_s2, r2_b2, T2b);
    patch_gemm_mfma<16, 224, 12288, 1536, true><<<dim3(13, 4, 8), blk, 0, stream>>>(
        T2b, h3wb, h3_s, h3_b, out + (size_t)g * 4 * 196 * 768, 784, 512);
  }
  (void)in_sizes; (void)n_in; (void)out_size; (void)ws_size;
}

// Round 8
// 832.852 us; speedup vs baseline: 3.3828x; 1.0560x over previous
//
#include <hip/hip_runtime.h>
#include <hip/hip_bf16.h>
#include <math.h>

typedef __attribute__((ext_vector_type(8))) short short8;
typedef __attribute__((ext_vector_type(4))) float f32x4;

// Exact-erf GELU via Abramowitz-Stegun 7.1.26 (|erf err| <= 1.5e-7 — far below
// bf16 resolution). ~14 VALU ops vs ~2x for libm erff.
__device__ __forceinline__ float gelu_f(float x) {
  float ax = fabsf(x);
  float z = ax * 0.70710678118654752f;
  float t = __builtin_amdgcn_rcpf(1.0f + 0.3275911f * z);
  float p = t * (0.254829592f +
           t * (-0.284496736f +
           t * (1.421413741f +
           t * (-1.453152027f + t * 1.061405429f))));
  float e = __expf(-z * z);
  float erf_abs = 1.0f - p * e;
  return 0.5f * x + 0.5f * ax * erf_abs;
}

// ---------------------------------------------------------------------------
// Generic conv-as-implicit-GEMM fp32 (branch1 only)
// ---------------------------------------------------------------------------
template<bool TBL, bool GELU, bool TOOUT>
__global__ __launch_bounds__(256) void convgemm_k(
    const float* __restrict__ in, const float* __restrict__ w,
    const float* __restrict__ bns, const float* __restrict__ bnb,
    float* __restrict__ out,
    int Cin, int H, int W, int ks, int stride, int pad, int ls,
    int OH, int OW, int N, int K, int ch0) {
  __shared__ __align__(16) float sA[16][64];
  __shared__ __align__(16) float sB[16][64];
  __shared__ int sTbl[256];
  const int tid = threadIdx.x;
  if (TBL) {
    int kk2 = ks * ks;
    for (int k = tid; k < K; k += 256) {
      int ic = k / kk2, r = k - ic * kk2;
      sTbl[k] = (ic << 16) | ((r / ks) << 8) | (r % ks);
    }
  }
  const int m0 = blockIdx.x * 64, n0 = blockIdx.y * 64;
  const int mm = tid >> 2, kq = tid & 3;
  const int OHW = OH * OW, HW = H * W;
  int m = m0 + mm;
  int bI = m / OHW; int r = m - bI * OHW;
  int oh = r / OW;  int ow = r - oh * OW;
  const int ihBase = oh * stride - pad, iwBase = ow * stride - pad;
  const int inBase = bI * Cin * HW;
  const int tm = tid & 15, tn = tid >> 4;
  float acc[4][4] = {};
  for (int k0 = 0; k0 < K; k0 += 16) {
    __syncthreads();
#pragma unroll
    for (int i = 0; i < 4; ++i) {
      int kk = kq * 4 + i, k = k0 + kk;
      float v = 0.0f;
      if (k < K) {
        int ic, dy, dx;
        if (TBL) {
          int tv = sTbl[k]; ic = tv >> 16; dy = (tv >> 8) & 255; dx = tv & 255;
        } else {
          ic = k >> (2 * ls);
          int r2 = k & ((1 << (2 * ls)) - 1);
          dy = r2 >> ls; dx = r2 & ((1 << ls) - 1);
        }
        int ih = ihBase + dy, iw = iwBase + dx;
        if (ih >= 0 && ih < H && iw >= 0 && iw < W)
          v = in[inBase + ic * HW + ih * W + iw];
      }
      sA[kk][mm] = v;
    }
#pragma unroll
    for (int i = 0; i < 4; ++i) {
      int kk = kq * 4 + i, k = k0 + kk;
      int n = n0 + mm;
      float v = 0.0f;
      if (n < N && k < K) v = w[n * K + k];
      sB[kk][mm] = v;
    }
    __syncthreads();
#pragma unroll
    for (int kk = 0; kk < 16; ++kk) {
      float4 a4 = *(const float4*)&sA[kk][tm * 4];
      float4 b4 = *(const float4*)&sB[kk][tn * 4];
      acc[0][0] += a4.x * b4.x; acc[0][1] += a4.x * b4.y;
      acc[0][2] += a4.x * b4.z; acc[0][3] += a4.x * b4.w;
      acc[1][0] += a4.y * b4.x; acc[1][1] += a4.y * b4.y;
      acc[1][2] += a4.y * b4.z; acc[1][3] += a4.y * b4.w;
      acc[2][0] += a4.z * b4.x; acc[2][1] += a4.z * b4.y;
      acc[2][2] += a4.z * b4.z; acc[2][3] += a4.z * b4.w;
      acc[3][0] += a4.w * b4.x; acc[3][1] += a4.w * b4.y;
      acc[3][2] += a4.w * b4.z; acc[3][3] += a4.w * b4.w;
    }
  }
#pragma unroll
  for (int i = 0; i < 4; ++i) {
    int mI = m0 + tm * 4 + i;
    int bO = mI / OHW; int rr = mI - bO * OHW;
#pragma unroll
    for (int j = 0; j < 4; ++j) {
      int n = n0 + tn * 4 + j;
      if (n < N) {
        float v = acc[i][j] * bns[n] + bnb[n];
        if (GELU) v = gelu_f(v);
        if (TOOUT) {
          out[(bO * OHW + rr) * 768 + ch0 + n] = v;  // OHW==196
        } else {
          int oh2 = rr / OW, ow2 = rr - oh2 * OW;
          out[((bO * N + n) * OH + oh2) * OW + ow2] = v;
        }
      }
    }
  }
}

// ---------------------------------------------------------------------------
// NHWC bf16 implicit-GEMM conv via MFMA.
// OUTMODE: 0 = NCHW fp32 (channel stride NVALID), 1 = NHWC bf16.
// CIN==4 uses an 8B-per-pixel staging path (conv5 on NHWC4-padded x).
// ---------------------------------------------------------------------------
template<int CIN, int KS, int STRIDE, int PAD, int NN, int KP, bool GELU,
         int OUTMODE, int NVALID = NN>
__global__ __launch_bounds__(256) void nhwc_conv_mfma(
    const __hip_bfloat16* __restrict__ in, const __hip_bfloat16* __restrict__ wb,
    const float* __restrict__ bns, const float* __restrict__ bnb,
    float* __restrict__ out, int Hin, int Win, int OW, int OHW) {
  constexpr int K = KS * KS * CIN;
  constexpr int LROW = KP + 8;
  __shared__ __align__(16) __hip_bfloat16 sA[64][LROW];
  __shared__ __align__(16) __hip_bfloat16 sB[NN][LROW];
  const int tid = threadIdx.x;
  const float4 f4z = make_float4(0.f, 0.f, 0.f, 0.f);
  if constexpr (CIN == 4) {
    const int m = tid & 63, tg = tid >> 6;
    const int mg = blockIdx.x * 64 + m;
    const int bI = mg / OHW; int pix = mg - bI * OHW;
    const int oh = pix / OW, ow = pix - oh * OW;
    for (int dy = tg; dy < KS; dy += 4) {
      const int ih = oh * STRIDE - PAD + dy;
      __hip_bfloat16* dst = &sA[m][dy * KS * 4];
#pragma unroll
      for (int j = 0; j < KS; ++j) {
        int iw = ow * STRIDE - PAD + j;
        uint2 v = make_uint2(0u, 0u);
        if (ih >= 0 && ih < Hin && iw >= 0 && iw < Win)
          v = *(const uint2*)(in + (((size_t)bI * Hin + ih) * Win + iw) * 4);
        *(uint2*)(dst + j * 4) = v;
      }
    }
    if (tg == 3) {
      for (int c = K; c < KP; c += 4) *(uint2*)&sA[m][c] = make_uint2(0u, 0u);
    }
  } else {
    const int m = tid & 63, dy = tid >> 6;
    const int mg = blockIdx.x * 64 + m;
    const int bI = mg / OHW; int pix = mg - bI * OHW;
    const int oh = pix / OW, ow = pix - oh * OW;
    if (dy < KS) {
      const int ih = oh * STRIDE - PAD + dy;
      __hip_bfloat16* dst = &sA[m][dy * KS * CIN];
      if (ih < 0 || ih >= Hin) {
#pragma unroll
        for (int i = 0; i < KS * CIN / 8; ++i) ((float4*)dst)[i] = f4z;
      } else {
        const __hip_bfloat16* srow = in + ((size_t)bI * Hin + ih) * Win * CIN;
#pragma unroll
        for (int j = 0; j < KS; ++j) {
          int iw = ow * STRIDE - PAD + j;
          if (PAD > 0 && (iw < 0 || iw >= Win)) {
#pragma unroll
            for (int i = 0; i < CIN / 8; ++i) ((float4*)(dst + j * CIN))[i] = f4z;
          } else {
            const float4* s4 = (const float4*)(srow + (size_t)iw * CIN);
#pragma unroll
            for (int i = 0; i < CIN / 8; ++i) ((float4*)(dst + j * CIN))[i] = s4[i];
          }
        }
      }
    } else if (K < KP) {
#pragma unroll
      for (int c = K; c < KP + 8; c += 8) *(float4*)&sA[m][c] = f4z;
    }
  }
  {
    constexpr int NV = NN * KP / 8;
    const float4* w4 = (const float4*)wb;
    for (int i = tid; i < NV; i += 256) {
      int n = i / (KP / 8), c = i - n * (KP / 8);
      *(float4*)&sB[n][c * 8] = w4[i];
    }
  }
  __syncthreads();
  constexpr int NT = NN / 16;
  const int wave = tid >> 6, lane = tid & 63;
  const int fm = lane & 15, quad = lane >> 4;
  const int wm = wave * 16;
  f32x4 acc[NT] = {};
#pragma unroll
  for (int ks = 0; ks < KP / 32; ++ks) {
    short8 a = *(const short8*)&sA[wm + fm][ks * 32 + quad * 8];
#pragma unroll
    for (int j = 0; j < NT; ++j) {
      short8 b = *(const short8*)&sB[j * 16 + fm][ks * 32 + quad * 8];
      acc[j] = __builtin_amdgcn_mfma_f32_16x16x32_bf16(a, b, acc[j], 0, 0, 0);
    }
  }
  const int mg0 = blockIdx.x * 64 + wm + quad * 4;
  const int bI = mg0 / OHW, pix = mg0 - bI * OHW;
#pragma unroll
  for (int j = 0; j < NT; ++j) {
    int n = j * 16 + fm;
    if (n >= NVALID) continue;
    float s = bns[n], bb = bnb[n];
    float v[4];
#pragma unroll
    for (int e = 0; e < 4; ++e) {
      v[e] = acc[j][e] * s + bb;
      if (GELU) v[e] = gelu_f(v[e]);
    }
    if (OUTMODE == 0) {
      float4 v4 = make_float4(v[0], v[1], v[2], v[3]);
      *(float4*)&out[((size_t)(bI * NVALID + n)) * OHW + pix] = v4;
    } else {
      __hip_bfloat16* ob = (__hip_bfloat16*)out;
#pragma unroll
      for (int e = 0; e < 4; ++e)
        ob[((size_t)(bI * OHW + pix + e)) * NN + n] = (__hip_bfloat16)v[e];
    }
  }
}

// ---------------------------------------------------------------------------
// Fused RegionLayerDW for region2, MFMA pointwise. v2: dw phase uses
// register rolling-window column-pair strips (192 tasks, 2x ds_read_b32/row)
// while wave 3 zero-pads sH. sIn row stride padded to 14 for b32 alignment.
// ---------------------------------------------------------------------------
__global__ __launch_bounds__(256) void region2_mfma(
    const __hip_bfloat16* __restrict__ in, const float* __restrict__ dww,
    const float* __restrict__ s1v, const float* __restrict__ b1v,
    const __hip_bfloat16* __restrict__ pwb,
    const float* __restrict__ s2v, const float* __restrict__ b2v,
    __hip_bfloat16* __restrict__ out) {
  __shared__ __hip_bfloat16 sIn[48][10][14];
  __shared__ __align__(16) __hip_bfloat16 sH[64][64];
  __shared__ __align__(16) __hip_bfloat16 sW[48][64];
  __shared__ float sDW[48][9];
  __shared__ float sS1[48], sB1[48], sS2[48], sB2[48];
  const int t = blockIdx.x, sb = blockIdx.y, b = blockIdx.z;
  const int gy = t >> 2, gx = t & 3;
  const int py0 = (sb / 7) * 8, px0 = (sb % 7) * 8;
  const int Y0 = gy * 56, X0 = gx * 56;
  const int tid = threadIdx.x;
  for (int i = tid; i < 48 * 8; i += 256) {
    int n = i >> 3, g = i & 7;
    float4 v = *(const float4*)&pwb[(size_t)(t * 48 + n) * 64 + g * 8];
    *(float4*)&sW[n][((g ^ (n & 7)) * 8)] = v;
  }
  for (int i = tid; i < 432; i += 256) ((float*)sDW)[i] = dww[t * 432 + i];
  if (tid < 48) {
    sS1[tid] = s1v[t * 48 + tid]; sB1[tid] = b1v[t * 48 + tid];
    sS2[tid] = s2v[t * 48 + tid]; sB2[tid] = b2v[t * 48 + tid];
  }
  for (int i = tid; i < 4800; i += 256) {
    int p = i / 48, ch = i - p * 48;
    int r = p / 10, c = p - r * 10;
    int ly = py0 + r - 1, lx = px0 + c - 1;
    __hip_bfloat16 v = (__hip_bfloat16)0.0f;
    if (ly >= 0 && ly < 56 && lx >= 0 && lx < 56)
      v = in[(((size_t)b * 224 + Y0 + ly) * 224 + X0 + lx) * 48 + ch];
    sIn[ch][r][c] = v;
  }
  __syncthreads();
  // dw 3x3 + BN + GELU -> sH. Threads 0..191: one (ch, col-pair) strip each.
  // Threads 192..255: zero-pad sH channels 48..63.
  if (tid < 192) {
    const int ch = tid >> 2, cp = (tid & 3) * 2;  // output cols cp, cp+1
    float wv[9];
#pragma unroll
    for (int q = 0; q < 9; ++q) wv[q] = sDW[ch][q];
    const float s1 = sS1[ch], b1 = sB1[ch];
    float win[3][4];
#pragma unroll
    for (int r = 0; r < 10; ++r) {
      const unsigned* p = (const unsigned*)&sIn[ch][r][cp];
      unsigned u0 = p[0], u1 = p[1];
      float* wr = win[r % 3];
      wr[0] = __uint_as_float(u0 << 16);
      wr[1] = __uint_as_float(u0 & 0xffff0000u);
      wr[2] = __uint_as_float(u1 << 16);
      wr[3] = __uint_as_float(u1 & 0xffff0000u);
      if (r >= 2) {
        const float* ra = win[(r + 1) % 3];  // row r-2
        const float* rb = win[(r + 2) % 3];  // row r-1
        const float* rc = win[r % 3];        // row r
#pragma unroll
        for (int j = 0; j < 2; ++j) {
          float a = ra[j] * wv[0] + ra[j + 1] * wv[1] + ra[j + 2] * wv[2]
                  + rb[j] * wv[3] + rb[j + 1] * wv[4] + rb[j + 2] * wv[5]
                  + rc[j] * wv[6] + rc[j + 1] * wv[7] + rc[j + 2] * wv[8];
          float h = gelu_f(a * s1 + b1);
          int px = (r - 2) * 8 + cp + j;
          sH[px][((ch >> 3) ^ (px & 7)) * 8 + (ch & 7)] = (__hip_bfloat16)h;
        }
      }
    }
  } else {
    for (int i = tid - 192; i < 64 * 16; i += 64) {
      int px2 = i >> 4, ch = 48 + (i & 15);
      sH[px2][((ch >> 3) ^ (px2 & 7)) * 8 + (ch & 7)] = (__hip_bfloat16)0.0f;
    }
  }
  __syncthreads();
  const int wave = tid >> 6, lane = tid & 63;
  const int fm = lane & 15, quad = lane >> 4;
  const int am = wave * 16 + fm;
  f32x4 acc[3] = {};
#pragma unroll
  for (int ks = 0; ks < 2; ++ks) {
    short8 a = *(const short8*)&sH[am][(((ks * 4 + quad) ^ (am & 7)) * 8)];
#pragma unroll
    for (int j = 0; j < 3; ++j) {
      int n = j * 16 + fm;
      short8 bf = *(const short8*)&sW[n][(((ks * 4 + quad) ^ (n & 7)) * 8)];
      acc[j] = __builtin_amdgcn_mfma_f32_16x16x32_bf16(a, bf, acc[j], 0, 0, 0);
    }
  }
  const int pxb = wave * 16 + quad * 4;
#pragma unroll
  for (int j = 0; j < 3; ++j) {
    int n = j * 16 + fm;
    float s = sS2[n], bb = sB2[n];
#pragma unroll
    for (int e = 0; e < 4; ++e) {
      int px = pxb + e, row = px >> 3, col = px & 7;
      float v = acc[j][e] * s + bb + (float)sIn[n][row + 1][col + 1];
      v = gelu_f(v);
      out[(((size_t)b * 224 + Y0 + py0 + row) * 224 + X0 + px0 + col) * 48 + n] =
          (__hip_bfloat16)v;
    }
  }
}

// ---------------------------------------------------------------------------
// Patch-GEMM via MFMA (b3 + branch2-conv2). Unchanged from R7.
// ---------------------------------------------------------------------------
template<int PS, int IMGW, int KTOT, int KSL, bool ATOMIC>
__global__ __launch_bounds__(256) void patch_gemm_mfma(
    const __hip_bfloat16* __restrict__ A, const __hip_bfloat16* __restrict__ Wb,
    const float* __restrict__ scale, const float* __restrict__ bias,
    float* __restrict__ out, int M, int ch0) {
  constexpr int RUN = PS * 48;
  __shared__ __align__(16) __hip_bfloat16 sA[64][64];
  __shared__ __align__(16) __hip_bfloat16 sB[64][64];
  const int tid = threadIdx.x;
  const int m0 = blockIdx.x * 64, n0 = blockIdx.y * 64;
  const int kBase = blockIdx.z * KSL;
  const int mi = tid >> 2, seg = tid & 3;
  int m = m0 + mi; int mc = (m < M) ? m : (M - 1);
  int bI = mc / 196; int r = mc - bI * 196;
  int oh = r / 14, ow = r - oh * 14;
  const __hip_bfloat16* Abase =
      A + (((size_t)bI * IMGW + oh * PS) * IMGW + ow * PS) * 48;
  const __hip_bfloat16* Wrow = Wb + (size_t)(n0 + mi) * KTOT;
  const int wave = tid >> 6, lane = tid & 63;
  const int wm = (wave & 1) * 32, wn = (wave >> 1) * 32;
  const int fm = lane & 15, quad = lane >> 4;
  const int sw = fm & 7;
  f32x4 acc[2][2] = {};
  for (int k0 = kBase; k0 < kBase + KSL; k0 += 64) {
    int dy = k0 / RUN, rem = k0 - dy * RUN;
    __syncthreads();
    {
      const __hip_bfloat16* p = Abase + (size_t)dy * IMGW * 48 + rem + seg * 16;
      float4 v0 = *(const float4*)p;
      float4 v1 = *(const float4*)(p + 8);
      int key = mi & 7;
      *(float4*)&sA[mi][((seg * 2) ^ key) * 8] = v0;
      *(float4*)&sA[mi][((seg * 2 + 1) ^ key) * 8] = v1;
      const __hip_bfloat16* q = Wrow + k0 + seg * 16;
      float4 w0 = *(const float4*)q;
      float4 w1 = *(const float4*)(q + 8);
      *(float4*)&sB[mi][((seg * 2) ^ key) * 8] = w0;
      *(float4*)&sB[mi][((seg * 2 + 1) ^ key) * 8] = w1;
    }
    __syncthreads();
#pragma unroll
    for (int ks = 0; ks < 2; ++ks) {
      int cg = (ks * 4 + quad) ^ sw;
#pragma unroll
      for (int i = 0; i < 2; ++i) {
        short8 a = *(const short8*)&sA[wm + i * 16 + fm][cg * 8];
#pragma unroll
        for (int j = 0; j < 2; ++j) {
          short8 b = *(const short8*)&sB[wn + j * 16 + fm][cg * 8];
          acc[i][j] = __builtin_amdgcn_mfma_f32_16x16x32_bf16(a, b, acc[i][j], 0, 0, 0);
        }
      }
    }
  }
#pragma unroll
  for (int i = 0; i < 2; ++i) {
#pragma unroll
    for (int j = 0; j < 2; ++j) {
      int gn = n0 + wn + j * 16 + fm;
      float sc = scale[gn];
#pragma unroll
      for (int e = 0; e < 4; ++e) {
        int gm = m0 + wm + i * 16 + quad * 4 + e;
        if (gm < M) {
          if (ATOMIC)
            atomicAdd(&out[(size_t)gm * 768 + ch0 + gn], acc[i][j][e] * sc);
          else
            out[(size_t)gm * 768 + ch0 + gn] = acc[i][j][e] * sc + bias[gn];
        }
      }
    }
  }
}

__global__ void init_b3(float* __restrict__ out, const float* __restrict__ bias) {
  int i = blockIdx.x * 256 + threadIdx.x;
  if (i < 16 * 196 * 256) {
    int n = i & 255, bp = i >> 8;
    out[bp * 768 + 512 + n] = bias[n];
  }
}

// OIHW fp32 -> [N][KP] bf16 with k=(dy*ks+dx)*Cin+ic, zero-padded to KP
__global__ void reorder_w_k(const float* __restrict__ w, __hip_bfloat16* __restrict__ o,
                            int N, int Cin, int ks, int KP) {
  int i = blockIdx.x * 256 + threadIdx.x;
  if (i >= N * KP) return;
  int n = i / KP, k = i - n * KP;
  float v = 0.f;
  int K = ks * ks * Cin;
  if (k < K) {
    int dy = k / (ks * Cin); int r = k - dy * ks * Cin;
    int dx = r / Cin, ic = r - dx * Cin;
    v = w[((n * Cin + ic) * ks + dy) * ks + dx];
  }
  o[i] = (__hip_bfloat16)v;
}

// OIHW fp32 -> [Nout][KP] bf16 with channel padding
__global__ void reorder_w4(const float* __restrict__ w, __hip_bfloat16* __restrict__ o,
                           int Nout, int Nreal, int Cp, int Cr, int ks, int KP) {
  int i = blockIdx.x * 256 + threadIdx.x;
  if (i >= Nout * KP) return;
  int n = i / KP, k = i - n * KP;
  float v = 0.f;
  if (n < Nreal && k < ks * ks * Cp) {
    int dy = k / (ks * Cp); int r = k - dy * ks * Cp;
    int dx = r / Cp, ic = r - dx * Cp;
    if (ic < Cr) v = w[((n * Cr + ic) * ks + dy) * ks + dx];
  }
  o[i] = (__hip_bfloat16)v;
}

// region2 pw weights [16][48][48] fp32 -> [16][48][64] bf16 (K-padded)
__global__ void rw_pw(const float* __restrict__ pw, __hip_bfloat16* __restrict__ o) {
  int i = blockIdx.x * 256 + threadIdx.x;
  if (i >= 16 * 48 * 64) return;
  int t = i / 3072, r = i - t * 3072;
  int n = r >> 6, k = r & 63;
  float v = (k < 48) ? pw[(t * 48 + n) * 48 + k] : 0.f;
  o[i] = (__hip_bfloat16)v;
}

// x [16,3,224,224] fp32 -> [16,224,224,4] bf16 (ch3 = 0)
__global__ void xcvt(const float* __restrict__ x, __hip_bfloat16* __restrict__ o) {
  int i = blockIdx.x * 256 + threadIdx.x;
  if (i >= 802816) return;
  int b = i / 50176, p = i - b * 50176;
  const float* src = x + (size_t)b * 150528 + p;
  __hip_bfloat16 v[4];
  v[0] = (__hip_bfloat16)src[0];
  v[1] = (__hip_bfloat16)src[50176];
  v[2] = (__hip_bfloat16)src[100352];
  v[3] = (__hip_bfloat16)0.0f;
  *(uint2*)&o[(size_t)i * 4] = *(uint2*)v;
}

// ---------------------------------------------------------------------------
// Fused RegionLayerDW (VALU version — region1 only, unchanged)
// ---------------------------------------------------------------------------
template<int C, int TH, int TW, int G, int BWc, int MINW, bool NHWC, typename OutT>
__global__ __launch_bounds__(256, MINW) void region_k(
    const float* __restrict__ in, const float* __restrict__ dww,
    const float* __restrict__ s1v, const float* __restrict__ b1v,
    const float* __restrict__ pwv, const float* __restrict__ s2v,
    const float* __restrict__ b2v, OutT* __restrict__ out) {
  constexpr int P = 8 * BWc;
  constexpr int FULL = G * TH;
  constexpr int NBX = TW / BWc;
  constexpr int PADW = (BWc == 14) ? 17 : 18;
  constexpr int HROW = BWc * 12;
  static_assert(TH % 8 == 0 && TW % BWc == 0, "tile divisibility");
  __shared__ __align__(16) float sIn[C][10][PADW];
  __shared__ __align__(16) float sH[C][HROW];
  __shared__ __align__(16) float sPWT[C][C];
  __shared__ float sDW[C][9];
  __shared__ float sS1[C], sB1[C], sS2[C], sB2[C];
  const int t = blockIdx.x, sb = blockIdx.y, b = blockIdx.z;
  const int gy = t / G, gx = t % G;
  const int py0 = (sb / NBX) * 8, px0 = (sb % NBX) * BWc;
  const int tid = threadIdx.x;
  for (int i = tid; i < C * C; i += 256) {
    int o = i / C, c = i - o * C;
    sPWT[c][o] = pwv[t * C * C + i];
  }
  for (int i = tid; i < C * 9; i += 256) ((float*)sDW)[i] = dww[t * C * 9 + i];
  for (int i = tid; i < C; i += 256) {
    sS1[i] = s1v[t * C + i]; sB1[i] = b1v[t * C + i];
    sS2[i] = s2v[t * C + i]; sB2[i] = b2v[t * C + i];
  }
  constexpr int HW2 = 10 * (BWc + 2);
  for (int i = tid; i < C * HW2; i += 256) {
    int c = i / HW2; int rr = i - c * HW2;
    int iy = rr / (BWc + 2), ix = rr - iy * (BWc + 2);
    int ly = py0 + iy - 1, lx = px0 + ix - 1;
    float v = 0.0f;
    if (ly >= 0 && ly < TH && lx >= 0 && lx < TW)
      v = in[((b * C + c) * FULL + gy * TH + ly) * FULL + gx * TW + lx];
    sIn[c][iy][ix] = v;
  }
  __syncthreads();
  for (int i = tid; i < C * P; i += 256) {
    int c = i / P, p = i - c * P;
    int col = p >> 3, row = p & 7;
    float a = 0.0f;
#pragma unroll
    for (int ky = 0; ky < 3; ++ky)
#pragma unroll
      for (int kx = 0; kx < 3; ++kx)
        a += sIn[c][row + ky][col + kx] * sDW[c][ky * 3 + kx];
    sH[c][col * 12 + row] = gelu_f(a * sS1[c] + sB1[c]);
  }
  __syncthreads();
  const int og = tid >> 4, pg = tid & 15;
  if (pg < BWc && og < C / 4) {
    const int o0 = og * 4;
    float acc[4][8] = {};
#pragma unroll 4
    for (int c = 0; c < C; ++c) {
      float4 h0 = *(const float4*)&sH[c][pg * 12];
      float4 h1 = *(const float4*)&sH[c][pg * 12 + 4];
      float4 w4 = *(const float4*)&sPWT[c][o0];
      float hh[8] = {h0.x, h0.y, h0.z, h0.w, h1.x, h1.y, h1.z, h1.w};
      float ww[4] = {w4.x, w4.y, w4.z, w4.w};
#pragma unroll
      for (int j = 0; j < 4; ++j)
#pragma unroll
        for (int e = 0; e < 8; ++e) acc[j][e] += ww[j] * hh[e];
    }
    const int Ybase = gy * TH + py0, X = gx * TW + px0 + pg;
    float vv[4][8];
#pragma unroll
    for (int j = 0; j < 4; ++j) {
      int o = o0 + j;
      float s = sS2[o], bb = sB2[o];
#pragma unroll
      for (int e = 0; e < 8; ++e)
        vv[j][e] = gelu_f(acc[j][e] * s + bb + sIn[o][e + 1][pg + 1]);
    }
    if (NHWC) {
#pragma unroll
      for (int e = 0; e < 8; ++e) {
        __hip_bfloat16 tmp[4];
#pragma unroll
        for (int j = 0; j < 4; ++j) tmp[j] = (__hip_bfloat16)vv[j][e];
        __hip_bfloat16* dst =
            (__hip_bfloat16*)out + (((size_t)b * FULL + Ybase + e) * FULL + X) * C + o0;
        *(uint2*)dst = *(uint2*)tmp;
      }
    } else {
#pragma unroll
      for (int j = 0; j < 4; ++j) {
        int o = o0 + j;
#pragma unroll
        for (int e = 0; e < 8; ++e)
          out[((size_t)(b * C + o) * FULL + Ybase + e) * FULL + X] = (OutT)vv[j][e];
      }
    }
  }
}

// ---------------------------------------------------------------------------
extern "C" void kernel_launch(void* const* d_in, const int* in_sizes, int n_in,
                              void* d_out, int out_size, void* d_ws, size_t ws_size,
                              hipStream_t stream) {
  const float* x     = (const float*)d_in[0];
  const float* r1_w  = (const float*)d_in[1];
  const float* r1_s  = (const float*)d_in[2];
  const float* r1_b  = (const float*)d_in[3];
  const float* r1_dw = (const float*)d_in[4];
  const float* r1_s1 = (const float*)d_in[5];
  const float* r1_b1 = (const float*)d_in[6];
  const float* r1_pw = (const float*)d_in[7];
  const float* r1_s2 = (const float*)d_in[8];
  const float* r1_b2 = (const float*)d_in[9];
  const float* r2_w  = (const float*)d_in[10];
  const float* r2_s  = (const float*)d_in[11];
  const float* r2_b  = (const float*)d_in[12];
  const float* r2_dw = (const float*)d_in[13];
  const float* r2_s1 = (const float*)d_in[14];
  const float* r2_b1 = (const float*)d_in[15];
  const float* r2_pw = (const float*)d_in[16];
  const float* r2_s2 = (const float*)d_in[17];
  const float* r2_b2 = (const float*)d_in[18];
  const float* h1_w1 = (const float*)d_in[19];
  const float* h1_s1 = (const float*)d_in[20];
  const float* h1_b1 = (const float*)d_in[21];
  const float* h1_w2 = (const float*)d_in[22];
  const float* h1_s2 = (const float*)d_in[23];
  const float* h1_b2 = (const float*)d_in[24];
  const float* h1_w3 = (const float*)d_in[25];
  const float* h1_s3 = (const float*)d_in[26];
  const float* h1_b3 = (const float*)d_in[27];
  const float* h2_w1 = (const float*)d_in[28];
  const float* h2_s1 = (const float*)d_in[29];
  const float* h2_b1 = (const float*)d_in[30];
  const float* h2_w2 = (const float*)d_in[31];
  const float* h2_s2 = (const float*)d_in[32];
  const float* h2_b2 = (const float*)d_in[33];
  const float* h3_w  = (const float*)d_in[34];
  const float* h3_s  = (const float*)d_in[35];
  const float* h3_b  = (const float*)d_in[36];
  float* out = (float*)d_out;

  // Workspace (float-slot offsets). Peak 26,800,384 f = 107.2 MB.
  float* F = (float*)d_ws;
  __hip_bfloat16* R1b   = (__hip_bfloat16*)F;                  // [16,224,224,24]
  __hip_bfloat16* T1b   = (__hip_bfloat16*)(F + 9633792);      // [4,224,224,48]
  float* T1f            = F + 9633792;   // fp32 alias [4,24,224,224]
  __hip_bfloat16* T2b   = (__hip_bfloat16*)(F + 14450688);     // [4,224,224,48]
  __hip_bfloat16* h3wb  = (__hip_bfloat16*)(F + 19267584);     // [256][12288]
  __hip_bfloat16* r2wb  = (__hip_bfloat16*)(F + 20840448);     // [48][224]
  __hip_bfloat16* h2w1b = (__hip_bfloat16*)(F + 20845824);     // [48][384]
  __hip_bfloat16* pw2wb = (__hip_bfloat16*)(F + 20855040);     // [16][48][64]
  __hip_bfloat16* r1wb  = (__hip_bfloat16*)(F + 20879616);     // [32][128]
  __hip_bfloat16* h2w2b = (__hip_bfloat16*)(F + 20881664);     // [256][768]
  __hip_bfloat16* xb    = (__hip_bfloat16*)(F + 20979968);     // [16,224,224,4]
  __hip_bfloat16* S1b   = (__hip_bfloat16*)(F + 22585600);     // [16,56,56,48]
  float* S1             = F + 23789824;                        // [16,48,56,56]
  float* S2             = F + 26198272;                        // [16,48,28,28]

  dim3 blk(256);

  // ---- input conversion + weight reorders
  xcvt<<<dim3(3136), blk, 0, stream>>>(x, xb);
  reorder_w_k<<<dim3(12288), blk, 0, stream>>>(h3_w, h3wb, 256, 48, 16, 12288);
  reorder_w_k<<<dim3(42), blk, 0, stream>>>(r2_w, r2wb, 48, 24, 3, 224);
  reorder_w_k<<<dim3(72), blk, 0, stream>>>(h2_w1, h2w1b, 48, 24, 4, 384);
  reorder_w_k<<<dim3(768), blk, 0, stream>>>(h2_w2, h2w2b, 256, 48, 4, 768);
  reorder_w4<<<dim3(16), blk, 0, stream>>>(r1_w, r1wb, 32, 24, 4, 3, 5, 128);
  rw_pw<<<dim3(192), blk, 0, stream>>>(r2_pw, pw2wb);

  // ---- region1 chain, 4-image chunks: conv5 MFMA (xb -> T1f), region1 -> R1b
  for (int g = 0; g < 4; ++g) {
    nhwc_conv_mfma<4, 5, 1, 2, 32, 128, true, 0, 24><<<dim3(3136), blk, 0, stream>>>(
        xb + (size_t)g * 4 * 224 * 224 * 4, r1wb, r1_s, r1_b, T1f,
        224, 224, 224, 50176);
    region_k<24, 32, 32, 7, 16, 4, true, __hip_bfloat16>
        <<<dim3(49, 8, 4), blk, 0, stream>>>(
        T1f, r1_dw, r1_s1, r1_b1, r1_pw, r1_s2, r1_b2,
        R1b + (size_t)g * 4 * 224 * 224 * 24);
  }
  // ---- branch2: R1b -> S1b bf16 NHWC [16,56,56,48] -> out[ch 256:512]
  nhwc_conv_mfma<24, 4, 4, 0, 48, 384, true, 1><<<dim3(784), blk, 0, stream>>>(
      R1b, h2w1b, h2_s1, h2_b1, (float*)S1b, 224, 224, 56, 3136);
  patch_gemm_mfma<4, 56, 768, 768, false><<<dim3(49, 4, 1), blk, 0, stream>>>(
      S1b, h2w2b, h2_s2, h2_b2, out, 3136, 256);
  // ---- branch1: x -> S1 -> S2 -> out[ch 0:256] (fp32, small)
  convgemm_k<false, true, false><<<dim3(784, 1), blk, 0, stream>>>(
      x, h1_w1, h1_s1, h1_b1, S1, 3, 224, 224, 4, 4, 0, 2, 56, 56, 48, 48, 0);
  convgemm_k<false, true, false><<<dim3(196, 1), blk, 0, stream>>>(
      S1, h1_w2, h1_s2, h1_b2, S2, 48, 56, 56, 2, 2, 0, 1, 28, 28, 48, 192, 0);
  convgemm_k<false, false, true><<<dim3(49, 4), blk, 0, stream>>>(
      S2, h1_w3, h1_s3, h1_b3, out, 48, 28, 28, 2, 2, 0, 1, 14, 14, 256, 192, 0);
  // ---- branch3: conv3 (MFMA) -> region2 (MFMA) -> b3 patch-GEMM (split-K)
  init_b3<<<dim3(3136), blk, 0, stream>>>(out, h3_b);
  for (int g = 0; g < 4; ++g) {
    nhwc_conv_mfma<24, 3, 1, 1, 48, 224, true, 1><<<dim3(3136), blk, 0, stream>>>(
        R1b + (size_t)g * 4 * 224 * 224 * 24, r2wb, r2_s, r2_b, (float*)T1b,
        224, 224, 224, 50176);
    region2_mfma<<<dim3(16, 49, 4), blk, 0, stream>>>(
        T1b, r2_dw, r2_s1, r2_b1, pw2wb, r2_s2, r2_b2, T2b);
    patch_gemm_mfma<16, 224, 12288, 1536, true><<<dim3(13, 4, 8), blk, 0, stream>>>(
        T2b, h3wb, h3_s, h3_b, out + (size_t)g * 4 * 196 * 768, 784, 512);
  }
  (void)in_sizes; (void)n_in; (void)out_size; (void)ws_size;
}

// Round 9
// 681.006 us; speedup vs baseline: 4.1371x; 1.2230x over previous
//
#include <hip/hip_runtime.h>
#include <hip/hip_bf16.h>
#include <math.h>

typedef __attribute__((ext_vector_type(8))) short short8;
typedef __attribute__((ext_vector_type(4))) float f32x4;

// Exact-erf GELU via Abramowitz-Stegun 7.1.26 (|erf err| <= 1.5e-7)
__device__ __forceinline__ float gelu_f(float x) {
  float ax = fabsf(x);
  float z = ax * 0.70710678118654752f;
  float t = __builtin_amdgcn_rcpf(1.0f + 0.3275911f * z);
  float p = t * (0.254829592f +
           t * (-0.284496736f +
           t * (1.421413741f +
           t * (-1.453152027f + t * 1.061405429f))));
  float e = __expf(-z * z);
  float erf_abs = 1.0f - p * e;
  return 0.5f * x + 0.5f * ax * erf_abs;
}

// ---------------------------------------------------------------------------
// Generic conv-as-implicit-GEMM fp32 (branch1 only)
// ---------------------------------------------------------------------------
template<bool TBL, bool GELU, bool TOOUT>
__global__ __launch_bounds__(256) void convgemm_k(
    const float* __restrict__ in, const float* __restrict__ w,
    const float* __restrict__ bns, const float* __restrict__ bnb,
    float* __restrict__ out,
    int Cin, int H, int W, int ks, int stride, int pad, int ls,
    int OH, int OW, int N, int K, int ch0) {
  __shared__ __align__(16) float sA[16][64];
  __shared__ __align__(16) float sB[16][64];
  __shared__ int sTbl[256];
  const int tid = threadIdx.x;
  if (TBL) {
    int kk2 = ks * ks;
    for (int k = tid; k < K; k += 256) {
      int ic = k / kk2, r = k - ic * kk2;
      sTbl[k] = (ic << 16) | ((r / ks) << 8) | (r % ks);
    }
  }
  const int m0 = blockIdx.x * 64, n0 = blockIdx.y * 64;
  const int mm = tid >> 2, kq = tid & 3;
  const int OHW = OH * OW, HW = H * W;
  int m = m0 + mm;
  int bI = m / OHW; int r = m - bI * OHW;
  int oh = r / OW;  int ow = r - oh * OW;
  const int ihBase = oh * stride - pad, iwBase = ow * stride - pad;
  const int inBase = bI * Cin * HW;
  const int tm = tid & 15, tn = tid >> 4;
  float acc[4][4] = {};
  for (int k0 = 0; k0 < K; k0 += 16) {
    __syncthreads();
#pragma unroll
    for (int i = 0; i < 4; ++i) {
      int kk = kq * 4 + i, k = k0 + kk;
      float v = 0.0f;
      if (k < K) {
        int ic, dy, dx;
        if (TBL) {
          int tv = sTbl[k]; ic = tv >> 16; dy = (tv >> 8) & 255; dx = tv & 255;
        } else {
          ic = k >> (2 * ls);
          int r2 = k & ((1 << (2 * ls)) - 1);
          dy = r2 >> ls; dx = r2 & ((1 << ls) - 1);
        }
        int ih = ihBase + dy, iw = iwBase + dx;
        if (ih >= 0 && ih < H && iw >= 0 && iw < W)
          v = in[inBase + ic * HW + ih * W + iw];
      }
      sA[kk][mm] = v;
    }
#pragma unroll
    for (int i = 0; i < 4; ++i) {
      int kk = kq * 4 + i, k = k0 + kk;
      int n = n0 + mm;
      float v = 0.0f;
      if (n < N && k < K) v = w[n * K + k];
      sB[kk][mm] = v;
    }
    __syncthreads();
#pragma unroll
    for (int kk = 0; kk < 16; ++kk) {
      float4 a4 = *(const float4*)&sA[kk][tm * 4];
      float4 b4 = *(const float4*)&sB[kk][tn * 4];
      acc[0][0] += a4.x * b4.x; acc[0][1] += a4.x * b4.y;
      acc[0][2] += a4.x * b4.z; acc[0][3] += a4.x * b4.w;
      acc[1][0] += a4.y * b4.x; acc[1][1] += a4.y * b4.y;
      acc[1][2] += a4.y * b4.z; acc[1][3] += a4.y * b4.w;
      acc[2][0] += a4.z * b4.x; acc[2][1] += a4.z * b4.y;
      acc[2][2] += a4.z * b4.z; acc[2][3] += a4.z * b4.w;
      acc[3][0] += a4.w * b4.x; acc[3][1] += a4.w * b4.y;
      acc[3][2] += a4.w * b4.z; acc[3][3] += a4.w * b4.w;
    }
  }
#pragma unroll
  for (int i = 0; i < 4; ++i) {
    int mI = m0 + tm * 4 + i;
    int bO = mI / OHW; int rr = mI - bO * OHW;
#pragma unroll
    for (int j = 0; j < 4; ++j) {
      int n = n0 + tn * 4 + j;
      if (n < N) {
        float v = acc[i][j] * bns[n] + bnb[n];
        if (GELU) v = gelu_f(v);
        if (TOOUT) {
          out[(bO * OHW + rr) * 768 + ch0 + n] = v;  // OHW==196
        } else {
          int oh2 = rr / OW, ow2 = rr - oh2 * OW;
          out[((bO * N + n) * OH + oh2) * OW + ow2] = v;
        }
      }
    }
  }
}

// ---------------------------------------------------------------------------
// NHWC bf16 implicit-GEMM conv via MFMA.
// OUTMODE: 0 = NCHW fp32 (channel stride NVALID), 1 = NHWC bf16.
// CIN==4 uses an 8B-per-pixel staging path (conv5 on NHWC4-padded x).
// ---------------------------------------------------------------------------
template<int CIN, int KS, int STRIDE, int PAD, int NN, int KP, bool GELU,
         int OUTMODE, int NVALID = NN>
__global__ __launch_bounds__(256) void nhwc_conv_mfma(
    const __hip_bfloat16* __restrict__ in, const __hip_bfloat16* __restrict__ wb,
    const float* __restrict__ bns, const float* __restrict__ bnb,
    float* __restrict__ out, int Hin, int Win, int OW, int OHW) {
  constexpr int K = KS * KS * CIN;
  constexpr int LROW = KP + 8;
  __shared__ __align__(16) __hip_bfloat16 sA[64][LROW];
  __shared__ __align__(16) __hip_bfloat16 sB[NN][LROW];
  const int tid = threadIdx.x;
  const float4 f4z = make_float4(0.f, 0.f, 0.f, 0.f);
  if constexpr (CIN == 4) {
    const int m = tid & 63, tg = tid >> 6;
    const int mg = blockIdx.x * 64 + m;
    const int bI = mg / OHW; int pix = mg - bI * OHW;
    const int oh = pix / OW, ow = pix - oh * OW;
    for (int dy = tg; dy < KS; dy += 4) {
      const int ih = oh * STRIDE - PAD + dy;
      __hip_bfloat16* dst = &sA[m][dy * KS * 4];
#pragma unroll
      for (int j = 0; j < KS; ++j) {
        int iw = ow * STRIDE - PAD + j;
        uint2 v = make_uint2(0u, 0u);
        if (ih >= 0 && ih < Hin && iw >= 0 && iw < Win)
          v = *(const uint2*)(in + (((size_t)bI * Hin + ih) * Win + iw) * 4);
        *(uint2*)(dst + j * 4) = v;
      }
    }
    if (tg == 3) {
      for (int c = K; c < KP; c += 4) *(uint2*)&sA[m][c] = make_uint2(0u, 0u);
    }
  } else {
    const int m = tid & 63, dy = tid >> 6;
    const int mg = blockIdx.x * 64 + m;
    const int bI = mg / OHW; int pix = mg - bI * OHW;
    const int oh = pix / OW, ow = pix - oh * OW;
    if (dy < KS) {
      const int ih = oh * STRIDE - PAD + dy;
      __hip_bfloat16* dst = &sA[m][dy * KS * CIN];
      if (ih < 0 || ih >= Hin) {
#pragma unroll
        for (int i = 0; i < KS * CIN / 8; ++i) ((float4*)dst)[i] = f4z;
      } else {
        const __hip_bfloat16* srow = in + ((size_t)bI * Hin + ih) * Win * CIN;
#pragma unroll
        for (int j = 0; j < KS; ++j) {
          int iw = ow * STRIDE - PAD + j;
          if (PAD > 0 && (iw < 0 || iw >= Win)) {
#pragma unroll
            for (int i = 0; i < CIN / 8; ++i) ((float4*)(dst + j * CIN))[i] = f4z;
          } else {
            const float4* s4 = (const float4*)(srow + (size_t)iw * CIN);
#pragma unroll
            for (int i = 0; i < CIN / 8; ++i) ((float4*)(dst + j * CIN))[i] = s4[i];
          }
        }
      }
    } else if (K < KP) {
#pragma unroll
      for (int c = K; c < KP + 8; c += 8) *(float4*)&sA[m][c] = f4z;
    }
  }
  {
    constexpr int NV = NN * KP / 8;
    const float4* w4 = (const float4*)wb;
    for (int i = tid; i < NV; i += 256) {
      int n = i / (KP / 8), c = i - n * (KP / 8);
      *(float4*)&sB[n][c * 8] = w4[i];
    }
  }
  __syncthreads();
  constexpr int NT = NN / 16;
  const int wave = tid >> 6, lane = tid & 63;
  const int fm = lane & 15, quad = lane >> 4;
  const int wm = wave * 16;
  f32x4 acc[NT] = {};
#pragma unroll
  for (int ks = 0; ks < KP / 32; ++ks) {
    short8 a = *(const short8*)&sA[wm + fm][ks * 32 + quad * 8];
#pragma unroll
    for (int j = 0; j < NT; ++j) {
      short8 b = *(const short8*)&sB[j * 16 + fm][ks * 32 + quad * 8];
      acc[j] = __builtin_amdgcn_mfma_f32_16x16x32_bf16(a, b, acc[j], 0, 0, 0);
    }
  }
  const int mg0 = blockIdx.x * 64 + wm + quad * 4;
  const int bI = mg0 / OHW, pix = mg0 - bI * OHW;
#pragma unroll
  for (int j = 0; j < NT; ++j) {
    int n = j * 16 + fm;
    if (n >= NVALID) continue;
    float s = bns[n], bb = bnb[n];
    float v[4];
#pragma unroll
    for (int e = 0; e < 4; ++e) {
      v[e] = acc[j][e] * s + bb;
      if (GELU) v[e] = gelu_f(v[e]);
    }
    if (OUTMODE == 0) {
      float4 v4 = make_float4(v[0], v[1], v[2], v[3]);
      *(float4*)&out[((size_t)(bI * NVALID + n)) * OHW + pix] = v4;
    } else {
      __hip_bfloat16* ob = (__hip_bfloat16*)out;
#pragma unroll
      for (int e = 0; e < 4; ++e)
        ob[((size_t)(bI * OHW + pix + e)) * NN + n] = (__hip_bfloat16)v[e];
    }
  }
}

// ---------------------------------------------------------------------------
// Fused RegionLayerDW for region2, MFMA pointwise (R8 version, unchanged)
// ---------------------------------------------------------------------------
__global__ __launch_bounds__(256) void region2_mfma(
    const __hip_bfloat16* __restrict__ in, const float* __restrict__ dww,
    const float* __restrict__ s1v, const float* __restrict__ b1v,
    const __hip_bfloat16* __restrict__ pwb,
    const float* __restrict__ s2v, const float* __restrict__ b2v,
    __hip_bfloat16* __restrict__ out) {
  __shared__ __hip_bfloat16 sIn[48][10][14];
  __shared__ __align__(16) __hip_bfloat16 sH[64][64];
  __shared__ __align__(16) __hip_bfloat16 sW[48][64];
  __shared__ float sDW[48][9];
  __shared__ float sS1[48], sB1[48], sS2[48], sB2[48];
  const int t = blockIdx.x, sb = blockIdx.y, b = blockIdx.z;
  const int gy = t >> 2, gx = t & 3;
  const int py0 = (sb / 7) * 8, px0 = (sb % 7) * 8;
  const int Y0 = gy * 56, X0 = gx * 56;
  const int tid = threadIdx.x;
  for (int i = tid; i < 48 * 8; i += 256) {
    int n = i >> 3, g = i & 7;
    float4 v = *(const float4*)&pwb[(size_t)(t * 48 + n) * 64 + g * 8];
    *(float4*)&sW[n][((g ^ (n & 7)) * 8)] = v;
  }
  for (int i = tid; i < 432; i += 256) ((float*)sDW)[i] = dww[t * 432 + i];
  if (tid < 48) {
    sS1[tid] = s1v[t * 48 + tid]; sB1[tid] = b1v[t * 48 + tid];
    sS2[tid] = s2v[t * 48 + tid]; sB2[tid] = b2v[t * 48 + tid];
  }
  for (int i = tid; i < 4800; i += 256) {
    int p = i / 48, ch = i - p * 48;
    int r = p / 10, c = p - r * 10;
    int ly = py0 + r - 1, lx = px0 + c - 1;
    __hip_bfloat16 v = (__hip_bfloat16)0.0f;
    if (ly >= 0 && ly < 56 && lx >= 0 && lx < 56)
      v = in[(((size_t)b * 224 + Y0 + ly) * 224 + X0 + lx) * 48 + ch];
    sIn[ch][r][c] = v;
  }
  __syncthreads();
  if (tid < 192) {
    const int ch = tid >> 2, cp = (tid & 3) * 2;
    float wv[9];
#pragma unroll
    for (int q = 0; q < 9; ++q) wv[q] = sDW[ch][q];
    const float s1 = sS1[ch], b1 = sB1[ch];
    float win[3][4];
#pragma unroll
    for (int r = 0; r < 10; ++r) {
      const unsigned* p = (const unsigned*)&sIn[ch][r][cp];
      unsigned u0 = p[0], u1 = p[1];
      float* wr = win[r % 3];
      wr[0] = __uint_as_float(u0 << 16);
      wr[1] = __uint_as_float(u0 & 0xffff0000u);
      wr[2] = __uint_as_float(u1 << 16);
      wr[3] = __uint_as_float(u1 & 0xffff0000u);
      if (r >= 2) {
        const float* ra = win[(r + 1) % 3];
        const float* rb = win[(r + 2) % 3];
        const float* rc = win[r % 3];
#pragma unroll
        for (int j = 0; j < 2; ++j) {
          float a = ra[j] * wv[0] + ra[j + 1] * wv[1] + ra[j + 2] * wv[2]
                  + rb[j] * wv[3] + rb[j + 1] * wv[4] + rb[j + 2] * wv[5]
                  + rc[j] * wv[6] + rc[j + 1] * wv[7] + rc[j + 2] * wv[8];
          float h = gelu_f(a * s1 + b1);
          int px = (r - 2) * 8 + cp + j;
          sH[px][((ch >> 3) ^ (px & 7)) * 8 + (ch & 7)] = (__hip_bfloat16)h;
        }
      }
    }
  } else {
    for (int i = tid - 192; i < 64 * 16; i += 64) {
      int px2 = i >> 4, ch = 48 + (i & 15);
      sH[px2][((ch >> 3) ^ (px2 & 7)) * 8 + (ch & 7)] = (__hip_bfloat16)0.0f;
    }
  }
  __syncthreads();
  const int wave = tid >> 6, lane = tid & 63;
  const int fm = lane & 15, quad = lane >> 4;
  const int am = wave * 16 + fm;
  f32x4 acc[3] = {};
#pragma unroll
  for (int ks = 0; ks < 2; ++ks) {
    short8 a = *(const short8*)&sH[am][(((ks * 4 + quad) ^ (am & 7)) * 8)];
#pragma unroll
    for (int j = 0; j < 3; ++j) {
      int n = j * 16 + fm;
      short8 bf = *(const short8*)&sW[n][(((ks * 4 + quad) ^ (n & 7)) * 8)];
      acc[j] = __builtin_amdgcn_mfma_f32_16x16x32_bf16(a, bf, acc[j], 0, 0, 0);
    }
  }
  const int pxb = wave * 16 + quad * 4;
#pragma unroll
  for (int j = 0; j < 3; ++j) {
    int n = j * 16 + fm;
    float s = sS2[n], bb = sB2[n];
#pragma unroll
    for (int e = 0; e < 4; ++e) {
      int px = pxb + e, row = px >> 3, col = px & 7;
      float v = acc[j][e] * s + bb + (float)sIn[n][row + 1][col + 1];
      v = gelu_f(v);
      out[(((size_t)b * 224 + Y0 + py0 + row) * 224 + X0 + px0 + col) * 48 + n] =
          (__hip_bfloat16)v;
    }
  }
}

// ---------------------------------------------------------------------------
// Patch-GEMM via MFMA (b3 + branch2-conv2). Unchanged.
// ---------------------------------------------------------------------------
template<int PS, int IMGW, int KTOT, int KSL, bool ATOMIC>
__global__ __launch_bounds__(256) void patch_gemm_mfma(
    const __hip_bfloat16* __restrict__ A, const __hip_bfloat16* __restrict__ Wb,
    const float* __restrict__ scale, const float* __restrict__ bias,
    float* __restrict__ out, int M, int ch0) {
  constexpr int RUN = PS * 48;
  __shared__ __align__(16) __hip_bfloat16 sA[64][64];
  __shared__ __align__(16) __hip_bfloat16 sB[64][64];
  const int tid = threadIdx.x;
  const int m0 = blockIdx.x * 64, n0 = blockIdx.y * 64;
  const int kBase = blockIdx.z * KSL;
  const int mi = tid >> 2, seg = tid & 3;
  int m = m0 + mi; int mc = (m < M) ? m : (M - 1);
  int bI = mc / 196; int r = mc - bI * 196;
  int oh = r / 14, ow = r - oh * 14;
  const __hip_bfloat16* Abase =
      A + (((size_t)bI * IMGW + oh * PS) * IMGW + ow * PS) * 48;
  const __hip_bfloat16* Wrow = Wb + (size_t)(n0 + mi) * KTOT;
  const int wave = tid >> 6, lane = tid & 63;
  const int wm = (wave & 1) * 32, wn = (wave >> 1) * 32;
  const int fm = lane & 15, quad = lane >> 4;
  const int sw = fm & 7;
  f32x4 acc[2][2] = {};
  for (int k0 = kBase; k0 < kBase + KSL; k0 += 64) {
    int dy = k0 / RUN, rem = k0 - dy * RUN;
    __syncthreads();
    {
      const __hip_bfloat16* p = Abase + (size_t)dy * IMGW * 48 + rem + seg * 16;
      float4 v0 = *(const float4*)p;
      float4 v1 = *(const float4*)(p + 8);
      int key = mi & 7;
      *(float4*)&sA[mi][((seg * 2) ^ key) * 8] = v0;
      *(float4*)&sA[mi][((seg * 2 + 1) ^ key) * 8] = v1;
      const __hip_bfloat16* q = Wrow + k0 + seg * 16;
      float4 w0 = *(const float4*)q;
      float4 w1 = *(const float4*)(q + 8);
      *(float4*)&sB[mi][((seg * 2) ^ key) * 8] = w0;
      *(float4*)&sB[mi][((seg * 2 + 1) ^ key) * 8] = w1;
    }
    __syncthreads();
#pragma unroll
    for (int ks = 0; ks < 2; ++ks) {
      int cg = (ks * 4 + quad) ^ sw;
#pragma unroll
      for (int i = 0; i < 2; ++i) {
        short8 a = *(const short8*)&sA[wm + i * 16 + fm][cg * 8];
#pragma unroll
        for (int j = 0; j < 2; ++j) {
          short8 b = *(const short8*)&sB[wn + j * 16 + fm][cg * 8];
          acc[i][j] = __builtin_amdgcn_mfma_f32_16x16x32_bf16(a, b, acc[i][j], 0, 0, 0);
        }
      }
    }
  }
#pragma unroll
  for (int i = 0; i < 2; ++i) {
#pragma unroll
    for (int j = 0; j < 2; ++j) {
      int gn = n0 + wn + j * 16 + fm;
      float sc = scale[gn];
#pragma unroll
      for (int e = 0; e < 4; ++e) {
        int gm = m0 + wm + i * 16 + quad * 4 + e;
        if (gm < M) {
          if (ATOMIC)
            atomicAdd(&out[(size_t)gm * 768 + ch0 + gn], acc[i][j][e] * sc);
          else
            out[(size_t)gm * 768 + ch0 + gn] = acc[i][j][e] * sc + bias[gn];
        }
      }
    }
  }
}

__global__ void init_b3(float* __restrict__ out, const float* __restrict__ bias) {
  int i = blockIdx.x * 256 + threadIdx.x;
  if (i < 16 * 196 * 256) {
    int n = i & 255, bp = i >> 8;
    out[bp * 768 + 512 + n] = bias[n];
  }
}

// OIHW fp32 -> [N][KP] bf16 with k=(dy*ks+dx)*Cin+ic, zero-padded to KP
__global__ void reorder_w_k(const float* __restrict__ w, __hip_bfloat16* __restrict__ o,
                            int N, int Cin, int ks, int KP) {
  int i = blockIdx.x * 256 + threadIdx.x;
  if (i >= N * KP) return;
  int n = i / KP, k = i - n * KP;
  float v = 0.f;
  int K = ks * ks * Cin;
  if (k < K) {
    int dy = k / (ks * Cin); int r = k - dy * ks * Cin;
    int dx = r / Cin, ic = r - dx * Cin;
    v = w[((n * Cin + ic) * ks + dy) * ks + dx];
  }
  o[i] = (__hip_bfloat16)v;
}

// OIHW fp32 -> [Nout][KP] bf16 with channel padding
__global__ void reorder_w4(const float* __restrict__ w, __hip_bfloat16* __restrict__ o,
                           int Nout, int Nreal, int Cp, int Cr, int ks, int KP) {
  int i = blockIdx.x * 256 + threadIdx.x;
  if (i >= Nout * KP) return;
  int n = i / KP, k = i - n * KP;
  float v = 0.f;
  if (n < Nreal && k < ks * ks * Cp) {
    int dy = k / (ks * Cp); int r = k - dy * ks * Cp;
    int dx = r / Cp, ic = r - dx * Cp;
    if (ic < Cr) v = w[((n * Cr + ic) * ks + dy) * ks + dx];
  }
  o[i] = (__hip_bfloat16)v;
}

// region2 pw weights [16][48][48] fp32 -> [16][48][64] bf16 (K-padded)
__global__ void rw_pw(const float* __restrict__ pw, __hip_bfloat16* __restrict__ o) {
  int i = blockIdx.x * 256 + threadIdx.x;
  if (i >= 16 * 48 * 64) return;
  int t = i / 3072, r = i - t * 3072;
  int n = r >> 6, k = r & 63;
  float v = (k < 48) ? pw[(t * 48 + n) * 48 + k] : 0.f;
  o[i] = (__hip_bfloat16)v;
}

// x [16,3,224,224] fp32 -> [16,224,224,4] bf16 (ch3 = 0)
__global__ void xcvt(const float* __restrict__ x, __hip_bfloat16* __restrict__ o) {
  int i = blockIdx.x * 256 + threadIdx.x;
  if (i >= 802816) return;
  int b = i / 50176, p = i - b * 50176;
  const float* src = x + (size_t)b * 150528 + p;
  __hip_bfloat16 v[4];
  v[0] = (__hip_bfloat16)src[0];
  v[1] = (__hip_bfloat16)src[50176];
  v[2] = (__hip_bfloat16)src[100352];
  v[3] = (__hip_bfloat16)0.0f;
  *(uint2*)&o[(size_t)i * 4] = *(uint2*)v;
}

// ---------------------------------------------------------------------------
// Fused RegionLayerDW (VALU version — region1 only, unchanged)
// ---------------------------------------------------------------------------
template<int C, int TH, int TW, int G, int BWc, int MINW, bool NHWC, typename OutT>
__global__ __launch_bounds__(256, MINW) void region_k(
    const float* __restrict__ in, const float* __restrict__ dww,
    const float* __restrict__ s1v, const float* __restrict__ b1v,
    const float* __restrict__ pwv, const float* __restrict__ s2v,
    const float* __restrict__ b2v, OutT* __restrict__ out) {
  constexpr int P = 8 * BWc;
  constexpr int FULL = G * TH;
  constexpr int NBX = TW / BWc;
  constexpr int PADW = (BWc == 14) ? 17 : 18;
  constexpr int HROW = BWc * 12;
  static_assert(TH % 8 == 0 && TW % BWc == 0, "tile divisibility");
  __shared__ __align__(16) float sIn[C][10][PADW];
  __shared__ __align__(16) float sH[C][HROW];
  __shared__ __align__(16) float sPWT[C][C];
  __shared__ float sDW[C][9];
  __shared__ float sS1[C], sB1[C], sS2[C], sB2[C];
  const int t = blockIdx.x, sb = blockIdx.y, b = blockIdx.z;
  const int gy = t / G, gx = t % G;
  const int py0 = (sb / NBX) * 8, px0 = (sb % NBX) * BWc;
  const int tid = threadIdx.x;
  for (int i = tid; i < C * C; i += 256) {
    int o = i / C, c = i - o * C;
    sPWT[c][o] = pwv[t * C * C + i];
  }
  for (int i = tid; i < C * 9; i += 256) ((float*)sDW)[i] = dww[t * C * 9 + i];
  for (int i = tid; i < C; i += 256) {
    sS1[i] = s1v[t * C + i]; sB1[i] = b1v[t * C + i];
    sS2[i] = s2v[t * C + i]; sB2[i] = b2v[t * C + i];
  }
  constexpr int HW2 = 10 * (BWc + 2);
  for (int i = tid; i < C * HW2; i += 256) {
    int c = i / HW2; int rr = i - c * HW2;
    int iy = rr / (BWc + 2), ix = rr - iy * (BWc + 2);
    int ly = py0 + iy - 1, lx = px0 + ix - 1;
    float v = 0.0f;
    if (ly >= 0 && ly < TH && lx >= 0 && lx < TW)
      v = in[((size_t)(b * C + c) * FULL + gy * TH + ly) * FULL + gx * TW + lx];
    sIn[c][iy][ix] = v;
  }
  __syncthreads();
  for (int i = tid; i < C * P; i += 256) {
    int c = i / P, p = i - c * P;
    int col = p >> 3, row = p & 7;
    float a = 0.0f;
#pragma unroll
    for (int ky = 0; ky < 3; ++ky)
#pragma unroll
      for (int kx = 0; kx < 3; ++kx)
        a += sIn[c][row + ky][col + kx] * sDW[c][ky * 3 + kx];
    sH[c][col * 12 + row] = gelu_f(a * sS1[c] + sB1[c]);
  }
  __syncthreads();
  const int og = tid >> 4, pg = tid & 15;
  if (pg < BWc && og < C / 4) {
    const int o0 = og * 4;
    float acc[4][8] = {};
#pragma unroll 4
    for (int c = 0; c < C; ++c) {
      float4 h0 = *(const float4*)&sH[c][pg * 12];
      float4 h1 = *(const float4*)&sH[c][pg * 12 + 4];
      float4 w4 = *(const float4*)&sPWT[c][o0];
      float hh[8] = {h0.x, h0.y, h0.z, h0.w, h1.x, h1.y, h1.z, h1.w};
      float ww[4] = {w4.x, w4.y, w4.z, w4.w};
#pragma unroll
      for (int j = 0; j < 4; ++j)
#pragma unroll
        for (int e = 0; e < 8; ++e) acc[j][e] += ww[j] * hh[e];
    }
    const int Ybase = gy * TH + py0, X = gx * TW + px0 + pg;
    float vv[4][8];
#pragma unroll
    for (int j = 0; j < 4; ++j) {
      int o = o0 + j;
      float s = sS2[o], bb = sB2[o];
#pragma unroll
      for (int e = 0; e < 8; ++e)
        vv[j][e] = gelu_f(acc[j][e] * s + bb + sIn[o][e + 1][pg + 1]);
    }
    if (NHWC) {
#pragma unroll
      for (int e = 0; e < 8; ++e) {
        __hip_bfloat16 tmp[4];
#pragma unroll
        for (int j = 0; j < 4; ++j) tmp[j] = (__hip_bfloat16)vv[j][e];
        __hip_bfloat16* dst =
            (__hip_bfloat16*)out + (((size_t)b * FULL + Ybase + e) * FULL + X) * C + o0;
        *(uint2*)dst = *(uint2*)tmp;
      }
    } else {
#pragma unroll
      for (int j = 0; j < 4; ++j) {
        int o = o0 + j;
#pragma unroll
        for (int e = 0; e < 8; ++e)
          out[((size_t)(b * C + o) * FULL + Ybase + e) * FULL + X] = (OutT)vv[j][e];
      }
    }
  }
}

// ---------------------------------------------------------------------------
extern "C" void kernel_launch(void* const* d_in, const int* in_sizes, int n_in,
                              void* d_out, int out_size, void* d_ws, size_t ws_size,
                              hipStream_t stream) {
  const float* x     = (const float*)d_in[0];
  const float* r1_w  = (const float*)d_in[1];
  const float* r1_s  = (const float*)d_in[2];
  const float* r1_b  = (const float*)d_in[3];
  const float* r1_dw = (const float*)d_in[4];
  const float* r1_s1 = (const float*)d_in[5];
  const float* r1_b1 = (const float*)d_in[6];
  const float* r1_pw = (const float*)d_in[7];
  const float* r1_s2 = (const float*)d_in[8];
  const float* r1_b2 = (const float*)d_in[9];
  const float* r2_w  = (const float*)d_in[10];
  const float* r2_s  = (const float*)d_in[11];
  const float* r2_b  = (const float*)d_in[12];
  const float* r2_dw = (const float*)d_in[13];
  const float* r2_s1 = (const float*)d_in[14];
  const float* r2_b1 = (const float*)d_in[15];
  const float* r2_pw = (const float*)d_in[16];
  const float* r2_s2 = (const float*)d_in[17];
  const float* r2_b2 = (const float*)d_in[18];
  const float* h1_w1 = (const float*)d_in[19];
  const float* h1_s1 = (const float*)d_in[20];
  const float* h1_b1 = (const float*)d_in[21];
  const float* h1_w2 = (const float*)d_in[22];
  const float* h1_s2 = (const float*)d_in[23];
  const float* h1_b2 = (const float*)d_in[24];
  const float* h1_w3 = (const float*)d_in[25];
  const float* h1_s3 = (const float*)d_in[26];
  const float* h1_b3 = (const float*)d_in[27];
  const float* h2_w1 = (const float*)d_in[28];
  const float* h2_s1 = (const float*)d_in[29];
  const float* h2_b1 = (const float*)d_in[30];
  const float* h2_w2 = (const float*)d_in[31];
  const float* h2_s2 = (const float*)d_in[32];
  const float* h2_b2 = (const float*)d_in[33];
  const float* h3_w  = (const float*)d_in[34];
  const float* h3_s  = (const float*)d_in[35];
  const float* h3_b  = (const float*)d_in[36];
  float* out = (float*)d_out;

  // Workspace (float-slot offsets). FULL-BATCH layout, peak 55,701,760 f
  // = 222.8 MB (< ws 256 MiB, verified via harness fill WRITE_SIZE).
  float* F = (float*)d_ws;
  __hip_bfloat16* R1b   = (__hip_bfloat16*)F;                    // [16,224,224,24]
  __hip_bfloat16* T1b   = (__hip_bfloat16*)(F + 9633792);        // [16,224,224,48]
  float* T1f            = F + 9633792;   // fp32 alias [16,24,224,224] (same size)
  __hip_bfloat16* T2b   = (__hip_bfloat16*)(F + 28901376);       // [16,224,224,48]
  __hip_bfloat16* h3wb  = (__hip_bfloat16*)(F + 48168960);       // [256][12288]
  __hip_bfloat16* r2wb  = (__hip_bfloat16*)(F + 49741824);       // [48][224]
  __hip_bfloat16* h2w1b = (__hip_bfloat16*)(F + 49747200);       // [48][384]
  __hip_bfloat16* pw2wb = (__hip_bfloat16*)(F + 49756416);       // [16][48][64]
  __hip_bfloat16* r1wb  = (__hip_bfloat16*)(F + 49780992);       // [32][128]
  __hip_bfloat16* h2w2b = (__hip_bfloat16*)(F + 49783040);       // [256][768]
  __hip_bfloat16* xb    = (__hip_bfloat16*)(F + 49881344);       // [16,224,224,4]
  __hip_bfloat16* S1b   = (__hip_bfloat16*)(F + 51486976);       // [16,56,56,48]
  float* S1             = F + 52691200;                          // [16,48,56,56]
  float* S2             = F + 55099648;                          // [16,48,28,28]

  dim3 blk(256);

  // ---- input conversion + weight reorders
  xcvt<<<dim3(3136), blk, 0, stream>>>(x, xb);
  reorder_w_k<<<dim3(12288), blk, 0, stream>>>(h3_w, h3wb, 256, 48, 16, 12288);
  reorder_w_k<<<dim3(42), blk, 0, stream>>>(r2_w, r2wb, 48, 24, 3, 224);
  reorder_w_k<<<dim3(72), blk, 0, stream>>>(h2_w1, h2w1b, 48, 24, 4, 384);
  reorder_w_k<<<dim3(768), blk, 0, stream>>>(h2_w2, h2w2b, 256, 48, 4, 768);
  reorder_w4<<<dim3(16), blk, 0, stream>>>(r1_w, r1wb, 32, 24, 4, 3, 5, 128);
  rw_pw<<<dim3(192), blk, 0, stream>>>(r2_pw, pw2wb);

  // ---- region1 chain, FULL BATCH: conv5 MFMA (xb -> T1f), region1 -> R1b
  nhwc_conv_mfma<4, 5, 1, 2, 32, 128, true, 0, 24><<<dim3(12544), blk, 0, stream>>>(
      xb, r1wb, r1_s, r1_b, T1f, 224, 224, 224, 50176);
  region_k<24, 32, 32, 7, 16, 4, true, __hip_bfloat16>
      <<<dim3(49, 8, 16), blk, 0, stream>>>(
      T1f, r1_dw, r1_s1, r1_b1, r1_pw, r1_s2, r1_b2, R1b);
  // ---- branch2: R1b -> S1b bf16 NHWC -> out[ch 256:512]
  nhwc_conv_mfma<24, 4, 4, 0, 48, 384, true, 1><<<dim3(784), blk, 0, stream>>>(
      R1b, h2w1b, h2_s1, h2_b1, (float*)S1b, 224, 224, 56, 3136);
  patch_gemm_mfma<4, 56, 768, 768, false><<<dim3(49, 4, 1), blk, 0, stream>>>(
      S1b, h2w2b, h2_s2, h2_b2, out, 3136, 256);
  // ---- branch1: x -> S1 -> S2 -> out[ch 0:256] (fp32, small)
  convgemm_k<false, true, false><<<dim3(784, 1), blk, 0, stream>>>(
      x, h1_w1, h1_s1, h1_b1, S1, 3, 224, 224, 4, 4, 0, 2, 56, 56, 48, 48, 0);
  convgemm_k<false, true, false><<<dim3(196, 1), blk, 0, stream>>>(
      S1, h1_w2, h1_s2, h1_b2, S2, 48, 56, 56, 2, 2, 0, 1, 28, 28, 48, 192, 0);
  convgemm_k<false, false, true><<<dim3(49, 4), blk, 0, stream>>>(
      S2, h1_w3, h1_s3, h1_b3, out, 48, 28, 28, 2, 2, 0, 1, 14, 14, 256, 192, 0);
  // ---- branch3 FULL BATCH: conv3 -> region2 -> b3 patch-GEMM (split-K)
  init_b3<<<dim3(3136), blk, 0, stream>>>(out, h3_b);
  nhwc_conv_mfma<24, 3, 1, 1, 48, 224, true, 1><<<dim3(12544), blk, 0, stream>>>(
      R1b, r2wb, r2_s, r2_b, (float*)T1b, 224, 224, 224, 50176);
  region2_mfma<<<dim3(16, 49, 16), blk, 0, stream>>>(
      T1b, r2_dw, r2_s1, r2_b1, pw2wb, r2_s2, r2_b2, T2b);
  patch_gemm_mfma<16, 224, 12288, 1536, true><<<dim3(49, 4, 8), blk, 0, stream>>>(
      T2b, h3wb, h3_s, h3_b, out, 3136, 512);
  (void)in_sizes; (void)n_in; (void)out_size; (void)ws_size;
}

// Round 10
// 626.883 us; speedup vs baseline: 4.4943x; 1.0863x over previous
//
#include <hip/hip_runtime.h>
#include <hip/hip_bf16.h>
#include <math.h>

typedef __attribute__((ext_vector_type(8))) short short8;
typedef __attribute__((ext_vector_type(4))) float f32x4;

// Exact-erf GELU via Abramowitz-Stegun 7.1.26 (|erf err| <= 1.5e-7)
__device__ __forceinline__ float gelu_f(float x) {
  float ax = fabsf(x);
  float z = ax * 0.70710678118654752f;
  float t = __builtin_amdgcn_rcpf(1.0f + 0.3275911f * z);
  float p = t * (0.254829592f +
           t * (-0.284496736f +
           t * (1.421413741f +
           t * (-1.453152027f + t * 1.061405429f))));
  float e = __expf(-z * z);
  float erf_abs = 1.0f - p * e;
  return 0.5f * x + 0.5f * ax * erf_abs;
}

// ---------------------------------------------------------------------------
// Generic conv-as-implicit-GEMM fp32 (branch1 only)
// ---------------------------------------------------------------------------
template<bool TBL, bool GELU, bool TOOUT>
__global__ __launch_bounds__(256) void convgemm_k(
    const float* __restrict__ in, const float* __restrict__ w,
    const float* __restrict__ bns, const float* __restrict__ bnb,
    float* __restrict__ out,
    int Cin, int H, int W, int ks, int stride, int pad, int ls,
    int OH, int OW, int N, int K, int ch0) {
  __shared__ __align__(16) float sA[16][64];
  __shared__ __align__(16) float sB[16][64];
  __shared__ int sTbl[256];
  const int tid = threadIdx.x;
  if (TBL) {
    int kk2 = ks * ks;
    for (int k = tid; k < K; k += 256) {
      int ic = k / kk2, r = k - ic * kk2;
      sTbl[k] = (ic << 16) | ((r / ks) << 8) | (r % ks);
    }
  }
  const int m0 = blockIdx.x * 64, n0 = blockIdx.y * 64;
  const int mm = tid >> 2, kq = tid & 3;
  const int OHW = OH * OW, HW = H * W;
  int m = m0 + mm;
  int bI = m / OHW; int r = m - bI * OHW;
  int oh = r / OW;  int ow = r - oh * OW;
  const int ihBase = oh * stride - pad, iwBase = ow * stride - pad;
  const int inBase = bI * Cin * HW;
  const int tm = tid & 15, tn = tid >> 4;
  float acc[4][4] = {};
  for (int k0 = 0; k0 < K; k0 += 16) {
    __syncthreads();
#pragma unroll
    for (int i = 0; i < 4; ++i) {
      int kk = kq * 4 + i, k = k0 + kk;
      float v = 0.0f;
      if (k < K) {
        int ic, dy, dx;
        if (TBL) {
          int tv = sTbl[k]; ic = tv >> 16; dy = (tv >> 8) & 255; dx = tv & 255;
        } else {
          ic = k >> (2 * ls);
          int r2 = k & ((1 << (2 * ls)) - 1);
          dy = r2 >> ls; dx = r2 & ((1 << ls) - 1);
        }
        int ih = ihBase + dy, iw = iwBase + dx;
        if (ih >= 0 && ih < H && iw >= 0 && iw < W)
          v = in[inBase + ic * HW + ih * W + iw];
      }
      sA[kk][mm] = v;
    }
#pragma unroll
    for (int i = 0; i < 4; ++i) {
      int kk = kq * 4 + i, k = k0 + kk;
      int n = n0 + mm;
      float v = 0.0f;
      if (n < N && k < K) v = w[n * K + k];
      sB[kk][mm] = v;
    }
    __syncthreads();
#pragma unroll
    for (int kk = 0; kk < 16; ++kk) {
      float4 a4 = *(const float4*)&sA[kk][tm * 4];
      float4 b4 = *(const float4*)&sB[kk][tn * 4];
      acc[0][0] += a4.x * b4.x; acc[0][1] += a4.x * b4.y;
      acc[0][2] += a4.x * b4.z; acc[0][3] += a4.x * b4.w;
      acc[1][0] += a4.y * b4.x; acc[1][1] += a4.y * b4.y;
      acc[1][2] += a4.y * b4.z; acc[1][3] += a4.y * b4.w;
      acc[2][0] += a4.z * b4.x; acc[2][1] += a4.z * b4.y;
      acc[2][2] += a4.z * b4.z; acc[2][3] += a4.z * b4.w;
      acc[3][0] += a4.w * b4.x; acc[3][1] += a4.w * b4.y;
      acc[3][2] += a4.w * b4.z; acc[3][3] += a4.w * b4.w;
    }
  }
#pragma unroll
  for (int i = 0; i < 4; ++i) {
    int mI = m0 + tm * 4 + i;
    int bO = mI / OHW; int rr = mI - bO * OHW;
#pragma unroll
    for (int j = 0; j < 4; ++j) {
      int n = n0 + tn * 4 + j;
      if (n < N) {
        float v = acc[i][j] * bns[n] + bnb[n];
        if (GELU) v = gelu_f(v);
        if (TOOUT) {
          out[(bO * OHW + rr) * 768 + ch0 + n] = v;  // OHW==196
        } else {
          int oh2 = rr / OW, ow2 = rr - oh2 * OW;
          out[((bO * N + n) * OH + oh2) * OW + ow2] = v;
        }
      }
    }
  }
}

// ---------------------------------------------------------------------------
// NHWC bf16 implicit-GEMM conv via MFMA (unchanged from R9)
// ---------------------------------------------------------------------------
template<int CIN, int KS, int STRIDE, int PAD, int NN, int KP, bool GELU,
         int OUTMODE, int NVALID = NN>
__global__ __launch_bounds__(256) void nhwc_conv_mfma(
    const __hip_bfloat16* __restrict__ in, const __hip_bfloat16* __restrict__ wb,
    const float* __restrict__ bns, const float* __restrict__ bnb,
    float* __restrict__ out, int Hin, int Win, int OW, int OHW) {
  constexpr int K = KS * KS * CIN;
  constexpr int LROW = KP + 8;
  __shared__ __align__(16) __hip_bfloat16 sA[64][LROW];
  __shared__ __align__(16) __hip_bfloat16 sB[NN][LROW];
  const int tid = threadIdx.x;
  const float4 f4z = make_float4(0.f, 0.f, 0.f, 0.f);
  if constexpr (CIN == 4) {
    const int m = tid & 63, tg = tid >> 6;
    const int mg = blockIdx.x * 64 + m;
    const int bI = mg / OHW; int pix = mg - bI * OHW;
    const int oh = pix / OW, ow = pix - oh * OW;
    for (int dy = tg; dy < KS; dy += 4) {
      const int ih = oh * STRIDE - PAD + dy;
      __hip_bfloat16* dst = &sA[m][dy * KS * 4];
#pragma unroll
      for (int j = 0; j < KS; ++j) {
        int iw = ow * STRIDE - PAD + j;
        uint2 v = make_uint2(0u, 0u);
        if (ih >= 0 && ih < Hin && iw >= 0 && iw < Win)
          v = *(const uint2*)(in + (((size_t)bI * Hin + ih) * Win + iw) * 4);
        *(uint2*)(dst + j * 4) = v;
      }
    }
    if (tg == 3) {
      for (int c = K; c < KP; c += 4) *(uint2*)&sA[m][c] = make_uint2(0u, 0u);
    }
  } else {
    const int m = tid & 63, dy = tid >> 6;
    const int mg = blockIdx.x * 64 + m;
    const int bI = mg / OHW; int pix = mg - bI * OHW;
    const int oh = pix / OW, ow = pix - oh * OW;
    if (dy < KS) {
      const int ih = oh * STRIDE - PAD + dy;
      __hip_bfloat16* dst = &sA[m][dy * KS * CIN];
      if (ih < 0 || ih >= Hin) {
#pragma unroll
        for (int i = 0; i < KS * CIN / 8; ++i) ((float4*)dst)[i] = f4z;
      } else {
        const __hip_bfloat16* srow = in + ((size_t)bI * Hin + ih) * Win * CIN;
#pragma unroll
        for (int j = 0; j < KS; ++j) {
          int iw = ow * STRIDE - PAD + j;
          if (PAD > 0 && (iw < 0 || iw >= Win)) {
#pragma unroll
            for (int i = 0; i < CIN / 8; ++i) ((float4*)(dst + j * CIN))[i] = f4z;
          } else {
            const float4* s4 = (const float4*)(srow + (size_t)iw * CIN);
#pragma unroll
            for (int i = 0; i < CIN / 8; ++i) ((float4*)(dst + j * CIN))[i] = s4[i];
          }
        }
      }
    } else if (K < KP) {
#pragma unroll
      for (int c = K; c < KP + 8; c += 8) *(float4*)&sA[m][c] = f4z;
    }
  }
  {
    constexpr int NV = NN * KP / 8;
    const float4* w4 = (const float4*)wb;
    for (int i = tid; i < NV; i += 256) {
      int n = i / (KP / 8), c = i - n * (KP / 8);
      *(float4*)&sB[n][c * 8] = w4[i];
    }
  }
  __syncthreads();
  constexpr int NT = NN / 16;
  const int wave = tid >> 6, lane = tid & 63;
  const int fm = lane & 15, quad = lane >> 4;
  const int wm = wave * 16;
  f32x4 acc[NT] = {};
#pragma unroll
  for (int ks = 0; ks < KP / 32; ++ks) {
    short8 a = *(const short8*)&sA[wm + fm][ks * 32 + quad * 8];
#pragma unroll
    for (int j = 0; j < NT; ++j) {
      short8 b = *(const short8*)&sB[j * 16 + fm][ks * 32 + quad * 8];
      acc[j] = __builtin_amdgcn_mfma_f32_16x16x32_bf16(a, b, acc[j], 0, 0, 0);
    }
  }
  const int mg0 = blockIdx.x * 64 + wm + quad * 4;
  const int bI = mg0 / OHW, pix = mg0 - bI * OHW;
#pragma unroll
  for (int j = 0; j < NT; ++j) {
    int n = j * 16 + fm;
    if (n >= NVALID) continue;
    float s = bns[n], bb = bnb[n];
    float v[4];
#pragma unroll
    for (int e = 0; e < 4; ++e) {
      v[e] = acc[j][e] * s + bb;
      if (GELU) v[e] = gelu_f(v[e]);
    }
    if (OUTMODE == 0) {
      float4 v4 = make_float4(v[0], v[1], v[2], v[3]);
      *(float4*)&out[((size_t)(bI * NVALID + n)) * OHW + pix] = v4;
    } else {
      __hip_bfloat16* ob = (__hip_bfloat16*)out;
#pragma unroll
      for (int e = 0; e < 4; ++e)
        ob[((size_t)(bI * OHW + pix + e)) * NN + n] = (__hip_bfloat16)v[e];
    }
  }
}

// ---------------------------------------------------------------------------
// Fused RegionLayerDW for region2, MFMA pointwise. v3:
//  - sIn px-major [10][10][56] (56-short px stride: conflict-spread), staged
//    with 600 coalesced uint4 tasks (was 4800 scalar 2B loads).
//  - dw: thread = (ch-group-of-4, col, row-half); rolling 3-row window,
//    ds_read_b64 per 4ch, b64 sH stores.
//  - pw MFMA operands swapped (A=weights, B=pixels): lane holds 4 consecutive
//    channels per pixel -> uint2 residual loads + uint2 output stores.
// ---------------------------------------------------------------------------
__global__ __launch_bounds__(256, 4) void region2_mfma(
    const __hip_bfloat16* __restrict__ in, const float* __restrict__ dww,
    const float* __restrict__ s1v, const float* __restrict__ b1v,
    const __hip_bfloat16* __restrict__ pwb,
    const float* __restrict__ s2v, const float* __restrict__ b2v,
    __hip_bfloat16* __restrict__ out) {
  __shared__ __align__(16) __hip_bfloat16 sIn[10][10][56];
  __shared__ __align__(16) __hip_bfloat16 sH[64][64];
  __shared__ __align__(16) __hip_bfloat16 sW[48][64];
  __shared__ float sDW[48][9];
  __shared__ float sS1[48], sB1[48], sS2[48], sB2[48];
  const int t = blockIdx.x, sb = blockIdx.y, b = blockIdx.z;
  const int gy = t >> 2, gx = t & 3;
  const int py0 = (sb / 7) * 8, px0 = (sb % 7) * 8;
  const int Y0 = gy * 56, X0 = gx * 56;
  const int tid = threadIdx.x;
  // pw weights -> sW (XOR-8 swizzle, unchanged)
  for (int i = tid; i < 48 * 8; i += 256) {
    int n = i >> 3, g = i & 7;
    float4 v = *(const float4*)&pwb[(size_t)(t * 48 + n) * 64 + g * 8];
    *(float4*)&sW[n][((g ^ (n & 7)) * 8)] = v;
  }
  for (int i = tid; i < 432; i += 256) ((float*)sDW)[i] = dww[t * 432 + i];
  if (tid < 48) {
    sS1[tid] = s1v[t * 48 + tid]; sB1[tid] = b1v[t * 48 + tid];
    sS2[tid] = s2v[t * 48 + tid]; sB2[tid] = b2v[t * 48 + tid];
  }
  // sIn staging: 100 px x 6 uint4 groups, coalesced
  for (int i = tid; i < 600; i += 256) {
    int px = i / 6, grp = i - px * 6;
    int r = px / 10, c = px - r * 10;
    int ly = py0 + r - 1, lx = px0 + c - 1;
    uint4 v = make_uint4(0u, 0u, 0u, 0u);
    if (ly >= 0 && ly < 56 && lx >= 0 && lx < 56)
      v = *(const uint4*)(in + (((size_t)b * 224 + Y0 + ly) * 224 + X0 + lx) * 48 +
                          grp * 8);
    *(uint4*)&sIn[r][c][grp * 8] = v;
  }
  __syncthreads();
  // dw 3x3 + BN + GELU -> sH (A/B-layout rows = pixels)
  if (tid < 192) {
    const int cg = tid >> 4;         // ch group of 4: 0..11
    const int rem = tid & 15;
    const int col = rem >> 1;        // 0..7
    const int rh = rem & 1;          // output rows rh*4 .. rh*4+3
    const int ch0 = cg * 4;
    float wv[4][9], s14[4], b14[4];
#pragma unroll
    for (int c4 = 0; c4 < 4; ++c4) {
#pragma unroll
      for (int q = 0; q < 9; ++q) wv[c4][q] = sDW[ch0 + c4][q];
      s14[c4] = sS1[ch0 + c4]; b14[c4] = sB1[ch0 + c4];
    }
    float win[3][12];  // [rowslot][cc*4 + ch4]
#pragma unroll
    for (int rr = 0; rr < 6; ++rr) {
      int r = rh * 4 + rr;
      float* wr = win[rr % 3];
#pragma unroll
      for (int cc = 0; cc < 3; ++cc) {
        uint2 u = *(const uint2*)&sIn[r][col + cc][ch0];
        wr[cc * 4 + 0] = __uint_as_float(u.x << 16);
        wr[cc * 4 + 1] = __uint_as_float(u.x & 0xffff0000u);
        wr[cc * 4 + 2] = __uint_as_float(u.y << 16);
        wr[cc * 4 + 3] = __uint_as_float(u.y & 0xffff0000u);
      }
      if (rr >= 2) {
        const float* ra = win[(rr - 2) % 3];
        const float* rb = win[(rr - 1) % 3];
        const float* rc = win[rr % 3];
        int px = (rh * 4 + rr - 2) * 8 + col;
        __hip_bfloat16 hv[4];
#pragma unroll
        for (int c4 = 0; c4 < 4; ++c4) {
          float a = ra[c4] * wv[c4][0] + ra[4 + c4] * wv[c4][1] + ra[8 + c4] * wv[c4][2]
                  + rb[c4] * wv[c4][3] + rb[4 + c4] * wv[c4][4] + rb[8 + c4] * wv[c4][5]
                  + rc[c4] * wv[c4][6] + rc[4 + c4] * wv[c4][7] + rc[8 + c4] * wv[c4][8];
          hv[c4] = (__hip_bfloat16)gelu_f(a * s14[c4] + b14[c4]);
        }
        *(uint2*)&sH[px][((cg >> 1) ^ (px & 7)) * 8 + (cg & 1) * 4] = *(uint2*)hv;
      }
    }
  } else {
    // zero-pad sH k-groups 6,7 (ch 48..63): 128 x 16B tasks
    for (int i = tid - 192; i < 128; i += 64) {
      int px = i >> 1, g = 6 + (i & 1);
      *(float4*)&sH[px][(g ^ (px & 7)) * 8] = make_float4(0.f, 0.f, 0.f, 0.f);
    }
  }
  __syncthreads();
  // pw MFMA: A = weights (M=48, 3 frags), B = pixels (N=64, 1 frag/wave)
  const int wave = tid >> 6, lane = tid & 63;
  const int fm = lane & 15, quad = lane >> 4;
  const int px = wave * 16 + fm, pxk = px & 7;
  f32x4 acc[3] = {};
#pragma unroll
  for (int ks = 0; ks < 2; ++ks) {
    short8 hb = *(const short8*)&sH[px][((ks * 4 + quad) ^ pxk) * 8];
#pragma unroll
    for (int m = 0; m < 3; ++m) {
      int wr = m * 16 + fm;
      short8 wa = *(const short8*)&sW[wr][((ks * 4 + quad) ^ (wr & 7)) * 8];
      acc[m] = __builtin_amdgcn_mfma_f32_16x16x32_bf16(wa, hb, acc[m], 0, 0, 0);
    }
  }
  // epilogue: lane = 1 px, 3 x (4 consecutive ch): uint2 residual + uint2 store
  const int row = px >> 3, col = px & 7;
  __hip_bfloat16* obase =
      out + (((size_t)b * 224 + Y0 + py0 + row) * 224 + X0 + px0 + col) * 48;
#pragma unroll
  for (int m = 0; m < 3; ++m) {
    int ch0m = m * 16 + quad * 4;
    uint2 ru = *(const uint2*)&sIn[row + 1][col + 1][ch0m];
    float res[4];
    res[0] = __uint_as_float(ru.x << 16);
    res[1] = __uint_as_float(ru.x & 0xffff0000u);
    res[2] = __uint_as_float(ru.y << 16);
    res[3] = __uint_as_float(ru.y & 0xffff0000u);
    __hip_bfloat16 vb[4];
#pragma unroll
    for (int e = 0; e < 4; ++e) {
      int ch = ch0m + e;
      float v = acc[m][e] * sS2[ch] + sB2[ch] + res[e];
      vb[e] = (__hip_bfloat16)gelu_f(v);
    }
    *(uint2*)&obase[ch0m] = *(uint2*)vb;
  }
}

// ---------------------------------------------------------------------------
// Patch-GEMM via MFMA (b3 + branch2-conv2). Unchanged.
// ---------------------------------------------------------------------------
template<int PS, int IMGW, int KTOT, int KSL, bool ATOMIC>
__global__ __launch_bounds__(256) void patch_gemm_mfma(
    const __hip_bfloat16* __restrict__ A, const __hip_bfloat16* __restrict__ Wb,
    const float* __restrict__ scale, const float* __restrict__ bias,
    float* __restrict__ out, int M, int ch0) {
  constexpr int RUN = PS * 48;
  __shared__ __align__(16) __hip_bfloat16 sA[64][64];
  __shared__ __align__(16) __hip_bfloat16 sB[64][64];
  const int tid = threadIdx.x;
  const int m0 = blockIdx.x * 64, n0 = blockIdx.y * 64;
  const int kBase = blockIdx.z * KSL;
  const int mi = tid >> 2, seg = tid & 3;
  int m = m0 + mi; int mc = (m < M) ? m : (M - 1);
  int bI = mc / 196; int r = mc - bI * 196;
  int oh = r / 14, ow = r - oh * 14;
  const __hip_bfloat16* Abase =
      A + (((size_t)bI * IMGW + oh * PS) * IMGW + ow * PS) * 48;
  const __hip_bfloat16* Wrow = Wb + (size_t)(n0 + mi) * KTOT;
  const int wave = tid >> 6, lane = tid & 63;
  const int wm = (wave & 1) * 32, wn = (wave >> 1) * 32;
  const int fm = lane & 15, quad = lane >> 4;
  const int sw = fm & 7;
  f32x4 acc[2][2] = {};
  for (int k0 = kBase; k0 < kBase + KSL; k0 += 64) {
    int dy = k0 / RUN, rem = k0 - dy * RUN;
    __syncthreads();
    {
      const __hip_bfloat16* p = Abase + (size_t)dy * IMGW * 48 + rem + seg * 16;
      float4 v0 = *(const float4*)p;
      float4 v1 = *(const float4*)(p + 8);
      int key = mi & 7;
      *(float4*)&sA[mi][((seg * 2) ^ key) * 8] = v0;
      *(float4*)&sA[mi][((seg * 2 + 1) ^ key) * 8] = v1;
      const __hip_bfloat16* q = Wrow + k0 + seg * 16;
      float4 w0 = *(const float4*)q;
      float4 w1 = *(const float4*)(q + 8);
      *(float4*)&sB[mi][((seg * 2) ^ key) * 8] = w0;
      *(float4*)&sB[mi][((seg * 2 + 1) ^ key) * 8] = w1;
    }
    __syncthreads();
#pragma unroll
    for (int ks = 0; ks < 2; ++ks) {
      int cg = (ks * 4 + quad) ^ sw;
#pragma unroll
      for (int i = 0; i < 2; ++i) {
        short8 a = *(const short8*)&sA[wm + i * 16 + fm][cg * 8];
#pragma unroll
        for (int j = 0; j < 2; ++j) {
          short8 b = *(const short8*)&sB[wn + j * 16 + fm][cg * 8];
          acc[i][j] = __builtin_amdgcn_mfma_f32_16x16x32_bf16(a, b, acc[i][j], 0, 0, 0);
        }
      }
    }
  }
#pragma unroll
  for (int i = 0; i < 2; ++i) {
#pragma unroll
    for (int j = 0; j < 2; ++j) {
      int gn = n0 + wn + j * 16 + fm;
      float sc = scale[gn];
#pragma unroll
      for (int e = 0; e < 4; ++e) {
        int gm = m0 + wm + i * 16 + quad * 4 + e;
        if (gm < M) {
          if (ATOMIC)
            atomicAdd(&out[(size_t)gm * 768 + ch0 + gn], acc[i][j][e] * sc);
          else
            out[(size_t)gm * 768 + ch0 + gn] = acc[i][j][e] * sc + bias[gn];
        }
      }
    }
  }
}

__global__ void init_b3(float* __restrict__ out, const float* __restrict__ bias) {
  int i = blockIdx.x * 256 + threadIdx.x;
  if (i < 16 * 196 * 256) {
    int n = i & 255, bp = i >> 8;
    out[bp * 768 + 512 + n] = bias[n];
  }
}

// OIHW fp32 -> [N][KP] bf16 with k=(dy*ks+dx)*Cin+ic, zero-padded to KP
__global__ void reorder_w_k(const float* __restrict__ w, __hip_bfloat16* __restrict__ o,
                            int N, int Cin, int ks, int KP) {
  int i = blockIdx.x * 256 + threadIdx.x;
  if (i >= N * KP) return;
  int n = i / KP, k = i - n * KP;
  float v = 0.f;
  int K = ks * ks * Cin;
  if (k < K) {
    int dy = k / (ks * Cin); int r = k - dy * ks * Cin;
    int dx = r / Cin, ic = r - dx * Cin;
    v = w[((n * Cin + ic) * ks + dy) * ks + dx];
  }
  o[i] = (__hip_bfloat16)v;
}

// OIHW fp32 -> [Nout][KP] bf16 with channel padding
__global__ void reorder_w4(const float* __restrict__ w, __hip_bfloat16* __restrict__ o,
                           int Nout, int Nreal, int Cp, int Cr, int ks, int KP) {
  int i = blockIdx.x * 256 + threadIdx.x;
  if (i >= Nout * KP) return;
  int n = i / KP, k = i - n * KP;
  float v = 0.f;
  if (n < Nreal && k < ks * ks * Cp) {
    int dy = k / (ks * Cp); int r = k - dy * ks * Cp;
    int dx = r / Cp, ic = r - dx * Cp;
    if (ic < Cr) v = w[((n * Cr + ic) * ks + dy) * ks + dx];
  }
  o[i] = (__hip_bfloat16)v;
}

// region2 pw weights [16][48][48] fp32 -> [16][48][64] bf16 (K-padded)
__global__ void rw_pw(const float* __restrict__ pw, __hip_bfloat16* __restrict__ o) {
  int i = blockIdx.x * 256 + threadIdx.x;
  if (i >= 16 * 48 * 64) return;
  int t = i / 3072, r = i - t * 3072;
  int n = r >> 6, k = r & 63;
  float v = (k < 48) ? pw[(t * 48 + n) * 48 + k] : 0.f;
  o[i] = (__hip_bfloat16)v;
}

// x [16,3,224,224] fp32 -> [16,224,224,4] bf16 (ch3 = 0)
__global__ void xcvt(const float* __restrict__ x, __hip_bfloat16* __restrict__ o) {
  int i = blockIdx.x * 256 + threadIdx.x;
  if (i >= 802816) return;
  int b = i / 50176, p = i - b * 50176;
  const float* src = x + (size_t)b * 150528 + p;
  __hip_bfloat16 v[4];
  v[0] = (__hip_bfloat16)src[0];
  v[1] = (__hip_bfloat16)src[50176];
  v[2] = (__hip_bfloat16)src[100352];
  v[3] = (__hip_bfloat16)0.0f;
  *(uint2*)&o[(size_t)i * 4] = *(uint2*)v;
}

// ---------------------------------------------------------------------------
// Fused RegionLayerDW (VALU version — region1 only, unchanged)
// ---------------------------------------------------------------------------
template<int C, int TH, int TW, int G, int BWc, int MINW, bool NHWC, typename OutT>
__global__ __launch_bounds__(256, MINW) void region_k(
    const float* __restrict__ in, const float* __restrict__ dww,
    const float* __restrict__ s1v, const float* __restrict__ b1v,
    const float* __restrict__ pwv, const float* __restrict__ s2v,
    const float* __restrict__ b2v, OutT* __restrict__ out) {
  constexpr int P = 8 * BWc;
  constexpr int FULL = G * TH;
  constexpr int NBX = TW / BWc;
  constexpr int PADW = (BWc == 14) ? 17 : 18;
  constexpr int HROW = BWc * 12;
  static_assert(TH % 8 == 0 && TW % BWc == 0, "tile divisibility");
  __shared__ __align__(16) float sIn[C][10][PADW];
  __shared__ __align__(16) float sH[C][HROW];
  __shared__ __align__(16) float sPWT[C][C];
  __shared__ float sDW[C][9];
  __shared__ float sS1[C], sB1[C], sS2[C], sB2[C];
  const int t = blockIdx.x, sb = blockIdx.y, b = blockIdx.z;
  const int gy = t / G, gx = t % G;
  const int py0 = (sb / NBX) * 8, px0 = (sb % NBX) * BWc;
  const int tid = threadIdx.x;
  for (int i = tid; i < C * C; i += 256) {
    int o = i / C, c = i - o * C;
    sPWT[c][o] = pwv[t * C * C + i];
  }
  for (int i = tid; i < C * 9; i += 256) ((float*)sDW)[i] = dww[t * C * 9 + i];
  for (int i = tid; i < C; i += 256) {
    sS1[i] = s1v[t * C + i]; sB1[i] = b1v[t * C + i];
    sS2[i] = s2v[t * C + i]; sB2[i] = b2v[t * C + i];
  }
  constexpr int HW2 = 10 * (BWc + 2);
  for (int i = tid; i < C * HW2; i += 256) {
    int c = i / HW2; int rr = i - c * HW2;
    int iy = rr / (BWc + 2), ix = rr - iy * (BWc + 2);
    int ly = py0 + iy - 1, lx = px0 + ix - 1;
    float v = 0.0f;
    if (ly >= 0 && ly < TH && lx >= 0 && lx < TW)
      v = in[((size_t)(b * C + c) * FULL + gy * TH + ly) * FULL + gx * TW + lx];
    sIn[c][iy][ix] = v;
  }
  __syncthreads();
  for (int i = tid; i < C * P; i += 256) {
    int c = i / P, p = i - c * P;
    int col = p >> 3, row = p & 7;
    float a = 0.0f;
#pragma unroll
    for (int ky = 0; ky < 3; ++ky)
#pragma unroll
      for (int kx = 0; kx < 3; ++kx)
        a += sIn[c][row + ky][col + kx] * sDW[c][ky * 3 + kx];
    sH[c][col * 12 + row] = gelu_f(a * sS1[c] + sB1[c]);
  }
  __syncthreads();
  const int og = tid >> 4, pg = tid & 15;
  if (pg < BWc && og < C / 4) {
    const int o0 = og * 4;
    float acc[4][8] = {};
#pragma unroll 4
    for (int c = 0; c < C; ++c) {
      float4 h0 = *(const float4*)&sH[c][pg * 12];
      float4 h1 = *(const float4*)&sH[c][pg * 12 + 4];
      float4 w4 = *(const float4*)&sPWT[c][o0];
      float hh[8] = {h0.x, h0.y, h0.z, h0.w, h1.x, h1.y, h1.z, h1.w};
      float ww[4] = {w4.x, w4.y, w4.z, w4.w};
#pragma unroll
      for (int j = 0; j < 4; ++j)
#pragma unroll
        for (int e = 0; e < 8; ++e) acc[j][e] += ww[j] * hh[e];
    }
    const int Ybase = gy * TH + py0, X = gx * TW + px0 + pg;
    float vv[4][8];
#pragma unroll
    for (int j = 0; j < 4; ++j) {
      int o = o0 + j;
      float s = sS2[o], bb = sB2[o];
#pragma unroll
      for (int e = 0; e < 8; ++e)
        vv[j][e] = gelu_f(acc[j][e] * s + bb + sIn[o][e + 1][pg + 1]);
    }
    if (NHWC) {
#pragma unroll
      for (int e = 0; e < 8; ++e) {
        __hip_bfloat16 tmp[4];
#pragma unroll
        for (int j = 0; j < 4; ++j) tmp[j] = (__hip_bfloat16)vv[j][e];
        __hip_bfloat16* dst =
            (__hip_bfloat16*)out + (((size_t)b * FULL + Ybase + e) * FULL + X) * C + o0;
        *(uint2*)dst = *(uint2*)tmp;
      }
    } else {
#pragma unroll
      for (int j = 0; j < 4; ++j) {
        int o = o0 + j;
#pragma unroll
        for (int e = 0; e < 8; ++e)
          out[((size_t)(b * C + o) * FULL + Ybase + e) * FULL + X] = (OutT)vv[j][e];
      }
    }
  }
}

// ---------------------------------------------------------------------------
extern "C" void kernel_launch(void* const* d_in, const int* in_sizes, int n_in,
                              void* d_out, int out_size, void* d_ws, size_t ws_size,
                              hipStream_t stream) {
  const float* x     = (const float*)d_in[0];
  const float* r1_w  = (const float*)d_in[1];
  const float* r1_s  = (const float*)d_in[2];
  const float* r1_b  = (const float*)d_in[3];
  const float* r1_dw = (const float*)d_in[4];
  const float* r1_s1 = (const float*)d_in[5];
  const float* r1_b1 = (const float*)d_in[6];
  const float* r1_pw = (const float*)d_in[7];
  const float* r1_s2 = (const float*)d_in[8];
  const float* r1_b2 = (const float*)d_in[9];
  const float* r2_w  = (const float*)d_in[10];
  const float* r2_s  = (const float*)d_in[11];
  const float* r2_b  = (const float*)d_in[12];
  const float* r2_dw = (const float*)d_in[13];
  const float* r2_s1 = (const float*)d_in[14];
  const float* r2_b1 = (const float*)d_in[15];
  const float* r2_pw = (const float*)d_in[16];
  const float* r2_s2 = (const float*)d_in[17];
  const float* r2_b2 = (const float*)d_in[18];
  const float* h1_w1 = (const float*)d_in[19];
  const float* h1_s1 = (const float*)d_in[20];
  const float* h1_b1 = (const float*)d_in[21];
  const float* h1_w2 = (const float*)d_in[22];
  const float* h1_s2 = (const float*)d_in[23];
  const float* h1_b2 = (const float*)d_in[24];
  const float* h1_w3 = (const float*)d_in[25];
  const float* h1_s3 = (const float*)d_in[26];
  const float* h1_b3 = (const float*)d_in[27];
  const float* h2_w1 = (const float*)d_in[28];
  const float* h2_s1 = (const float*)d_in[29];
  const float* h2_b1 = (const float*)d_in[30];
  const float* h2_w2 = (const float*)d_in[31];
  const float* h2_s2 = (const float*)d_in[32];
  const float* h2_b2 = (const float*)d_in[33];
  const float* h3_w  = (const float*)d_in[34];
  const float* h3_s  = (const float*)d_in[35];
  const float* h3_b  = (const float*)d_in[36];
  float* out = (float*)d_out;

  // Workspace (float-slot offsets). FULL-BATCH layout, peak 222.8 MB.
  float* F = (float*)d_ws;
  __hip_bfloat16* R1b   = (__hip_bfloat16*)F;                    // [16,224,224,24]
  __hip_bfloat16* T1b   = (__hip_bfloat16*)(F + 9633792);        // [16,224,224,48]
  float* T1f            = F + 9633792;   // fp32 alias [16,24,224,224]
  __hip_bfloat16* T2b   = (__hip_bfloat16*)(F + 28901376);       // [16,224,224,48]
  __hip_bfloat16* h3wb  = (__hip_bfloat16*)(F + 48168960);       // [256][12288]
  __hip_bfloat16* r2wb  = (__hip_bfloat16*)(F + 49741824);       // [48][224]
  __hip_bfloat16* h2w1b = (__hip_bfloat16*)(F + 49747200);       // [48][384]
  __hip_bfloat16* pw2wb = (__hip_bfloat16*)(F + 49756416);       // [16][48][64]
  __hip_bfloat16* r1wb  = (__hip_bfloat16*)(F + 49780992);       // [32][128]
  __hip_bfloat16* h2w2b = (__hip_bfloat16*)(F + 49783040);       // [256][768]
  __hip_bfloat16* xb    = (__hip_bfloat16*)(F + 49881344);       // [16,224,224,4]
  __hip_bfloat16* S1b   = (__hip_bfloat16*)(F + 51486976);       // [16,56,56,48]
  float* S1             = F + 52691200;                          // [16,48,56,56]
  float* S2             = F + 55099648;                          // [16,48,28,28]

  dim3 blk(256);

  // ---- input conversion + weight reorders
  xcvt<<<dim3(3136), blk, 0, stream>>>(x, xb);
  reorder_w_k<<<dim3(12288), blk, 0, stream>>>(h3_w, h3wb, 256, 48, 16, 12288);
  reorder_w_k<<<dim3(42), blk, 0, stream>>>(r2_w, r2wb, 48, 24, 3, 224);
  reorder_w_k<<<dim3(72), blk, 0, stream>>>(h2_w1, h2w1b, 48, 24, 4, 384);
  reorder_w_k<<<dim3(768), blk, 0, stream>>>(h2_w2, h2w2b, 256, 48, 4, 768);
  reorder_w4<<<dim3(16), blk, 0, stream>>>(r1_w, r1wb, 32, 24, 4, 3, 5, 128);
  rw_pw<<<dim3(192), blk, 0, stream>>>(r2_pw, pw2wb);

  // ---- region1 chain, FULL BATCH: conv5 MFMA (xb -> T1f), region1 -> R1b
  nhwc_conv_mfma<4, 5, 1, 2, 32, 128, true, 0, 24><<<dim3(12544), blk, 0, stream>>>(
      xb, r1wb, r1_s, r1_b, T1f, 224, 224, 224, 50176);
  region_k<24, 32, 32, 7, 16, 4, true, __hip_bfloat16>
      <<<dim3(49, 8, 16), blk, 0, stream>>>(
      T1f, r1_dw, r1_s1, r1_b1, r1_pw, r1_s2, r1_b2, R1b);
  // ---- branch2: R1b -> S1b bf16 NHWC -> out[ch 256:512]
  nhwc_conv_mfma<24, 4, 4, 0, 48, 384, true, 1><<<dim3(784), blk, 0, stream>>>(
      R1b, h2w1b, h2_s1, h2_b1, (float*)S1b, 224, 224, 56, 3136);
  patch_gemm_mfma<4, 56, 768, 768, false><<<dim3(49, 4, 1), blk, 0, stream>>>(
      S1b, h2w2b, h2_s2, h2_b2, out, 3136, 256);
  // ---- branch1: x -> S1 -> S2 -> out[ch 0:256] (fp32, small)
  convgemm_k<false, true, false><<<dim3(784, 1), blk, 0, stream>>>(
      x, h1_w1, h1_s1, h1_b1, S1, 3, 224, 224, 4, 4, 0, 2, 56, 56, 48, 48, 0);
  convgemm_k<false, true, false><<<dim3(196, 1), blk, 0, stream>>>(
      S1, h1_w2, h1_s2, h1_b2, S2, 48, 56, 56, 2, 2, 0, 1, 28, 28, 48, 192, 0);
  convgemm_k<false, false, true><<<dim3(49, 4), blk, 0, stream>>>(
      S2, h1_w3, h1_s3, h1_b3, out, 48, 28, 28, 2, 2, 0, 1, 14, 14, 256, 192, 0);
  // ---- branch3 FULL BATCH: conv3 -> region2 -> b3 patch-GEMM (split-K)
  init_b3<<<dim3(3136), blk, 0, stream>>>(out, h3_b);
  nhwc_conv_mfma<24, 3, 1, 1, 48, 224, true, 1><<<dim3(12544), blk, 0, stream>>>(
      R1b, r2wb, r2_s, r2_b, (float*)T1b, 224, 224, 224, 50176);
  region2_mfma<<<dim3(16, 49, 16), blk, 0, stream>>>(
      T1b, r2_dw, r2_s1, r2_b1, pw2wb, r2_s2, r2_b2, T2b);
  patch_gemm_mfma<16, 224, 12288, 1536, true><<<dim3(49, 4, 8), blk, 0, stream>>>(
      T2b, h3wb, h3_s, h3_b, out, 3136, 512);
  (void)in_sizes; (void)n_in; (void)out_size; (void)ws_size;
}

// Round 11
// 573.118 us; speedup vs baseline: 4.9159x; 1.0938x over previous
//
#include <hip/hip_runtime.h>
#include <hip/hip_bf16.h>
#include <math.h>

typedef __attribute__((ext_vector_type(8))) short short8;
typedef __attribute__((ext_vector_type(4))) float f32x4;

// Exact-erf GELU via Abramowitz-Stegun 7.1.26 (|erf err| <= 1.5e-7)
__device__ __forceinline__ float gelu_f(float x) {
  float ax = fabsf(x);
  float z = ax * 0.70710678118654752f;
  float t = __builtin_amdgcn_rcpf(1.0f + 0.3275911f * z);
  float p = t * (0.254829592f +
           t * (-0.284496736f +
           t * (1.421413741f +
           t * (-1.453152027f + t * 1.061405429f))));
  float e = __expf(-z * z);
  float erf_abs = 1.0f - p * e;
  return 0.5f * x + 0.5f * ax * erf_abs;
}

// ---------------------------------------------------------------------------
// Generic conv-as-implicit-GEMM fp32 (branch1 only)
// ---------------------------------------------------------------------------
template<bool TBL, bool GELU, bool TOOUT>
__global__ __launch_bounds__(256) void convgemm_k(
    const float* __restrict__ in, const float* __restrict__ w,
    const float* __restrict__ bns, const float* __restrict__ bnb,
    float* __restrict__ out,
    int Cin, int H, int W, int ks, int stride, int pad, int ls,
    int OH, int OW, int N, int K, int ch0) {
  __shared__ __align__(16) float sA[16][64];
  __shared__ __align__(16) float sB[16][64];
  __shared__ int sTbl[256];
  const int tid = threadIdx.x;
  if (TBL) {
    int kk2 = ks * ks;
    for (int k = tid; k < K; k += 256) {
      int ic = k / kk2, r = k - ic * kk2;
      sTbl[k] = (ic << 16) | ((r / ks) << 8) | (r % ks);
    }
  }
  const int m0 = blockIdx.x * 64, n0 = blockIdx.y * 64;
  const int mm = tid >> 2, kq = tid & 3;
  const int OHW = OH * OW, HW = H * W;
  int m = m0 + mm;
  int bI = m / OHW; int r = m - bI * OHW;
  int oh = r / OW;  int ow = r - oh * OW;
  const int ihBase = oh * stride - pad, iwBase = ow * stride - pad;
  const int inBase = bI * Cin * HW;
  const int tm = tid & 15, tn = tid >> 4;
  float acc[4][4] = {};
  for (int k0 = 0; k0 < K; k0 += 16) {
    __syncthreads();
#pragma unroll
    for (int i = 0; i < 4; ++i) {
      int kk = kq * 4 + i, k = k0 + kk;
      float v = 0.0f;
      if (k < K) {
        int ic, dy, dx;
        if (TBL) {
          int tv = sTbl[k]; ic = tv >> 16; dy = (tv >> 8) & 255; dx = tv & 255;
        } else {
          ic = k >> (2 * ls);
          int r2 = k & ((1 << (2 * ls)) - 1);
          dy = r2 >> ls; dx = r2 & ((1 << ls) - 1);
        }
        int ih = ihBase + dy, iw = iwBase + dx;
        if (ih >= 0 && ih < H && iw >= 0 && iw < W)
          v = in[inBase + ic * HW + ih * W + iw];
      }
      sA[kk][mm] = v;
    }
#pragma unroll
    for (int i = 0; i < 4; ++i) {
      int kk = kq * 4 + i, k = k0 + kk;
      int n = n0 + mm;
      float v = 0.0f;
      if (n < N && k < K) v = w[n * K + k];
      sB[kk][mm] = v;
    }
    __syncthreads();
#pragma unroll
    for (int kk = 0; kk < 16; ++kk) {
      float4 a4 = *(const float4*)&sA[kk][tm * 4];
      float4 b4 = *(const float4*)&sB[kk][tn * 4];
      acc[0][0] += a4.x * b4.x; acc[0][1] += a4.x * b4.y;
      acc[0][2] += a4.x * b4.z; acc[0][3] += a4.x * b4.w;
      acc[1][0] += a4.y * b4.x; acc[1][1] += a4.y * b4.y;
      acc[1][2] += a4.y * b4.z; acc[1][3] += a4.y * b4.w;
      acc[2][0] += a4.z * b4.x; acc[2][1] += a4.z * b4.y;
      acc[2][2] += a4.z * b4.z; acc[2][3] += a4.z * b4.w;
      acc[3][0] += a4.w * b4.x; acc[3][1] += a4.w * b4.y;
      acc[3][2] += a4.w * b4.z; acc[3][3] += a4.w * b4.w;
    }
  }
#pragma unroll
  for (int i = 0; i < 4; ++i) {
    int mI = m0 + tm * 4 + i;
    int bO = mI / OHW; int rr = mI - bO * OHW;
#pragma unroll
    for (int j = 0; j < 4; ++j) {
      int n = n0 + tn * 4 + j;
      if (n < N) {
        float v = acc[i][j] * bns[n] + bnb[n];
        if (GELU) v = gelu_f(v);
        if (TOOUT) {
          out[(bO * OHW + rr) * 768 + ch0 + n] = v;  // OHW==196
        } else {
          int oh2 = rr / OW, ow2 = rr - oh2 * OW;
          out[((bO * N + n) * OH + oh2) * OW + ow2] = v;
        }
      }
    }
  }
}

// ---------------------------------------------------------------------------
// NHWC bf16 implicit-GEMM conv via MFMA.
// OUTMODE: 0 = NCHW fp32 (ch stride NVALID), 1 = NHWC bf16 (ch stride NVALID).
// ---------------------------------------------------------------------------
template<int CIN, int KS, int STRIDE, int PAD, int NN, int KP, bool GELU,
         int OUTMODE, int NVALID = NN>
__global__ __launch_bounds__(256) void nhwc_conv_mfma(
    const __hip_bfloat16* __restrict__ in, const __hip_bfloat16* __restrict__ wb,
    const float* __restrict__ bns, const float* __restrict__ bnb,
    float* __restrict__ out, int Hin, int Win, int OW, int OHW) {
  constexpr int K = KS * KS * CIN;
  constexpr int LROW = KP + 8;
  __shared__ __align__(16) __hip_bfloat16 sA[64][LROW];
  __shared__ __align__(16) __hip_bfloat16 sB[NN][LROW];
  const int tid = threadIdx.x;
  const float4 f4z = make_float4(0.f, 0.f, 0.f, 0.f);
  if constexpr (CIN == 4) {
    const int m = tid & 63, tg = tid >> 6;
    const int mg = blockIdx.x * 64 + m;
    const int bI = mg / OHW; int pix = mg - bI * OHW;
    const int oh = pix / OW, ow = pix - oh * OW;
    for (int dy = tg; dy < KS; dy += 4) {
      const int ih = oh * STRIDE - PAD + dy;
      __hip_bfloat16* dst = &sA[m][dy * KS * 4];
#pragma unroll
      for (int j = 0; j < KS; ++j) {
        int iw = ow * STRIDE - PAD + j;
        uint2 v = make_uint2(0u, 0u);
        if (ih >= 0 && ih < Hin && iw >= 0 && iw < Win)
          v = *(const uint2*)(in + (((size_t)bI * Hin + ih) * Win + iw) * 4);
        *(uint2*)(dst + j * 4) = v;
      }
    }
    if (tg == 3) {
      for (int c = K; c < KP; c += 4) *(uint2*)&sA[m][c] = make_uint2(0u, 0u);
    }
  } else {
    const int m = tid & 63, dy = tid >> 6;
    const int mg = blockIdx.x * 64 + m;
    const int bI = mg / OHW; int pix = mg - bI * OHW;
    const int oh = pix / OW, ow = pix - oh * OW;
    if (dy < KS) {
      const int ih = oh * STRIDE - PAD + dy;
      __hip_bfloat16* dst = &sA[m][dy * KS * CIN];
      if (ih < 0 || ih >= Hin) {
#pragma unroll
        for (int i = 0; i < KS * CIN / 8; ++i) ((float4*)dst)[i] = f4z;
      } else {
        const __hip_bfloat16* srow = in + ((size_t)bI * Hin + ih) * Win * CIN;
#pragma unroll
        for (int j = 0; j < KS; ++j) {
          int iw = ow * STRIDE - PAD + j;
          if (PAD > 0 && (iw < 0 || iw >= Win)) {
#pragma unroll
            for (int i = 0; i < CIN / 8; ++i) ((float4*)(dst + j * CIN))[i] = f4z;
          } else {
            const float4* s4 = (const float4*)(srow + (size_t)iw * CIN);
#pragma unroll
            for (int i = 0; i < CIN / 8; ++i) ((float4*)(dst + j * CIN))[i] = s4[i];
          }
        }
      }
    } else if (K < KP) {
#pragma unroll
      for (int c = K; c < KP + 8; c += 8) *(float4*)&sA[m][c] = f4z;
    }
  }
  {
    constexpr int NV = NN * KP / 8;
    const float4* w4 = (const float4*)wb;
    for (int i = tid; i < NV; i += 256) {
      int n = i / (KP / 8), c = i - n * (KP / 8);
      *(float4*)&sB[n][c * 8] = w4[i];
    }
  }
  __syncthreads();
  constexpr int NT = NN / 16;
  const int wave = tid >> 6, lane = tid & 63;
  const int fm = lane & 15, quad = lane >> 4;
  const int wm = wave * 16;
  f32x4 acc[NT] = {};
#pragma unroll
  for (int ks = 0; ks < KP / 32; ++ks) {
    short8 a = *(const short8*)&sA[wm + fm][ks * 32 + quad * 8];
#pragma unroll
    for (int j = 0; j < NT; ++j) {
      short8 b = *(const short8*)&sB[j * 16 + fm][ks * 32 + quad * 8];
      acc[j] = __builtin_amdgcn_mfma_f32_16x16x32_bf16(a, b, acc[j], 0, 0, 0);
    }
  }
  const int mg0 = blockIdx.x * 64 + wm + quad * 4;
  const int bI = mg0 / OHW, pix = mg0 - bI * OHW;
#pragma unroll
  for (int j = 0; j < NT; ++j) {
    int n = j * 16 + fm;
    if (n >= NVALID) continue;
    float s = bns[n], bb = bnb[n];
    float v[4];
#pragma unroll
    for (int e = 0; e < 4; ++e) {
      v[e] = acc[j][e] * s + bb;
      if (GELU) v[e] = gelu_f(v[e]);
    }
    if (OUTMODE == 0) {
      float4 v4 = make_float4(v[0], v[1], v[2], v[3]);
      *(float4*)&out[((size_t)(bI * NVALID + n)) * OHW + pix] = v4;
    } else {
      __hip_bfloat16* ob = (__hip_bfloat16*)out;
#pragma unroll
      for (int e = 0; e < 4; ++e)
        ob[((size_t)(bI * OHW + pix + e)) * NVALID + n] = (__hip_bfloat16)v[e];
    }
  }
}

// ---------------------------------------------------------------------------
// Fused RegionLayerDW for region2 (R10 v3, unchanged — validated)
// ---------------------------------------------------------------------------
__global__ __launch_bounds__(256, 4) void region2_mfma(
    const __hip_bfloat16* __restrict__ in, const float* __restrict__ dww,
    const float* __restrict__ s1v, const float* __restrict__ b1v,
    const __hip_bfloat16* __restrict__ pwb,
    const float* __restrict__ s2v, const float* __restrict__ b2v,
    __hip_bfloat16* __restrict__ out) {
  __shared__ __align__(16) __hip_bfloat16 sIn[10][10][56];
  __shared__ __align__(16) __hip_bfloat16 sH[64][64];
  __shared__ __align__(16) __hip_bfloat16 sW[48][64];
  __shared__ float sDW[48][9];
  __shared__ float sS1[48], sB1[48], sS2[48], sB2[48];
  const int t = blockIdx.x, sb = blockIdx.y, b = blockIdx.z;
  const int gy = t >> 2, gx = t & 3;
  const int py0 = (sb / 7) * 8, px0 = (sb % 7) * 8;
  const int Y0 = gy * 56, X0 = gx * 56;
  const int tid = threadIdx.x;
  for (int i = tid; i < 48 * 8; i += 256) {
    int n = i >> 3, g = i & 7;
    float4 v = *(const float4*)&pwb[(size_t)(t * 48 + n) * 64 + g * 8];
    *(float4*)&sW[n][((g ^ (n & 7)) * 8)] = v;
  }
  for (int i = tid; i < 432; i += 256) ((float*)sDW)[i] = dww[t * 432 + i];
  if (tid < 48) {
    sS1[tid] = s1v[t * 48 + tid]; sB1[tid] = b1v[t * 48 + tid];
    sS2[tid] = s2v[t * 48 + tid]; sB2[tid] = b2v[t * 48 + tid];
  }
  for (int i = tid; i < 600; i += 256) {
    int px = i / 6, grp = i - px * 6;
    int r = px / 10, c = px - r * 10;
    int ly = py0 + r - 1, lx = px0 + c - 1;
    uint4 v = make_uint4(0u, 0u, 0u, 0u);
    if (ly >= 0 && ly < 56 && lx >= 0 && lx < 56)
      v = *(const uint4*)(in + (((size_t)b * 224 + Y0 + ly) * 224 + X0 + lx) * 48 +
                          grp * 8);
    *(uint4*)&sIn[r][c][grp * 8] = v;
  }
  __syncthreads();
  if (tid < 192) {
    const int cg = tid >> 4;
    const int rem = tid & 15;
    const int col = rem >> 1;
    const int rh = rem & 1;
    const int ch0 = cg * 4;
    float wv[4][9], s14[4], b14[4];
#pragma unroll
    for (int c4 = 0; c4 < 4; ++c4) {
#pragma unroll
      for (int q = 0; q < 9; ++q) wv[c4][q] = sDW[ch0 + c4][q];
      s14[c4] = sS1[ch0 + c4]; b14[c4] = sB1[ch0 + c4];
    }
    float win[3][12];
#pragma unroll
    for (int rr = 0; rr < 6; ++rr) {
      int r = rh * 4 + rr;
      float* wr = win[rr % 3];
#pragma unroll
      for (int cc = 0; cc < 3; ++cc) {
        uint2 u = *(const uint2*)&sIn[r][col + cc][ch0];
        wr[cc * 4 + 0] = __uint_as_float(u.x << 16);
        wr[cc * 4 + 1] = __uint_as_float(u.x & 0xffff0000u);
        wr[cc * 4 + 2] = __uint_as_float(u.y << 16);
        wr[cc * 4 + 3] = __uint_as_float(u.y & 0xffff0000u);
      }
      if (rr >= 2) {
        const float* ra = win[(rr - 2) % 3];
        const float* rb = win[(rr - 1) % 3];
        const float* rc = win[rr % 3];
        int px = (rh * 4 + rr - 2) * 8 + col;
        __hip_bfloat16 hv[4];
#pragma unroll
        for (int c4 = 0; c4 < 4; ++c4) {
          float a = ra[c4] * wv[c4][0] + ra[4 + c4] * wv[c4][1] + ra[8 + c4] * wv[c4][2]
                  + rb[c4] * wv[c4][3] + rb[4 + c4] * wv[c4][4] + rb[8 + c4] * wv[c4][5]
                  + rc[c4] * wv[c4][6] + rc[4 + c4] * wv[c4][7] + rc[8 + c4] * wv[c4][8];
          hv[c4] = (__hip_bfloat16)gelu_f(a * s14[c4] + b14[c4]);
        }
        *(uint2*)&sH[px][((cg >> 1) ^ (px & 7)) * 8 + (cg & 1) * 4] = *(uint2*)hv;
      }
    }
  } else {
    for (int i = tid - 192; i < 128; i += 64) {
      int px = i >> 1, g = 6 + (i & 1);
      *(float4*)&sH[px][(g ^ (px & 7)) * 8] = make_float4(0.f, 0.f, 0.f, 0.f);
    }
  }
  __syncthreads();
  const int wave = tid >> 6, lane = tid & 63;
  const int fm = lane & 15, quad = lane >> 4;
  const int px = wave * 16 + fm, pxk = px & 7;
  f32x4 acc[3] = {};
#pragma unroll
  for (int ks = 0; ks < 2; ++ks) {
    short8 hb = *(const short8*)&sH[px][((ks * 4 + quad) ^ pxk) * 8];
#pragma unroll
    for (int m = 0; m < 3; ++m) {
      int wr = m * 16 + fm;
      short8 wa = *(const short8*)&sW[wr][((ks * 4 + quad) ^ (wr & 7)) * 8];
      acc[m] = __builtin_amdgcn_mfma_f32_16x16x32_bf16(wa, hb, acc[m], 0, 0, 0);
    }
  }
  const int row = px >> 3, col = px & 7;
  __hip_bfloat16* obase =
      out + (((size_t)b * 224 + Y0 + py0 + row) * 224 + X0 + px0 + col) * 48;
#pragma unroll
  for (int m = 0; m < 3; ++m) {
    int ch0m = m * 16 + quad * 4;
    uint2 ru = *(const uint2*)&sIn[row + 1][col + 1][ch0m];
    float res[4];
    res[0] = __uint_as_float(ru.x << 16);
    res[1] = __uint_as_float(ru.x & 0xffff0000u);
    res[2] = __uint_as_float(ru.y << 16);
    res[3] = __uint_as_float(ru.y & 0xffff0000u);
    __hip_bfloat16 vb[4];
#pragma unroll
    for (int e = 0; e < 4; ++e) {
      int ch = ch0m + e;
      float v = acc[m][e] * sS2[ch] + sB2[ch] + res[e];
      vb[e] = (__hip_bfloat16)gelu_f(v);
    }
    *(uint2*)&obase[ch0m] = *(uint2*)vb;
  }
}

// ---------------------------------------------------------------------------
// Fused RegionLayerDW for region1: same structure as region2_mfma, C=24,
// tile 32x32, G=7. Input/output NHWC bf16 [16,224,224,24]. K padded to 32
// (1 MFMA k-step), XOR-4 swizzle, A=weights (2 frags, rows 24..31 zero).
// ---------------------------------------------------------------------------
__global__ __launch_bounds__(256, 4) void region1_mfma(
    const __hip_bfloat16* __restrict__ in, const float* __restrict__ dww,
    const float* __restrict__ s1v, const float* __restrict__ b1v,
    const __hip_bfloat16* __restrict__ pwb,  // [49][24][32] bf16 K-padded
    const float* __restrict__ s2v, const float* __restrict__ b2v,
    __hip_bfloat16* __restrict__ out) {
  __shared__ __align__(16) __hip_bfloat16 sIn[10][10][24];
  __shared__ __align__(16) __hip_bfloat16 sH[64][32];
  __shared__ __align__(16) __hip_bfloat16 sW[32][32];
  __shared__ float sDW[24][9];
  __shared__ float sS1[24], sB1[24], sS2[24], sB2[24];
  const int t = blockIdx.x, sb = blockIdx.y, b = blockIdx.z;
  const int gy = t / 7, gx = t % 7;
  const int py0 = (sb >> 2) * 8, px0 = (sb & 3) * 8;
  const int Y0 = gy * 32, X0 = gx * 32;
  const int tid = threadIdx.x;
  // pw weights -> sW, XOR-4 swizzle; rows 24..31 zero
  for (int i = tid; i < 128; i += 256) {
    int n = i >> 2, g = i & 3;
    float4 v = make_float4(0.f, 0.f, 0.f, 0.f);
    if (n < 24) v = *(const float4*)&pwb[(size_t)(t * 24 + n) * 32 + g * 8];
    *(float4*)&sW[n][(g ^ (n & 3)) * 8] = v;
  }
  for (int i = tid; i < 216; i += 256) ((float*)sDW)[i] = dww[t * 216 + i];
  if (tid < 24) {
    sS1[tid] = s1v[t * 24 + tid]; sB1[tid] = b1v[t * 24 + tid];
    sS2[tid] = s2v[t * 24 + tid]; sB2[tid] = b2v[t * 24 + tid];
  }
  // sIn: 100 px x 3 uint4 groups
  for (int i = tid; i < 300; i += 256) {
    int px = i / 3, grp = i - px * 3;
    int r = px / 10, c = px - r * 10;
    int ly = py0 + r - 1, lx = px0 + c - 1;
    uint4 v = make_uint4(0u, 0u, 0u, 0u);
    if (ly >= 0 && ly < 32 && lx >= 0 && lx < 32)
      v = *(const uint4*)(in + (((size_t)b * 224 + Y0 + ly) * 224 + X0 + lx) * 24 +
                          grp * 8);
    *(uint4*)&sIn[r][c][grp * 8] = v;
  }
  __syncthreads();
  // dw 3x3 + BN + GELU -> sH; 192 threads = (cg 0..5, col 0..7, rq 0..3)
  if (tid < 192) {
    const int cg = tid >> 5;
    const int rem = tid & 31;
    const int col = rem >> 2;
    const int rq = rem & 3;          // output rows rq*2, rq*2+1
    const int ch0 = cg * 4;
    float wv[4][9], s14[4], b14[4];
#pragma unroll
    for (int c4 = 0; c4 < 4; ++c4) {
#pragma unroll
      for (int q = 0; q < 9; ++q) wv[c4][q] = sDW[ch0 + c4][q];
      s14[c4] = sS1[ch0 + c4]; b14[c4] = sB1[ch0 + c4];
    }
    float win[3][12];
#pragma unroll
    for (int rr = 0; rr < 4; ++rr) {
      int r = rq * 2 + rr;
      float* wr = win[rr % 3];
#pragma unroll
      for (int cc = 0; cc < 3; ++cc) {
        uint2 u = *(const uint2*)&sIn[r][col + cc][ch0];
        wr[cc * 4 + 0] = __uint_as_float(u.x << 16);
        wr[cc * 4 + 1] = __uint_as_float(u.x & 0xffff0000u);
        wr[cc * 4 + 2] = __uint_as_float(u.y << 16);
        wr[cc * 4 + 3] = __uint_as_float(u.y & 0xffff0000u);
      }
      if (rr >= 2) {
        const float* ra = win[(rr - 2) % 3];
        const float* rb = win[(rr - 1) % 3];
        const float* rc = win[rr % 3];
        int px = (rq * 2 + rr - 2) * 8 + col;
        __hip_bfloat16 hv[4];
#pragma unroll
        for (int c4 = 0; c4 < 4; ++c4) {
          float a = ra[c4] * wv[c4][0] + ra[4 + c4] * wv[c4][1] + ra[8 + c4] * wv[c4][2]
                  + rb[c4] * wv[c4][3] + rb[4 + c4] * wv[c4][4] + rb[8 + c4] * wv[c4][5]
                  + rc[c4] * wv[c4][6] + rc[4 + c4] * wv[c4][7] + rc[8 + c4] * wv[c4][8];
          hv[c4] = (__hip_bfloat16)gelu_f(a * s14[c4] + b14[c4]);
        }
        *(uint2*)&sH[px][((cg >> 1) ^ (px & 3)) * 8 + (cg & 1) * 4] = *(uint2*)hv;
      }
    }
  } else {
    // zero-pad sH k-group 3 (ch 24..31): 64 px, one float4 each
    int px = tid - 192;
    *(float4*)&sH[px][(3 ^ (px & 3)) * 8] = make_float4(0.f, 0.f, 0.f, 0.f);
  }
  __syncthreads();
  // pw MFMA: A = weights (2 frags), B = pixels (1 frag/wave), K=32 (1 step)
  const int wave = tid >> 6, lane = tid & 63;
  const int fm = lane & 15, quad = lane >> 4;
  const int px = wave * 16 + fm;
  short8 hb = *(const short8*)&sH[px][(quad ^ (px & 3)) * 8];
  f32x4 acc[2] = {};
#pragma unroll
  for (int m = 0; m < 2; ++m) {
    int wr = m * 16 + fm;
    short8 wa = *(const short8*)&sW[wr][(quad ^ (wr & 3)) * 8];
    acc[m] = __builtin_amdgcn_mfma_f32_16x16x32_bf16(wa, hb, acc[m], 0, 0, 0);
  }
  // epilogue: lane = 1 px; channels m*16+quad*4 (valid < 24)
  const int row = px >> 3, col = px & 7;
  __hip_bfloat16* obase =
      out + (((size_t)b * 224 + Y0 + py0 + row) * 224 + X0 + px0 + col) * 24;
#pragma unroll
  for (int m = 0; m < 2; ++m) {
    int ch0m = m * 16 + quad * 4;
    if (ch0m < 24) {
      uint2 ru = *(const uint2*)&sIn[row + 1][col + 1][ch0m];
      float res[4];
      res[0] = __uint_as_float(ru.x << 16);
      res[1] = __uint_as_float(ru.x & 0xffff0000u);
      res[2] = __uint_as_float(ru.y << 16);
      res[3] = __uint_as_float(ru.y & 0xffff0000u);
      __hip_bfloat16 vb[4];
#pragma unroll
      for (int e = 0; e < 4; ++e) {
        int ch = ch0m + e;
        float v = acc[m][e] * sS2[ch] + sB2[ch] + res[e];
        vb[e] = (__hip_bfloat16)gelu_f(v);
      }
      *(uint2*)&obase[ch0m] = *(uint2*)vb;
    }
  }
}

// ---------------------------------------------------------------------------
// Patch-GEMM via MFMA (b3 + branch2-conv2). Unchanged.
// ---------------------------------------------------------------------------
template<int PS, int IMGW, int KTOT, int KSL, bool ATOMIC>
__global__ __launch_bounds__(256) void patch_gemm_mfma(
    const __hip_bfloat16* __restrict__ A, const __hip_bfloat16* __restrict__ Wb,
    const float* __restrict__ scale, const float* __restrict__ bias,
    float* __restrict__ out, int M, int ch0) {
  constexpr int RUN = PS * 48;
  __shared__ __align__(16) __hip_bfloat16 sA[64][64];
  __shared__ __align__(16) __hip_bfloat16 sB[64][64];
  const int tid = threadIdx.x;
  const int m0 = blockIdx.x * 64, n0 = blockIdx.y * 64;
  const int kBase = blockIdx.z * KSL;
  const int mi = tid >> 2, seg = tid & 3;
  int m = m0 + mi; int mc = (m < M) ? m : (M - 1);
  int bI = mc / 196; int r = mc - bI * 196;
  int oh = r / 14, ow = r - oh * 14;
  const __hip_bfloat16* Abase =
      A + (((size_t)bI * IMGW + oh * PS) * IMGW + ow * PS) * 48;
  const __hip_bfloat16* Wrow = Wb + (size_t)(n0 + mi) * KTOT;
  const int wave = tid >> 6, lane = tid & 63;
  const int wm = (wave & 1) * 32, wn = (wave >> 1) * 32;
  const int fm = lane & 15, quad = lane >> 4;
  const int sw = fm & 7;
  f32x4 acc[2][2] = {};
  for (int k0 = kBase; k0 < kBase + KSL; k0 += 64) {
    int dy = k0 / RUN, rem = k0 - dy * RUN;
    __syncthreads();
    {
      const __hip_bfloat16* p = Abase + (size_t)dy * IMGW * 48 + rem + seg * 16;
      float4 v0 = *(const float4*)p;
      float4 v1 = *(const float4*)(p + 8);
      int key = mi & 7;
      *(float4*)&sA[mi][((seg * 2) ^ key) * 8] = v0;
      *(float4*)&sA[mi][((seg * 2 + 1) ^ key) * 8] = v1;
      const __hip_bfloat16* q = Wrow + k0 + seg * 16;
      float4 w0 = *(const float4*)q;
      float4 w1 = *(const float4*)(q + 8);
      *(float4*)&sB[mi][((seg * 2) ^ key) * 8] = w0;
      *(float4*)&sB[mi][((seg * 2 + 1) ^ key) * 8] = w1;
    }
    __syncthreads();
#pragma unroll
    for (int ks = 0; ks < 2; ++ks) {
      int cg = (ks * 4 + quad) ^ sw;
#pragma unroll
      for (int i = 0; i < 2; ++i) {
        short8 a = *(const short8*)&sA[wm + i * 16 + fm][cg * 8];
#pragma unroll
        for (int j = 0; j < 2; ++j) {
          short8 b = *(const short8*)&sB[wn + j * 16 + fm][cg * 8];
          acc[i][j] = __builtin_amdgcn_mfma_f32_16x16x32_bf16(a, b, acc[i][j], 0, 0, 0);
        }
      }
    }
  }
#pragma unroll
  for (int i = 0; i < 2; ++i) {
#pragma unroll
    for (int j = 0; j < 2; ++j) {
      int gn = n0 + wn + j * 16 + fm;
      float sc = scale[gn];
#pragma unroll
      for (int e = 0; e < 4; ++e) {
        int gm = m0 + wm + i * 16 + quad * 4 + e;
        if (gm < M) {
          if (ATOMIC)
            atomicAdd(&out[(size_t)gm * 768 + ch0 + gn], acc[i][j][e] * sc);
          else
            out[(size_t)gm * 768 + ch0 + gn] = acc[i][j][e] * sc + bias[gn];
        }
      }
    }
  }
}

__global__ void init_b3(float* __restrict__ out, const float* __restrict__ bias) {
  int i = blockIdx.x * 256 + threadIdx.x;
  if (i < 16 * 196 * 256) {
    int n = i & 255, bp = i >> 8;
    out[bp * 768 + 512 + n] = bias[n];
  }
}

// OIHW fp32 -> [N][KP] bf16 with k=(dy*ks+dx)*Cin+ic, zero-padded to KP
__global__ void reorder_w_k(const float* __restrict__ w, __hip_bfloat16* __restrict__ o,
                            int N, int Cin, int ks, int KP) {
  int i = blockIdx.x * 256 + threadIdx.x;
  if (i >= N * KP) return;
  int n = i / KP, k = i - n * KP;
  float v = 0.f;
  int K = ks * ks * Cin;
  if (k < K) {
    int dy = k / (ks * Cin); int r = k - dy * ks * Cin;
    int dx = r / Cin, ic = r - dx * Cin;
    v = w[((n * Cin + ic) * ks + dy) * ks + dx];
  }
  o[i] = (__hip_bfloat16)v;
}

// OIHW fp32 -> [Nout][KP] bf16 with channel padding
__global__ void reorder_w4(const float* __restrict__ w, __hip_bfloat16* __restrict__ o,
                           int Nout, int Nreal, int Cp, int Cr, int ks, int KP) {
  int i = blockIdx.x * 256 + threadIdx.x;
  if (i >= Nout * KP) return;
  int n = i / KP, k = i - n * KP;
  float v = 0.f;
  if (n < Nreal && k < ks * ks * Cp) {
    int dy = k / (ks * Cp); int r = k - dy * ks * Cp;
    int dx = r / Cp, ic = r - dx * Cp;
    if (ic < Cr) v = w[((n * Cr + ic) * ks + dy) * ks + dx];
  }
  o[i] = (__hip_bfloat16)v;
}

// region2 pw weights [16][48][48] fp32 -> [16][48][64] bf16 (K-padded)
__global__ void rw_pw(const float* __restrict__ pw, __hip_bfloat16* __restrict__ o) {
  int i = blockIdx.x * 256 + threadIdx.x;
  if (i >= 16 * 48 * 64) return;
  int t = i / 3072, r = i - t * 3072;
  int n = r >> 6, k = r & 63;
  float v = (k < 48) ? pw[(t * 48 + n) * 48 + k] : 0.f;
  o[i] = (__hip_bfloat16)v;
}

// region1 pw weights [49][24][24] fp32 -> [49][24][32] bf16 (K-padded)
__global__ void rw_pw1(const float* __restrict__ pw, __hip_bfloat16* __restrict__ o) {
  int i = blockIdx.x * 256 + threadIdx.x;
  if (i >= 49 * 24 * 32) return;
  int t = i / 768, r = i - t * 768;
  int n = r >> 5, k = r & 31;
  float v = (k < 24) ? pw[(t * 24 + n) * 24 + k] : 0.f;
  o[i] = (__hip_bfloat16)v;
}

// x [16,3,224,224] fp32 -> [16,224,224,4] bf16 (ch3 = 0)
__global__ void xcvt(const float* __restrict__ x, __hip_bfloat16* __restrict__ o) {
  int i = blockIdx.x * 256 + threadIdx.x;
  if (i >= 802816) return;
  int b = i / 50176, p = i - b * 50176;
  const float* src = x + (size_t)b * 150528 + p;
  __hip_bfloat16 v[4];
  v[0] = (__hip_bfloat16)src[0];
  v[1] = (__hip_bfloat16)src[50176];
  v[2] = (__hip_bfloat16)src[100352];
  v[3] = (__hip_bfloat16)0.0f;
  *(uint2*)&o[(size_t)i * 4] = *(uint2*)v;
}

// ---------------------------------------------------------------------------
extern "C" void kernel_launch(void* const* d_in, const int* in_sizes, int n_in,
                              void* d_out, int out_size, void* d_ws, size_t ws_size,
                              hipStream_t stream) {
  const float* x     = (const float*)d_in[0];
  const float* r1_w  = (const float*)d_in[1];
  const float* r1_s  = (const float*)d_in[2];
  const float* r1_b  = (const float*)d_in[3];
  const float* r1_dw = (const float*)d_in[4];
  const float* r1_s1 = (const float*)d_in[5];
  const float* r1_b1 = (const float*)d_in[6];
  const float* r1_pw = (const float*)d_in[7];
  const float* r1_s2 = (const float*)d_in[8];
  const float* r1_b2 = (const float*)d_in[9];
  const float* r2_w  = (const float*)d_in[10];
  const float* r2_s  = (const float*)d_in[11];
  const float* r2_b  = (const float*)d_in[12];
  const float* r2_dw = (const float*)d_in[13];
  const float* r2_s1 = (const float*)d_in[14];
  const float* r2_b1 = (const float*)d_in[15];
  const float* r2_pw = (const float*)d_in[16];
  const float* r2_s2 = (const float*)d_in[17];
  const float* r2_b2 = (const float*)d_in[18];
  const float* h1_w1 = (const float*)d_in[19];
  const float* h1_s1 = (const float*)d_in[20];
  const float* h1_b1 = (const float*)d_in[21];
  const float* h1_w2 = (const float*)d_in[22];
  const float* h1_s2 = (const float*)d_in[23];
  const float* h1_b2 = (const float*)d_in[24];
  const float* h1_w3 = (const float*)d_in[25];
  const float* h1_s3 = (const float*)d_in[26];
  const float* h1_b3 = (const float*)d_in[27];
  const float* h2_w1 = (const float*)d_in[28];
  const float* h2_s1 = (const float*)d_in[29];
  const float* h2_b1 = (const float*)d_in[30];
  const float* h2_w2 = (const float*)d_in[31];
  const float* h2_s2 = (const float*)d_in[32];
  const float* h2_b2 = (const float*)d_in[33];
  const float* h3_w  = (const float*)d_in[34];
  const float* h3_s  = (const float*)d_in[35];
  const float* h3_b  = (const float*)d_in[36];
  float* out = (float*)d_out;

  // Workspace (float-slot offsets). FULL-BATCH, peak 222.9 MB < 256 MiB.
  float* F = (float*)d_ws;
  __hip_bfloat16* R1b   = (__hip_bfloat16*)F;                    // [16,224,224,24]
  __hip_bfloat16* C5b   = (__hip_bfloat16*)(F + 9633792);        // [16,224,224,24] (conv5 out; dead before conv3)
  __hip_bfloat16* T1b   = (__hip_bfloat16*)(F + 9633792);        // [16,224,224,48]
  __hip_bfloat16* T2b   = (__hip_bfloat16*)(F + 28901376);       // [16,224,224,48]
  __hip_bfloat16* h3wb  = (__hip_bfloat16*)(F + 48168960);       // [256][12288]
  __hip_bfloat16* r2wb  = (__hip_bfloat16*)(F + 49741824);       // [48][224]
  __hip_bfloat16* h2w1b = (__hip_bfloat16*)(F + 49747200);       // [48][384]
  __hip_bfloat16* pw2wb = (__hip_bfloat16*)(F + 49756416);       // [16][48][64]
  __hip_bfloat16* r1wb  = (__hip_bfloat16*)(F + 49780992);       // [32][128]
  __hip_bfloat16* h2w2b = (__hip_bfloat16*)(F + 49783040);       // [256][768]
  __hip_bfloat16* xb    = (__hip_bfloat16*)(F + 49881344);       // [16,224,224,4]
  __hip_bfloat16* S1b   = (__hip_bfloat16*)(F + 51486976);       // [16,56,56,48]
  float* S1             = F + 52691200;                          // [16,48,56,56]
  float* S2             = F + 55099648;                          // [16,48,28,28]
  __hip_bfloat16* pw1wb = (__hip_bfloat16*)(F + 55701760);       // [49][24][32]

  dim3 blk(256);

  // ---- input conversion + weight reorders
  xcvt<<<dim3(3136), blk, 0, stream>>>(x, xb);
  reorder_w_k<<<dim3(12288), blk, 0, stream>>>(h3_w, h3wb, 256, 48, 16, 12288);
  reorder_w_k<<<dim3(42), blk, 0, stream>>>(r2_w, r2wb, 48, 24, 3, 224);
  reorder_w_k<<<dim3(72), blk, 0, stream>>>(h2_w1, h2w1b, 48, 24, 4, 384);
  reorder_w_k<<<dim3(768), blk, 0, stream>>>(h2_w2, h2w2b, 256, 48, 4, 768);
  reorder_w4<<<dim3(16), blk, 0, stream>>>(r1_w, r1wb, 32, 24, 4, 3, 5, 128);
  rw_pw<<<dim3(192), blk, 0, stream>>>(r2_pw, pw2wb);
  rw_pw1<<<dim3(147), blk, 0, stream>>>(r1_pw, pw1wb);

  // ---- region1 chain, FULL BATCH: conv5 MFMA -> C5b NHWC bf16, region1 -> R1b
  nhwc_conv_mfma<4, 5, 1, 2, 32, 128, true, 1, 24><<<dim3(12544), blk, 0, stream>>>(
      xb, r1wb, r1_s, r1_b, (float*)C5b, 224, 224, 224, 50176);
  region1_mfma<<<dim3(49, 16, 16), blk, 0, stream>>>(
      C5b, r1_dw, r1_s1, r1_b1, pw1wb, r1_s2, r1_b2, R1b);
  // ---- branch2: R1b -> S1b bf16 NHWC -> out[ch 256:512]
  nhwc_conv_mfma<24, 4, 4, 0, 48, 384, true, 1><<<dim3(784), blk, 0, stream>>>(
      R1b, h2w1b, h2_s1, h2_b1, (float*)S1b, 224, 224, 56, 3136);
  patch_gemm_mfma<4, 56, 768, 768, false><<<dim3(49, 4, 1), blk, 0, stream>>>(
      S1b, h2w2b, h2_s2, h2_b2, out, 3136, 256);
  // ---- branch1: x -> S1 -> S2 -> out[ch 0:256] (fp32, small)
  convgemm_k<false, true, false><<<dim3(784, 1), blk, 0, stream>>>(
      x, h1_w1, h1_s1, h1_b1, S1, 3, 224, 224, 4, 4, 0, 2, 56, 56, 48, 48, 0);
  convgemm_k<false, true, false><<<dim3(196, 1), blk, 0, stream>>>(
      S1, h1_w2, h1_s2, h1_b2, S2, 48, 56, 56, 2, 2, 0, 1, 28, 28, 48, 192, 0);
  convgemm_k<false, false, true><<<dim3(49, 4), blk, 0, stream>>>(
      S2, h1_w3, h1_s3, h1_b3, out, 48, 28, 28, 2, 2, 0, 1, 14, 14, 256, 192, 0);
  // ---- branch3 FULL BATCH: conv3 -> region2 -> b3 patch-GEMM (split-K)
  init_b3<<<dim3(3136), blk, 0, stream>>>(out, h3_b);
  nhwc_conv_mfma<24, 3, 1, 1, 48, 224, true, 1><<<dim3(12544), blk, 0, stream>>>(
      R1b, r2wb, r2_s, r2_b, (float*)T1b, 224, 224, 224, 50176);
  region2_mfma<<<dim3(16, 49, 16), blk, 0, stream>>>(
      T1b, r2_dw, r2_s1, r2_b1, pw2wb, r2_s2, r2_b2, T2b);
  patch_gemm_mfma<16, 224, 12288, 1536, true><<<dim3(49, 4, 8), blk, 0, stream>>>(
      T2b, h3wb, h3_s, h3_b, out, 3136, 512);
  (void)in_sizes; (void)n_in; (void)out_size; (void)ws_size;
}